// Round 3
// baseline (1433.661 us; speedup 1.0000x reference)
//
#include <hip/hip_runtime.h>

#define N_NODES 100000
#define N_EDGES 640000
#define HID 128
#define N_CLASSES 40
#define N_GRAPHS 128
#define BN_EPS 1e-5f
#define POOL_SLICES 16

// ---------------------------------------------------------------------------
// degree / CSR construction
// ---------------------------------------------------------------------------
__global__ void count_kernel(const int* __restrict__ row, const int* __restrict__ col,
                             int* degcnt, int* cnt, int E) {
    int e = blockIdx.x * 256 + threadIdx.x;
    if (e < E) {
        atomicAdd(&degcnt[row[e]], 1);
        atomicAdd(&cnt[col[e]], 1);
    }
}

__global__ void dinv_kernel(const int* __restrict__ degcnt, float* __restrict__ dinv, int n) {
    int i = blockIdx.x * 256 + threadIdx.x;
    if (i < n) dinv[i] = rsqrtf((float)degcnt[i] + 1.0f);
}

// block-level exclusive scan (1024 elements per block of 256 threads)
__global__ __launch_bounds__(256) void scanA(const int* __restrict__ cnt, int* __restrict__ rowptr,
                                             int* __restrict__ blockSums, int n) {
    __shared__ int sdata[256];
    int t = threadIdx.x;
    int base = blockIdx.x * 1024 + t * 4;
    int c[4];
#pragma unroll
    for (int j = 0; j < 4; ++j) c[j] = (base + j < n) ? cnt[base + j] : 0;
    int s = c[0] + c[1] + c[2] + c[3];
    sdata[t] = s;
    __syncthreads();
    for (int off = 1; off < 256; off <<= 1) {
        int v = (t >= off) ? sdata[t - off] : 0;
        __syncthreads();
        sdata[t] += v;
        __syncthreads();
    }
    int excl = sdata[t] - s;
    if (t == 255) blockSums[blockIdx.x] = sdata[255];
    int run = excl;
#pragma unroll
    for (int j = 0; j < 4; ++j) {
        if (base + j < n) rowptr[base + j] = run;
        run += c[j];
    }
}

__global__ void scanB(const int* __restrict__ blockSums, int* __restrict__ blockOffs, int nb) {
    __shared__ int sdata[128];
    int t = threadIdx.x;
    int v = (t < nb) ? blockSums[t] : 0;
    sdata[t] = v;
    __syncthreads();
    for (int off = 1; off < 128; off <<= 1) {
        int u = (t >= off) ? sdata[t - off] : 0;
        __syncthreads();
        sdata[t] += u;
        __syncthreads();
    }
    if (t < nb) blockOffs[t] = sdata[t] - v;
}

__global__ void scanC(int* __restrict__ rowptr, const int* __restrict__ blockOffs,
                      int* __restrict__ wptr, int n) {
    int i = blockIdx.x * 256 + threadIdx.x;
    if (i < n) {
        int v = rowptr[i] + blockOffs[i >> 10];
        rowptr[i] = v;
        wptr[i] = v;
    }
}

__global__ void fill_kernel(const int* __restrict__ row, const int* __restrict__ col,
                            int* wptr, int* __restrict__ srcIdx, int E) {
    int e = blockIdx.x * 256 + threadIdx.x;
    if (e < E) {
        int p = atomicAdd(&wptr[col[e]], 1);
        srcIdx[p] = row[e];
    }
}

// ---------------------------------------------------------------------------
// GEMM: out[N x 128] = f(in)[N x 128] @ W[128 x 128]
// f = identity, or BN(scale,shift)+ReLU fused on input load when useBN!=0.
// 512 threads / block, 128x128 tile, W in 64KB LDS. 2 blocks/CU -> 16
// waves/CU (4/SIMD). Input fragments double-buffered (k unrolled by 2).
// Thread (rg=t>>4: 4 rows, cg=t&15: cols cg*4 and cg*4+64).
// ---------------------------------------------------------------------------
__global__ __launch_bounds__(512, 4) void gemm128(
    const float* __restrict__ in, const float* __restrict__ W,
    const float* __restrict__ bn_s, const float* __restrict__ bn_t,
    float* __restrict__ out, int nRows, int useBN) {
    __shared__ float Wl[128 * 128];  // 64 KB
    {
        const float4* Ws = (const float4*)W;
        float4* Wd = (float4*)Wl;
        for (int i = threadIdx.x; i < 128 * 128 / 4; i += 512) Wd[i] = Ws[i];
    }
    __syncthreads();

    const int cg = threadIdx.x & 15;
    const int rg = threadIdx.x >> 4;  // 0..31
    const int c0 = cg * 4;
    const long base_row = (long)blockIdx.x * 128 + rg * 4;

    bool ok[4];
    const float* rp[4];
#pragma unroll
    for (int i = 0; i < 4; ++i) {
        long r = base_row + i;
        ok[i] = (r < nRows);
        rp[i] = in + (ok[i] ? r : 0) * 128;
    }

    float acc[4][8];
#pragma unroll
    for (int i = 0; i < 4; ++i)
#pragma unroll
        for (int j = 0; j < 8; ++j) acc[i][j] = 0.f;

    const float4 z4 = make_float4(0.f, 0.f, 0.f, 0.f);
    float4 aA[4], aB[4];
#pragma unroll
    for (int i = 0; i < 4; ++i) aA[i] = ok[i] ? *(const float4*)(rp[i] + 0) : z4;

    // one k-quad (4 k values) of FMAs against fragment a[]
    auto compute = [&](float4* a, int kq) {
        if (useBN) {
            float4 sv = *(const float4*)&bn_s[kq * 4];
            float4 tv = *(const float4*)&bn_t[kq * 4];
#pragma unroll
            for (int i = 0; i < 4; ++i) {
                a[i].x = fmaxf(fmaf(a[i].x, sv.x, tv.x), 0.f);
                a[i].y = fmaxf(fmaf(a[i].y, sv.y, tv.y), 0.f);
                a[i].z = fmaxf(fmaf(a[i].z, sv.z, tv.z), 0.f);
                a[i].w = fmaxf(fmaf(a[i].w, sv.w, tv.w), 0.f);
            }
        }
#pragma unroll
        for (int c = 0; c < 4; ++c) {
            int k = kq * 4 + c;
            float4 w0 = *(const float4*)&Wl[k * 128 + c0];
            float4 w1 = *(const float4*)&Wl[k * 128 + c0 + 64];
#pragma unroll
            for (int i = 0; i < 4; ++i) {
                float av = (c == 0) ? a[i].x : (c == 1) ? a[i].y : (c == 2) ? a[i].z : a[i].w;
                acc[i][0] = fmaf(av, w0.x, acc[i][0]);
                acc[i][1] = fmaf(av, w0.y, acc[i][1]);
                acc[i][2] = fmaf(av, w0.z, acc[i][2]);
                acc[i][3] = fmaf(av, w0.w, acc[i][3]);
                acc[i][4] = fmaf(av, w1.x, acc[i][4]);
                acc[i][5] = fmaf(av, w1.y, acc[i][5]);
                acc[i][6] = fmaf(av, w1.z, acc[i][6]);
                acc[i][7] = fmaf(av, w1.w, acc[i][7]);
            }
        }
    };

    for (int kq = 0; kq < 32; kq += 2) {
        // prefetch kq+1 while computing kq
#pragma unroll
        for (int i = 0; i < 4; ++i) aB[i] = ok[i] ? *(const float4*)(rp[i] + (kq + 1) * 4) : z4;
        compute(aA, kq);
        if (kq + 2 < 32) {
#pragma unroll
            for (int i = 0; i < 4; ++i) aA[i] = ok[i] ? *(const float4*)(rp[i] + (kq + 2) * 4) : z4;
        }
        compute(aB, kq + 1);
    }

#pragma unroll
    for (int i = 0; i < 4; ++i) {
        long r = base_row + i;
        if (r < nRows) {
            *(float4*)&out[r * 128 + c0] =
                make_float4(acc[i][0], acc[i][1], acc[i][2], acc[i][3]);
            *(float4*)&out[r * 128 + c0 + 64] =
                make_float4(acc[i][4], acc[i][5], acc[i][6], acc[i][7]);
        }
    }
}

// ---------------------------------------------------------------------------
// Aggregation: out[v] = dinv[v] * sum_{e in CSR(v)} dinv[src_e] * h[src_e]
// One wave (64 lanes) per node; lane holds 2 features (float2). No atomics.
// ---------------------------------------------------------------------------
__global__ __launch_bounds__(256) void agg_kernel(
    const float* __restrict__ h, const int* __restrict__ rowptr,
    const int* __restrict__ cnt, const int* __restrict__ srcIdx,
    const float* __restrict__ dinv, float* __restrict__ out, int nNodes) {
    int wave = threadIdx.x >> 6;
    int lane = threadIdx.x & 63;
    int v = blockIdx.x * 4 + wave;
    if (v >= nNodes) return;
    int start = rowptr[v];
    int n = cnt[v];
    float ax = 0.f, ay = 0.f;
    for (int e = 0; e < n; ++e) {
        int src = srcIdx[start + e];
        float w = dinv[src];
        float2 hv = *(const float2*)&h[(long)src * 128 + lane * 2];
        ax = fmaf(w, hv.x, ax);
        ay = fmaf(w, hv.y, ay);
    }
    float dv = dinv[v];
    *(float2*)&out[(long)v * 128 + lane * 2] = make_float2(ax * dv, ay * dv);
}

// ---------------------------------------------------------------------------
// BN statistics: per-column sum and sum-of-squares via block partials + atomics
// ---------------------------------------------------------------------------
__global__ __launch_bounds__(256) void bnstats(const float* __restrict__ h,
                                               float* __restrict__ sums, int nRows) {
    int col = threadIdx.x & 127;
    int half = threadIdx.x >> 7;
    int chunk = (nRows + gridDim.x - 1) / gridDim.x;
    int r0 = blockIdx.x * chunk;
    int r1 = min(r0 + chunk, nRows);
    float s = 0.f, s2 = 0.f;
    for (int r = r0 + half; r < r1; r += 2) {
        float v = h[(long)r * 128 + col];
        s += v;
        s2 = fmaf(v, v, s2);
    }
    __shared__ float l1[256], l2[256];
    l1[threadIdx.x] = s;
    l2[threadIdx.x] = s2;
    __syncthreads();
    if (half == 0) {
        s = l1[threadIdx.x] + l1[threadIdx.x + 128];
        s2 = l2[threadIdx.x] + l2[threadIdx.x + 128];
        atomicAdd(&sums[col], s);
        atomicAdd(&sums[128 + col], s2);
    }
}

__global__ void bnfin(const float* __restrict__ sums, const float* __restrict__ gamma,
                      const float* __restrict__ beta, float* __restrict__ bn_s,
                      float* __restrict__ bn_t, float invN) {
    int c = threadIdx.x;
    float mean = sums[c] * invN;
    float var = sums[128 + c] * invN - mean * mean;
    float rs = rsqrtf(var + BN_EPS);
    float s = gamma[c] * rs;
    bn_s[c] = s;
    bn_t[c] = beta[c] - mean * s;
}

// ---------------------------------------------------------------------------
// Global mean pool, stage 1: per-slice partial sums, atomicAdd into poolAcc.
// ---------------------------------------------------------------------------
__global__ __launch_bounds__(256) void pool_partial(
    const float* __restrict__ h, const int* __restrict__ batch,
    float* __restrict__ poolAcc, int nNodes) {
    int g = blockIdx.x / POOL_SLICES;
    int s = blockIdx.x % POOL_SLICES;
    int a = 0, b = nNodes;
    while (a < b) { int m = (a + b) >> 1; if (batch[m] < g) a = m + 1; else b = m; }
    int lo = a;
    b = nNodes;
    while (a < b) { int m = (a + b) >> 1; if (batch[m] < g + 1) a = m + 1; else b = m; }
    int hi = a;
    int len = hi - lo;
    int per = (len + POOL_SLICES - 1) / POOL_SLICES;
    int a0 = lo + s * per;
    int a1 = min(a0 + per, hi);
    if (a0 >= a1) return;
    int col = threadIdx.x & 127;
    int half = threadIdx.x >> 7;
    float acc = 0.f;
    for (int v = a0 + half; v < a1; v += 2) acc += h[(long)v * 128 + col];
    __shared__ float l[256];
    l[threadIdx.x] = acc;
    __syncthreads();
    if (half == 0) atomicAdd(&poolAcc[g * 128 + col], l[threadIdx.x] + l[threadIdx.x + 128]);
}

// ---------------------------------------------------------------------------
// MLP head: mean = poolAcc/cnt; relu(xg@Wg1+bg1) @ Wg2 + bg2 -> log_softmax
// ---------------------------------------------------------------------------
__global__ __launch_bounds__(128) void head_kernel(
    const float* __restrict__ poolAcc, const int* __restrict__ batch,
    const float* __restrict__ Wg1, const float* __restrict__ bg1,
    const float* __restrict__ Wg2, const float* __restrict__ bg2,
    float* __restrict__ out, int nNodes) {
    __shared__ float xr[128], tr[128], lg[N_CLASSES], red[2];
    int g = blockIdx.x, t = threadIdx.x;
    int a = 0, b = nNodes;
    while (a < b) { int m = (a + b) >> 1; if (batch[m] < g) a = m + 1; else b = m; }
    int lo = a;
    b = nNodes;
    while (a < b) { int m = (a + b) >> 1; if (batch[m] < g + 1) a = m + 1; else b = m; }
    float cntf = fmaxf((float)(a - lo), 1.0f);
    xr[t] = poolAcc[g * 128 + t] / cntf;
    __syncthreads();
    float s = bg1[t];
    for (int k = 0; k < 128; ++k) s = fmaf(xr[k], Wg1[k * 128 + t], s);
    tr[t] = fmaxf(s, 0.f);
    __syncthreads();
    if (t < N_CLASSES) {
        float s2 = bg2[t];
        for (int k = 0; k < 128; ++k) s2 = fmaf(tr[k], Wg2[k * N_CLASSES + t], s2);
        lg[t] = s2;
    }
    __syncthreads();
    if (t == 0) {
        float m = -1e30f;
        for (int j = 0; j < N_CLASSES; ++j) m = fmaxf(m, lg[j]);
        float se = 0.f;
        for (int j = 0; j < N_CLASSES; ++j) se += expf(lg[j] - m);
        red[0] = m;
        red[1] = logf(se);
    }
    __syncthreads();
    if (t < N_CLASSES) out[g * N_CLASSES + t] = lg[t] - red[0] - red[1];
}

// ---------------------------------------------------------------------------
extern "C" void kernel_launch(void* const* d_in, const int* in_sizes, int n_in,
                              void* d_out, int out_size, void* d_ws, size_t ws_size,
                              hipStream_t stream) {
    const float* x = (const float*)d_in[0];
    const int* edge = (const int*)d_in[1];
    const int* row = edge;
    const int* col = edge + N_EDGES;
    const int* batch = (const int*)d_in[2];
    const float* W0 = (const float*)d_in[3];
    const float* g0 = (const float*)d_in[4];
    const float* b0 = (const float*)d_in[5];
    const float* W1 = (const float*)d_in[6];
    const float* g1 = (const float*)d_in[7];
    const float* b1 = (const float*)d_in[8];
    const float* W2 = (const float*)d_in[9];
    const float* Wg1 = (const float*)d_in[10];
    const float* bg1 = (const float*)d_in[11];
    const float* Wg2 = (const float*)d_in[12];
    const float* bg2 = (const float*)d_in[13];
    float* out = (float*)d_out;

    char* p = (char*)d_ws;
    auto alloc = [&](size_t bytes) {
        void* r = (void*)p;
        p += (bytes + 255) & ~(size_t)255;
        return r;
    };
    float* bufA = (float*)alloc((size_t)N_NODES * 128 * 4);
    float* bufB = (float*)alloc((size_t)N_NODES * 128 * 4);
    float* dinv = (float*)alloc((size_t)N_NODES * 4);
    int* degcnt = (int*)alloc((size_t)N_NODES * 4);
    int* cnt = (int*)alloc((size_t)N_NODES * 4);
    int* rowptr = (int*)alloc((size_t)N_NODES * 4);
    int* wptr = (int*)alloc((size_t)N_NODES * 4);
    int* srcIdx = (int*)alloc((size_t)N_EDGES * 4);
    int* blockSums = (int*)alloc(1024 * 4);
    int* blockOffs = (int*)alloc(1024 * 4);
    float* bnacc = (float*)alloc(256 * 4);
    float* bn_s = (float*)alloc(128 * 4);
    float* bn_t = (float*)alloc(128 * 4);
    float* poolAcc = (float*)alloc(128 * 128 * 4);

    const int E = N_EDGES, N = N_NODES;
    const int scanBlocks = (N + 1023) / 1024;  // 98

    // --- degree + CSR (recomputed every call: deterministic work) ---
    hipMemsetAsync(degcnt, 0, (size_t)N * 4, stream);
    hipMemsetAsync(cnt, 0, (size_t)N * 4, stream);
    count_kernel<<<(E + 255) / 256, 256, 0, stream>>>(row, col, degcnt, cnt, E);
    dinv_kernel<<<(N + 255) / 256, 256, 0, stream>>>(degcnt, dinv, N);
    scanA<<<scanBlocks, 256, 0, stream>>>(cnt, rowptr, blockSums, N);
    scanB<<<1, 128, 0, stream>>>(blockSums, blockOffs, scanBlocks);
    scanC<<<(N + 255) / 256, 256, 0, stream>>>(rowptr, blockOffs, wptr, N);
    fill_kernel<<<(E + 255) / 256, 256, 0, stream>>>(row, col, wptr, srcIdx, E);

    const int gemmGrid = (N + 127) / 128;  // 782
    const int aggGrid = (N + 3) / 4;       // 25000

    // --- layer 1 ---
    gemm128<<<gemmGrid, 512, 0, stream>>>(x, W0, nullptr, nullptr, bufA, N, 0);
    agg_kernel<<<aggGrid, 256, 0, stream>>>(bufA, rowptr, cnt, srcIdx, dinv, bufB, N);
    hipMemsetAsync(bnacc, 0, 256 * 4, stream);
    bnstats<<<512, 256, 0, stream>>>(bufB, bnacc, N);
    bnfin<<<1, 128, 0, stream>>>(bnacc, g0, b0, bn_s, bn_t, 1.0f / N);

    // --- layer 2 ---
    gemm128<<<gemmGrid, 512, 0, stream>>>(bufB, W1, bn_s, bn_t, bufA, N, 1);
    agg_kernel<<<aggGrid, 256, 0, stream>>>(bufA, rowptr, cnt, srcIdx, dinv, bufB, N);
    hipMemsetAsync(bnacc, 0, 256 * 4, stream);
    bnstats<<<512, 256, 0, stream>>>(bufB, bnacc, N);
    bnfin<<<1, 128, 0, stream>>>(bnacc, g1, b1, bn_s, bn_t, 1.0f / N);

    // --- layer 3 ---
    gemm128<<<gemmGrid, 512, 0, stream>>>(bufB, W2, bn_s, bn_t, bufA, N, 1);
    agg_kernel<<<aggGrid, 256, 0, stream>>>(bufA, rowptr, cnt, srcIdx, dinv, bufB, N);

    // --- pool (parallel partials) + head ---
    hipMemsetAsync(poolAcc, 0, 128 * 128 * 4, stream);
    pool_partial<<<N_GRAPHS * POOL_SLICES, 256, 0, stream>>>(bufB, batch, poolAcc, N);
    head_kernel<<<N_GRAPHS, 128, 0, stream>>>(poolAcc, batch, Wg1, bg1, Wg2, bg2, out, N);
}

// Round 4
// 712.266 us; speedup vs baseline: 2.0128x; 2.0128x over previous
//
#include <hip/hip_runtime.h>

#define N_NODES 100000
#define N_EDGES 640000
#define HID 128
#define N_CLASSES 40
#define N_GRAPHS 128
#define BN_EPS 1e-5f
#define POOL_SLICES 16

// ---------------------------------------------------------------------------
// degree / CSR construction
// ---------------------------------------------------------------------------
__global__ void count_kernel(const int* __restrict__ row, const int* __restrict__ col,
                             int* degcnt, int* cnt, int E) {
    int e = blockIdx.x * 256 + threadIdx.x;
    if (e < E) {
        atomicAdd(&degcnt[row[e]], 1);
        atomicAdd(&cnt[col[e]], 1);
    }
}

__global__ void dinv_kernel(const int* __restrict__ degcnt, float* __restrict__ dinv, int n) {
    int i = blockIdx.x * 256 + threadIdx.x;
    if (i < n) dinv[i] = rsqrtf((float)degcnt[i] + 1.0f);
}

// block-level exclusive scan (1024 elements per block of 256 threads)
__global__ __launch_bounds__(256) void scanA(const int* __restrict__ cnt, int* __restrict__ rowptr,
                                             int* __restrict__ blockSums, int n) {
    __shared__ int sdata[256];
    int t = threadIdx.x;
    int base = blockIdx.x * 1024 + t * 4;
    int c[4];
#pragma unroll
    for (int j = 0; j < 4; ++j) c[j] = (base + j < n) ? cnt[base + j] : 0;
    int s = c[0] + c[1] + c[2] + c[3];
    sdata[t] = s;
    __syncthreads();
    for (int off = 1; off < 256; off <<= 1) {
        int v = (t >= off) ? sdata[t - off] : 0;
        __syncthreads();
        sdata[t] += v;
        __syncthreads();
    }
    int excl = sdata[t] - s;
    if (t == 255) blockSums[blockIdx.x] = sdata[255];
    int run = excl;
#pragma unroll
    for (int j = 0; j < 4; ++j) {
        if (base + j < n) rowptr[base + j] = run;
        run += c[j];
    }
}

__global__ void scanB(const int* __restrict__ blockSums, int* __restrict__ blockOffs, int nb) {
    __shared__ int sdata[128];
    int t = threadIdx.x;
    int v = (t < nb) ? blockSums[t] : 0;
    sdata[t] = v;
    __syncthreads();
    for (int off = 1; off < 128; off <<= 1) {
        int u = (t >= off) ? sdata[t - off] : 0;
        __syncthreads();
        sdata[t] += u;
        __syncthreads();
    }
    if (t < nb) blockOffs[t] = sdata[t] - v;
}

__global__ void scanC(int* __restrict__ rowptr, const int* __restrict__ blockOffs,
                      int* __restrict__ wptr, int n) {
    int i = blockIdx.x * 256 + threadIdx.x;
    if (i < n) {
        int v = rowptr[i] + blockOffs[i >> 10];
        rowptr[i] = v;
        wptr[i] = v;
    }
}

__global__ void fill_kernel(const int* __restrict__ row, const int* __restrict__ col,
                            int* wptr, int* __restrict__ srcIdx, int E) {
    int e = blockIdx.x * 256 + threadIdx.x;
    if (e < E) {
        int p = atomicAdd(&wptr[col[e]], 1);
        srcIdx[p] = row[e];
    }
}

// ---------------------------------------------------------------------------
// GEMM: out[N x 128] = f(in)[N x 128] @ W[128 x 128]
// f = identity, or BN(scale,shift)+ReLU fused on input load when useBN!=0.
// Round-2 structure (proven no-spill) but NO LDS: W read direct from global.
// Per k-quad only 4 rows of W (2 KB) are hot -> L1-resident, block-wide reuse;
// W total 64 KB is L2-resident. No LDS -> occupancy VGPR-limited (~16 wv/CU),
// double round 2's 8 (LDS capped 2 blocks/CU before).
// ---------------------------------------------------------------------------
__global__ __launch_bounds__(256) void gemm128(
    const float* __restrict__ in, const float* __restrict__ W,
    const float* __restrict__ bn_s, const float* __restrict__ bn_t,
    float* __restrict__ out, int nRows, int useBN) {
    const int cg = threadIdx.x & 15;
    const int rg = threadIdx.x >> 4;
    const int c0 = cg * 4;
    const long base_row = (long)blockIdx.x * 64 + rg * 4;

    float acc[4][8];
#pragma unroll
    for (int i = 0; i < 4; ++i)
#pragma unroll
        for (int j = 0; j < 8; ++j) acc[i][j] = 0.f;

    for (int kq = 0; kq < 32; ++kq) {
        float4 a[4];
#pragma unroll
        for (int i = 0; i < 4; ++i) {
            long r = base_row + i;
            a[i] = (r < nRows) ? *(const float4*)&in[r * 128 + kq * 4]
                               : make_float4(0.f, 0.f, 0.f, 0.f);
        }
        if (useBN) {
            float4 sv = *(const float4*)&bn_s[kq * 4];
            float4 tv = *(const float4*)&bn_t[kq * 4];
#pragma unroll
            for (int i = 0; i < 4; ++i) {
                a[i].x = fmaxf(fmaf(a[i].x, sv.x, tv.x), 0.f);
                a[i].y = fmaxf(fmaf(a[i].y, sv.y, tv.y), 0.f);
                a[i].z = fmaxf(fmaf(a[i].z, sv.z, tv.z), 0.f);
                a[i].w = fmaxf(fmaf(a[i].w, sv.w, tv.w), 0.f);
            }
        }
#pragma unroll
        for (int c = 0; c < 4; ++c) {
            int k = kq * 4 + c;
            float4 w0 = *(const float4*)&W[k * 128 + c0];
            float4 w1 = *(const float4*)&W[k * 128 + c0 + 64];
#pragma unroll
            for (int i = 0; i < 4; ++i) {
                float av = (c == 0) ? a[i].x : (c == 1) ? a[i].y : (c == 2) ? a[i].z : a[i].w;
                acc[i][0] = fmaf(av, w0.x, acc[i][0]);
                acc[i][1] = fmaf(av, w0.y, acc[i][1]);
                acc[i][2] = fmaf(av, w0.z, acc[i][2]);
                acc[i][3] = fmaf(av, w0.w, acc[i][3]);
                acc[i][4] = fmaf(av, w1.x, acc[i][4]);
                acc[i][5] = fmaf(av, w1.y, acc[i][5]);
                acc[i][6] = fmaf(av, w1.z, acc[i][6]);
                acc[i][7] = fmaf(av, w1.w, acc[i][7]);
            }
        }
    }
#pragma unroll
    for (int i = 0; i < 4; ++i) {
        long r = base_row + i;
        if (r < nRows) {
            *(float4*)&out[r * 128 + c0] =
                make_float4(acc[i][0], acc[i][1], acc[i][2], acc[i][3]);
            *(float4*)&out[r * 128 + c0 + 64] =
                make_float4(acc[i][4], acc[i][5], acc[i][6], acc[i][7]);
        }
    }
}

// ---------------------------------------------------------------------------
// Aggregation: out[v] = dinv[v] * sum_{e in CSR(v)} dinv[src_e] * h[src_e]
// One wave (64 lanes) per node; lane holds 2 features (float2). No atomics.
// ---------------------------------------------------------------------------
__global__ __launch_bounds__(256) void agg_kernel(
    const float* __restrict__ h, const int* __restrict__ rowptr,
    const int* __restrict__ cnt, const int* __restrict__ srcIdx,
    const float* __restrict__ dinv, float* __restrict__ out, int nNodes) {
    int wave = threadIdx.x >> 6;
    int lane = threadIdx.x & 63;
    int v = blockIdx.x * 4 + wave;
    if (v >= nNodes) return;
    int start = rowptr[v];
    int n = cnt[v];
    float ax = 0.f, ay = 0.f;
    for (int e = 0; e < n; ++e) {
        int src = srcIdx[start + e];
        float w = dinv[src];
        float2 hv = *(const float2*)&h[(long)src * 128 + lane * 2];
        ax = fmaf(w, hv.x, ax);
        ay = fmaf(w, hv.y, ay);
    }
    float dv = dinv[v];
    *(float2*)&out[(long)v * 128 + lane * 2] = make_float2(ax * dv, ay * dv);
}

// ---------------------------------------------------------------------------
// BN statistics: per-column sum and sum-of-squares via block partials + atomics
// ---------------------------------------------------------------------------
__global__ __launch_bounds__(256) void bnstats(const float* __restrict__ h,
                                               float* __restrict__ sums, int nRows) {
    int col = threadIdx.x & 127;
    int half = threadIdx.x >> 7;
    int chunk = (nRows + gridDim.x - 1) / gridDim.x;
    int r0 = blockIdx.x * chunk;
    int r1 = min(r0 + chunk, nRows);
    float s = 0.f, s2 = 0.f;
    for (int r = r0 + half; r < r1; r += 2) {
        float v = h[(long)r * 128 + col];
        s += v;
        s2 = fmaf(v, v, s2);
    }
    __shared__ float l1[256], l2[256];
    l1[threadIdx.x] = s;
    l2[threadIdx.x] = s2;
    __syncthreads();
    if (half == 0) {
        s = l1[threadIdx.x] + l1[threadIdx.x + 128];
        s2 = l2[threadIdx.x] + l2[threadIdx.x + 128];
        atomicAdd(&sums[col], s);
        atomicAdd(&sums[128 + col], s2);
    }
}

__global__ void bnfin(const float* __restrict__ sums, const float* __restrict__ gamma,
                      const float* __restrict__ beta, float* __restrict__ bn_s,
                      float* __restrict__ bn_t, float invN) {
    int c = threadIdx.x;
    float mean = sums[c] * invN;
    float var = sums[128 + c] * invN - mean * mean;
    float rs = rsqrtf(var + BN_EPS);
    float s = gamma[c] * rs;
    bn_s[c] = s;
    bn_t[c] = beta[c] - mean * s;
}

// ---------------------------------------------------------------------------
// Global mean pool, stage 1: per-slice partial sums, atomicAdd into poolAcc.
// ---------------------------------------------------------------------------
__global__ __launch_bounds__(256) void pool_partial(
    const float* __restrict__ h, const int* __restrict__ batch,
    float* __restrict__ poolAcc, int nNodes) {
    int g = blockIdx.x / POOL_SLICES;
    int s = blockIdx.x % POOL_SLICES;
    int a = 0, b = nNodes;
    while (a < b) { int m = (a + b) >> 1; if (batch[m] < g) a = m + 1; else b = m; }
    int lo = a;
    b = nNodes;
    while (a < b) { int m = (a + b) >> 1; if (batch[m] < g + 1) a = m + 1; else b = m; }
    int hi = a;
    int len = hi - lo;
    int per = (len + POOL_SLICES - 1) / POOL_SLICES;
    int a0 = lo + s * per;
    int a1 = min(a0 + per, hi);
    if (a0 >= a1) return;
    int col = threadIdx.x & 127;
    int half = threadIdx.x >> 7;
    float acc = 0.f;
    for (int v = a0 + half; v < a1; v += 2) acc += h[(long)v * 128 + col];
    __shared__ float l[256];
    l[threadIdx.x] = acc;
    __syncthreads();
    if (half == 0) atomicAdd(&poolAcc[g * 128 + col], l[threadIdx.x] + l[threadIdx.x + 128]);
}

// ---------------------------------------------------------------------------
// MLP head: mean = poolAcc/cnt; relu(xg@Wg1+bg1) @ Wg2 + bg2 -> log_softmax
// ---------------------------------------------------------------------------
__global__ __launch_bounds__(128) void head_kernel(
    const float* __restrict__ poolAcc, const int* __restrict__ batch,
    const float* __restrict__ Wg1, const float* __restrict__ bg1,
    const float* __restrict__ Wg2, const float* __restrict__ bg2,
    float* __restrict__ out, int nNodes) {
    __shared__ float xr[128], tr[128], lg[N_CLASSES], red[2];
    int g = blockIdx.x, t = threadIdx.x;
    int a = 0, b = nNodes;
    while (a < b) { int m = (a + b) >> 1; if (batch[m] < g) a = m + 1; else b = m; }
    int lo = a;
    b = nNodes;
    while (a < b) { int m = (a + b) >> 1; if (batch[m] < g + 1) a = m + 1; else b = m; }
    float cntf = fmaxf((float)(a - lo), 1.0f);
    xr[t] = poolAcc[g * 128 + t] / cntf;
    __syncthreads();
    float s = bg1[t];
    for (int k = 0; k < 128; ++k) s = fmaf(xr[k], Wg1[k * 128 + t], s);
    tr[t] = fmaxf(s, 0.f);
    __syncthreads();
    if (t < N_CLASSES) {
        float s2 = bg2[t];
        for (int k = 0; k < 128; ++k) s2 = fmaf(tr[k], Wg2[k * N_CLASSES + t], s2);
        lg[t] = s2;
    }
    __syncthreads();
    if (t == 0) {
        float m = -1e30f;
        for (int j = 0; j < N_CLASSES; ++j) m = fmaxf(m, lg[j]);
        float se = 0.f;
        for (int j = 0; j < N_CLASSES; ++j) se += expf(lg[j] - m);
        red[0] = m;
        red[1] = logf(se);
    }
    __syncthreads();
    if (t < N_CLASSES) out[g * N_CLASSES + t] = lg[t] - red[0] - red[1];
}

// ---------------------------------------------------------------------------
extern "C" void kernel_launch(void* const* d_in, const int* in_sizes, int n_in,
                              void* d_out, int out_size, void* d_ws, size_t ws_size,
                              hipStream_t stream) {
    const float* x = (const float*)d_in[0];
    const int* edge = (const int*)d_in[1];
    const int* row = edge;
    const int* col = edge + N_EDGES;
    const int* batch = (const int*)d_in[2];
    const float* W0 = (const float*)d_in[3];
    const float* g0 = (const float*)d_in[4];
    const float* b0 = (const float*)d_in[5];
    const float* W1 = (const float*)d_in[6];
    const float* g1 = (const float*)d_in[7];
    const float* b1 = (const float*)d_in[8];
    const float* W2 = (const float*)d_in[9];
    const float* Wg1 = (const float*)d_in[10];
    const float* bg1 = (const float*)d_in[11];
    const float* Wg2 = (const float*)d_in[12];
    const float* bg2 = (const float*)d_in[13];
    float* out = (float*)d_out;

    char* p = (char*)d_ws;
    auto alloc = [&](size_t bytes) {
        void* r = (void*)p;
        p += (bytes + 255) & ~(size_t)255;
        return r;
    };
    float* bufA = (float*)alloc((size_t)N_NODES * 128 * 4);
    float* bufB = (float*)alloc((size_t)N_NODES * 128 * 4);
    float* dinv = (float*)alloc((size_t)N_NODES * 4);
    int* degcnt = (int*)alloc((size_t)N_NODES * 4);
    int* cnt = (int*)alloc((size_t)N_NODES * 4);
    int* rowptr = (int*)alloc((size_t)N_NODES * 4);
    int* wptr = (int*)alloc((size_t)N_NODES * 4);
    int* srcIdx = (int*)alloc((size_t)N_EDGES * 4);
    int* blockSums = (int*)alloc(1024 * 4);
    int* blockOffs = (int*)alloc(1024 * 4);
    float* bnacc = (float*)alloc(256 * 4);
    float* bn_s = (float*)alloc(128 * 4);
    float* bn_t = (float*)alloc(128 * 4);
    float* poolAcc = (float*)alloc(128 * 128 * 4);

    const int E = N_EDGES, N = N_NODES;
    const int scanBlocks = (N + 1023) / 1024;  // 98

    // --- degree + CSR (recomputed every call: deterministic work) ---
    hipMemsetAsync(degcnt, 0, (size_t)N * 4, stream);
    hipMemsetAsync(cnt, 0, (size_t)N * 4, stream);
    count_kernel<<<(E + 255) / 256, 256, 0, stream>>>(row, col, degcnt, cnt, E);
    dinv_kernel<<<(N + 255) / 256, 256, 0, stream>>>(degcnt, dinv, N);
    scanA<<<scanBlocks, 256, 0, stream>>>(cnt, rowptr, blockSums, N);
    scanB<<<1, 128, 0, stream>>>(blockSums, blockOffs, scanBlocks);
    scanC<<<(N + 255) / 256, 256, 0, stream>>>(rowptr, blockOffs, wptr, N);
    fill_kernel<<<(E + 255) / 256, 256, 0, stream>>>(row, col, wptr, srcIdx, E);

    const int gemmGrid = (N + 63) / 64;  // 1563
    const int aggGrid = (N + 3) / 4;     // 25000

    // --- layer 1 ---
    gemm128<<<gemmGrid, 256, 0, stream>>>(x, W0, nullptr, nullptr, bufA, N, 0);
    agg_kernel<<<aggGrid, 256, 0, stream>>>(bufA, rowptr, cnt, srcIdx, dinv, bufB, N);
    hipMemsetAsync(bnacc, 0, 256 * 4, stream);
    bnstats<<<512, 256, 0, stream>>>(bufB, bnacc, N);
    bnfin<<<1, 128, 0, stream>>>(bnacc, g0, b0, bn_s, bn_t, 1.0f / N);

    // --- layer 2 ---
    gemm128<<<gemmGrid, 256, 0, stream>>>(bufB, W1, bn_s, bn_t, bufA, N, 1);
    agg_kernel<<<aggGrid, 256, 0, stream>>>(bufA, rowptr, cnt, srcIdx, dinv, bufB, N);
    hipMemsetAsync(bnacc, 0, 256 * 4, stream);
    bnstats<<<512, 256, 0, stream>>>(bufB, bnacc, N);
    bnfin<<<1, 128, 0, stream>>>(bnacc, g1, b1, bn_s, bn_t, 1.0f / N);

    // --- layer 3 ---
    gemm128<<<gemmGrid, 256, 0, stream>>>(bufB, W2, bn_s, bn_t, bufA, N, 1);
    agg_kernel<<<aggGrid, 256, 0, stream>>>(bufA, rowptr, cnt, srcIdx, dinv, bufB, N);

    // --- pool (parallel partials) + head ---
    hipMemsetAsync(poolAcc, 0, 128 * 128 * 4, stream);
    pool_partial<<<N_GRAPHS * POOL_SLICES, 256, 0, stream>>>(bufB, batch, poolAcc, N);
    head_kernel<<<N_GRAPHS, 128, 0, stream>>>(poolAcc, batch, Wg1, bg1, Wg2, bg2, out, N);
}

// Round 5
// 540.887 us; speedup vs baseline: 2.6506x; 1.3168x over previous
//
#include <hip/hip_runtime.h>

#define N_NODES 100000
#define N_EDGES 640000
#define HID 128
#define N_CLASSES 40
#define N_GRAPHS 128
#define BN_EPS 1e-5f
#define POOL_SLICES 16

typedef __attribute__((ext_vector_type(8))) short bf16x8;
typedef __attribute__((ext_vector_type(4))) float f32x4;

// round-to-nearest-even f32 -> bf16 (as raw u16)
__device__ __forceinline__ unsigned short f2bf(float f) {
    unsigned u = __float_as_uint(f);
    u += 0x7FFFu + ((u >> 16) & 1u);
    return (unsigned short)(u >> 16);
}

// ---------------------------------------------------------------------------
// degree / CSR construction
// ---------------------------------------------------------------------------
__global__ void count_kernel(const int* __restrict__ row, const int* __restrict__ col,
                             int* degcnt, int* cnt, int E) {
    int e = blockIdx.x * 256 + threadIdx.x;
    if (e < E) {
        atomicAdd(&degcnt[row[e]], 1);
        atomicAdd(&cnt[col[e]], 1);
    }
}

__global__ void dinv_kernel(const int* __restrict__ degcnt, float* __restrict__ dinv, int n) {
    int i = blockIdx.x * 256 + threadIdx.x;
    if (i < n) dinv[i] = rsqrtf((float)degcnt[i] + 1.0f);
}

// block-level exclusive scan (1024 elements per block of 256 threads)
__global__ __launch_bounds__(256) void scanA(const int* __restrict__ cnt, int* __restrict__ rowptr,
                                             int* __restrict__ blockSums, int n) {
    __shared__ int sdata[256];
    int t = threadIdx.x;
    int base = blockIdx.x * 1024 + t * 4;
    int c[4];
#pragma unroll
    for (int j = 0; j < 4; ++j) c[j] = (base + j < n) ? cnt[base + j] : 0;
    int s = c[0] + c[1] + c[2] + c[3];
    sdata[t] = s;
    __syncthreads();
    for (int off = 1; off < 256; off <<= 1) {
        int v = (t >= off) ? sdata[t - off] : 0;
        __syncthreads();
        sdata[t] += v;
        __syncthreads();
    }
    int excl = sdata[t] - s;
    if (t == 255) blockSums[blockIdx.x] = sdata[255];
    int run = excl;
#pragma unroll
    for (int j = 0; j < 4; ++j) {
        if (base + j < n) rowptr[base + j] = run;
        run += c[j];
    }
}

__global__ void scanB(const int* __restrict__ blockSums, int* __restrict__ blockOffs, int nb) {
    __shared__ int sdata[128];
    int t = threadIdx.x;
    int v = (t < nb) ? blockSums[t] : 0;
    sdata[t] = v;
    __syncthreads();
    for (int off = 1; off < 128; off <<= 1) {
        int u = (t >= off) ? sdata[t - off] : 0;
        __syncthreads();
        sdata[t] += u;
        __syncthreads();
    }
    if (t < nb) blockOffs[t] = sdata[t] - v;
}

__global__ void scanC(int* __restrict__ rowptr, const int* __restrict__ blockOffs,
                      int* __restrict__ wptr, int n) {
    int i = blockIdx.x * 256 + threadIdx.x;
    if (i < n) {
        int v = rowptr[i] + blockOffs[i >> 10];
        rowptr[i] = v;
        wptr[i] = v;
    }
}

__global__ void fill_kernel(const int* __restrict__ row, const int* __restrict__ col,
                            int* wptr, int* __restrict__ srcIdx, int E) {
    int e = blockIdx.x * 256 + threadIdx.x;
    if (e < E) {
        int p = atomicAdd(&wptr[col[e]], 1);
        srcIdx[p] = row[e];
    }
}

// ---------------------------------------------------------------------------
// Pack W [128x128 f32, row-major k,n] -> bf16 fragment layout:
// Wb[(k>>3)*1024 + n*8 + (k&7)]. B-fragment for (k-group, col) is then one
// contiguous 16B load per lane. Total 32 KB -> L1-resident.
// ---------------------------------------------------------------------------
__global__ void packW(const float* __restrict__ W, unsigned short* __restrict__ Wb) {
    int idx = blockIdx.x * 256 + threadIdx.x;  // 0..16383
    int k = idx >> 7, n = idx & 127;
    Wb[(k >> 3) * 1024 + n * 8 + (k & 7)] = f2bf(W[k * 128 + n]);
}

// ---------------------------------------------------------------------------
// MFMA GEMM: out[N x 128] = f(in)[N x 128] @ W[128 x 128]
// f = identity or BN(scale,shift)+ReLU applied in f32 BEFORE bf16 rounding.
// Block 256 = 4 waves; wave computes 16 rows x 128 cols with
// mfma_f32_16x16x32_bf16 (8 col-tiles x 4 k-steps = 32 MFMA / wave).
// A-frag: lane l -> row (l&15), k = kk*32 + (l>>4)*8 + j (2x float4 loads).
// B-frag: lane l -> col n0+(l&15), same k range (one 16B load from Wb).
// D: col = lane&15, row = (lane>>4)*4 + reg  [guide §3, m89-verified].
// ---------------------------------------------------------------------------
__global__ __launch_bounds__(256) void gemm_mfma(
    const float* __restrict__ in, const unsigned short* __restrict__ Wb,
    const float* __restrict__ bn_s, const float* __restrict__ bn_t,
    float* __restrict__ out, int nRows, int useBN) {
    const int wave = threadIdx.x >> 6;
    const int lane = threadIdx.x & 63;
    const int lrow = lane & 15;   // A row within tile / B,D col within tile
    const int lk = lane >> 4;     // k-group 0..3
    const long rowA = (long)blockIdx.x * 64 + wave * 16 + lrow;
    const bool okA = rowA < (long)nRows;
    const float* rp = in + (okA ? rowA : 0) * 128;

    // build 4 A-fragments (k = 0..127 in slices of 32)
    bf16x8 afrag[4];
#pragma unroll
    for (int kk = 0; kk < 4; ++kk) {
        int k0 = kk * 32 + lk * 8;
        float4 v0, v1;
        if (okA) {
            v0 = *(const float4*)(rp + k0);
            v1 = *(const float4*)(rp + k0 + 4);
        } else {
            v0 = v1 = make_float4(0.f, 0.f, 0.f, 0.f);
        }
        if (useBN) {
            float4 s0 = *(const float4*)&bn_s[k0];
            float4 s1 = *(const float4*)&bn_s[k0 + 4];
            float4 t0 = *(const float4*)&bn_t[k0];
            float4 t1 = *(const float4*)&bn_t[k0 + 4];
            v0.x = fmaxf(fmaf(v0.x, s0.x, t0.x), 0.f);
            v0.y = fmaxf(fmaf(v0.y, s0.y, t0.y), 0.f);
            v0.z = fmaxf(fmaf(v0.z, s0.z, t0.z), 0.f);
            v0.w = fmaxf(fmaf(v0.w, s0.w, t0.w), 0.f);
            v1.x = fmaxf(fmaf(v1.x, s1.x, t1.x), 0.f);
            v1.y = fmaxf(fmaf(v1.y, s1.y, t1.y), 0.f);
            v1.z = fmaxf(fmaf(v1.z, s1.z, t1.z), 0.f);
            v1.w = fmaxf(fmaf(v1.w, s1.w, t1.w), 0.f);
        }
        bf16x8 a;
        a[0] = (short)f2bf(v0.x); a[1] = (short)f2bf(v0.y);
        a[2] = (short)f2bf(v0.z); a[3] = (short)f2bf(v0.w);
        a[4] = (short)f2bf(v1.x); a[5] = (short)f2bf(v1.y);
        a[6] = (short)f2bf(v1.z); a[7] = (short)f2bf(v1.w);
        afrag[kk] = a;
    }

    // 8 column tiles of 16
    f32x4 acc[8];
#pragma unroll
    for (int nt = 0; nt < 8; ++nt) acc[nt] = (f32x4){0.f, 0.f, 0.f, 0.f};

#pragma unroll
    for (int nt = 0; nt < 8; ++nt) {
        const unsigned short* wp = Wb + lk * 1024 + (nt * 16 + lrow) * 8;
#pragma unroll
        for (int kk = 0; kk < 4; ++kk) {
            bf16x8 b = *(const bf16x8*)(wp + kk * 4096);
            acc[nt] = __builtin_amdgcn_mfma_f32_16x16x32_bf16(afrag[kk], b, acc[nt], 0, 0, 0);
        }
    }

    // write-out: lane holds rows lk*4+r, col nt*16+lrow
    const long rowD0 = (long)blockIdx.x * 64 + wave * 16 + lk * 4;
#pragma unroll
    for (int r = 0; r < 4; ++r) {
        long rd = rowD0 + r;
        if (rd < nRows) {
            float* op = out + rd * 128 + lrow;
#pragma unroll
            for (int nt = 0; nt < 8; ++nt) op[nt * 16] = acc[nt][r];
        }
    }
}

// ---------------------------------------------------------------------------
// Aggregation: out[v] = dinv[v] * sum_{e in CSR(v)} dinv[src_e] * h[src_e]
// One wave (64 lanes) per node; lane holds 2 features (float2). No atomics.
// ---------------------------------------------------------------------------
__global__ __launch_bounds__(256) void agg_kernel(
    const float* __restrict__ h, const int* __restrict__ rowptr,
    const int* __restrict__ cnt, const int* __restrict__ srcIdx,
    const float* __restrict__ dinv, float* __restrict__ out, int nNodes) {
    int wave = threadIdx.x >> 6;
    int lane = threadIdx.x & 63;
    int v = blockIdx.x * 4 + wave;
    if (v >= nNodes) return;
    int start = rowptr[v];
    int n = cnt[v];
    float ax = 0.f, ay = 0.f;
    for (int e = 0; e < n; ++e) {
        int src = srcIdx[start + e];
        float w = dinv[src];
        float2 hv = *(const float2*)&h[(long)src * 128 + lane * 2];
        ax = fmaf(w, hv.x, ax);
        ay = fmaf(w, hv.y, ay);
    }
    float dv = dinv[v];
    *(float2*)&out[(long)v * 128 + lane * 2] = make_float2(ax * dv, ay * dv);
}

// ---------------------------------------------------------------------------
// BN statistics: per-column sum and sum-of-squares via block partials + atomics
// ---------------------------------------------------------------------------
__global__ __launch_bounds__(256) void bnstats(const float* __restrict__ h,
                                               float* __restrict__ sums, int nRows) {
    int col = threadIdx.x & 127;
    int half = threadIdx.x >> 7;
    int chunk = (nRows + gridDim.x - 1) / gridDim.x;
    int r0 = blockIdx.x * chunk;
    int r1 = min(r0 + chunk, nRows);
    float s = 0.f, s2 = 0.f;
    for (int r = r0 + half; r < r1; r += 2) {
        float v = h[(long)r * 128 + col];
        s += v;
        s2 = fmaf(v, v, s2);
    }
    __shared__ float l1[256], l2[256];
    l1[threadIdx.x] = s;
    l2[threadIdx.x] = s2;
    __syncthreads();
    if (half == 0) {
        s = l1[threadIdx.x] + l1[threadIdx.x + 128];
        s2 = l2[threadIdx.x] + l2[threadIdx.x + 128];
        atomicAdd(&sums[col], s);
        atomicAdd(&sums[128 + col], s2);
    }
}

__global__ void bnfin(const float* __restrict__ sums, const float* __restrict__ gamma,
                      const float* __restrict__ beta, float* __restrict__ bn_s,
                      float* __restrict__ bn_t, float invN) {
    int c = threadIdx.x;
    float mean = sums[c] * invN;
    float var = sums[128 + c] * invN - mean * mean;
    float rs = rsqrtf(var + BN_EPS);
    float s = gamma[c] * rs;
    bn_s[c] = s;
    bn_t[c] = beta[c] - mean * s;
}

// ---------------------------------------------------------------------------
// Global mean pool, stage 1: per-slice partial sums, atomicAdd into poolAcc.
// ---------------------------------------------------------------------------
__global__ __launch_bounds__(256) void pool_partial(
    const float* __restrict__ h, const int* __restrict__ batch,
    float* __restrict__ poolAcc, int nNodes) {
    int g = blockIdx.x / POOL_SLICES;
    int s = blockIdx.x % POOL_SLICES;
    int a = 0, b = nNodes;
    while (a < b) { int m = (a + b) >> 1; if (batch[m] < g) a = m + 1; else b = m; }
    int lo = a;
    b = nNodes;
    while (a < b) { int m = (a + b) >> 1; if (batch[m] < g + 1) a = m + 1; else b = m; }
    int hi = a;
    int len = hi - lo;
    int per = (len + POOL_SLICES - 1) / POOL_SLICES;
    int a0 = lo + s * per;
    int a1 = min(a0 + per, hi);
    if (a0 >= a1) return;
    int col = threadIdx.x & 127;
    int half = threadIdx.x >> 7;
    float acc = 0.f;
    for (int v = a0 + half; v < a1; v += 2) acc += h[(long)v * 128 + col];
    __shared__ float l[256];
    l[threadIdx.x] = acc;
    __syncthreads();
    if (half == 0) atomicAdd(&poolAcc[g * 128 + col], l[threadIdx.x] + l[threadIdx.x + 128]);
}

// ---------------------------------------------------------------------------
// MLP head: mean = poolAcc/cnt; relu(xg@Wg1+bg1) @ Wg2 + bg2 -> log_softmax
// ---------------------------------------------------------------------------
__global__ __launch_bounds__(128) void head_kernel(
    const float* __restrict__ poolAcc, const int* __restrict__ batch,
    const float* __restrict__ Wg1, const float* __restrict__ bg1,
    const float* __restrict__ Wg2, const float* __restrict__ bg2,
    float* __restrict__ out, int nNodes) {
    __shared__ float xr[128], tr[128], lg[N_CLASSES], red[2];
    int g = blockIdx.x, t = threadIdx.x;
    int a = 0, b = nNodes;
    while (a < b) { int m = (a + b) >> 1; if (batch[m] < g) a = m + 1; else b = m; }
    int lo = a;
    b = nNodes;
    while (a < b) { int m = (a + b) >> 1; if (batch[m] < g + 1) a = m + 1; else b = m; }
    float cntf = fmaxf((float)(a - lo), 1.0f);
    xr[t] = poolAcc[g * 128 + t] / cntf;
    __syncthreads();
    float s = bg1[t];
    for (int k = 0; k < 128; ++k) s = fmaf(xr[k], Wg1[k * 128 + t], s);
    tr[t] = fmaxf(s, 0.f);
    __syncthreads();
    if (t < N_CLASSES) {
        float s2 = bg2[t];
        for (int k = 0; k < 128; ++k) s2 = fmaf(tr[k], Wg2[k * N_CLASSES + t], s2);
        lg[t] = s2;
    }
    __syncthreads();
    if (t == 0) {
        float m = -1e30f;
        for (int j = 0; j < N_CLASSES; ++j) m = fmaxf(m, lg[j]);
        float se = 0.f;
        for (int j = 0; j < N_CLASSES; ++j) se += expf(lg[j] - m);
        red[0] = m;
        red[1] = logf(se);
    }
    __syncthreads();
    if (t < N_CLASSES) out[g * N_CLASSES + t] = lg[t] - red[0] - red[1];
}

// ---------------------------------------------------------------------------
extern "C" void kernel_launch(void* const* d_in, const int* in_sizes, int n_in,
                              void* d_out, int out_size, void* d_ws, size_t ws_size,
                              hipStream_t stream) {
    const float* x = (const float*)d_in[0];
    const int* edge = (const int*)d_in[1];
    const int* row = edge;
    const int* col = edge + N_EDGES;
    const int* batch = (const int*)d_in[2];
    const float* W0 = (const float*)d_in[3];
    const float* g0 = (const float*)d_in[4];
    const float* b0 = (const float*)d_in[5];
    const float* W1 = (const float*)d_in[6];
    const float* g1 = (const float*)d_in[7];
    const float* b1 = (const float*)d_in[8];
    const float* W2 = (const float*)d_in[9];
    const float* Wg1 = (const float*)d_in[10];
    const float* bg1 = (const float*)d_in[11];
    const float* Wg2 = (const float*)d_in[12];
    const float* bg2 = (const float*)d_in[13];
    float* out = (float*)d_out;

    char* p = (char*)d_ws;
    auto alloc = [&](size_t bytes) {
        void* r = (void*)p;
        p += (bytes + 255) & ~(size_t)255;
        return r;
    };
    float* bufA = (float*)alloc((size_t)N_NODES * 128 * 4);
    float* bufB = (float*)alloc((size_t)N_NODES * 128 * 4);
    float* dinv = (float*)alloc((size_t)N_NODES * 4);
    int* degcnt = (int*)alloc((size_t)N_NODES * 4);
    int* cnt = (int*)alloc((size_t)N_NODES * 4);
    int* rowptr = (int*)alloc((size_t)N_NODES * 4);
    int* wptr = (int*)alloc((size_t)N_NODES * 4);
    int* srcIdx = (int*)alloc((size_t)N_EDGES * 4);
    int* blockSums = (int*)alloc(1024 * 4);
    int* blockOffs = (int*)alloc(1024 * 4);
    float* bnacc = (float*)alloc(256 * 4);
    float* bn_s = (float*)alloc(128 * 4);
    float* bn_t = (float*)alloc(128 * 4);
    float* poolAcc = (float*)alloc(128 * 128 * 4);
    unsigned short* Wb0 = (unsigned short*)alloc(128 * 128 * 2);
    unsigned short* Wb1 = (unsigned short*)alloc(128 * 128 * 2);
    unsigned short* Wb2 = (unsigned short*)alloc(128 * 128 * 2);

    const int E = N_EDGES, N = N_NODES;
    const int scanBlocks = (N + 1023) / 1024;  // 98

    // --- degree + CSR (recomputed every call: deterministic work) ---
    hipMemsetAsync(degcnt, 0, (size_t)N * 4, stream);
    hipMemsetAsync(cnt, 0, (size_t)N * 4, stream);
    count_kernel<<<(E + 255) / 256, 256, 0, stream>>>(row, col, degcnt, cnt, E);
    dinv_kernel<<<(N + 255) / 256, 256, 0, stream>>>(degcnt, dinv, N);
    scanA<<<scanBlocks, 256, 0, stream>>>(cnt, rowptr, blockSums, N);
    scanB<<<1, 128, 0, stream>>>(blockSums, blockOffs, scanBlocks);
    scanC<<<(N + 255) / 256, 256, 0, stream>>>(rowptr, blockOffs, wptr, N);
    fill_kernel<<<(E + 255) / 256, 256, 0, stream>>>(row, col, wptr, srcIdx, E);

    // --- pack weights to bf16 fragment layout (96 KB total, trivial) ---
    packW<<<64, 256, 0, stream>>>(W0, Wb0);
    packW<<<64, 256, 0, stream>>>(W1, Wb1);
    packW<<<64, 256, 0, stream>>>(W2, Wb2);

    const int gemmGrid = (N + 63) / 64;  // 1563
    const int aggGrid = (N + 3) / 4;     // 25000

    // --- layer 1 ---
    gemm_mfma<<<gemmGrid, 256, 0, stream>>>(x, Wb0, nullptr, nullptr, bufA, N, 0);
    agg_kernel<<<aggGrid, 256, 0, stream>>>(bufA, rowptr, cnt, srcIdx, dinv, bufB, N);
    hipMemsetAsync(bnacc, 0, 256 * 4, stream);
    bnstats<<<512, 256, 0, stream>>>(bufB, bnacc, N);
    bnfin<<<1, 128, 0, stream>>>(bnacc, g0, b0, bn_s, bn_t, 1.0f / N);

    // --- layer 2 ---
    gemm_mfma<<<gemmGrid, 256, 0, stream>>>(bufB, Wb1, bn_s, bn_t, bufA, N, 1);
    agg_kernel<<<aggGrid, 256, 0, stream>>>(bufA, rowptr, cnt, srcIdx, dinv, bufB, N);
    hipMemsetAsync(bnacc, 0, 256 * 4, stream);
    bnstats<<<512, 256, 0, stream>>>(bufB, bnacc, N);
    bnfin<<<1, 128, 0, stream>>>(bnacc, g1, b1, bn_s, bn_t, 1.0f / N);

    // --- layer 3 ---
    gemm_mfma<<<gemmGrid, 256, 0, stream>>>(bufB, Wb2, bn_s, bn_t, bufA, N, 1);
    agg_kernel<<<aggGrid, 256, 0, stream>>>(bufA, rowptr, cnt, srcIdx, dinv, bufB, N);

    // --- pool (parallel partials) + head ---
    hipMemsetAsync(poolAcc, 0, 128 * 128 * 4, stream);
    pool_partial<<<N_GRAPHS * POOL_SLICES, 256, 0, stream>>>(bufB, batch, poolAcc, N);
    head_kernel<<<N_GRAPHS, 128, 0, stream>>>(poolAcc, batch, Wg1, bg1, Wg2, bg2, out, N);
}

// Round 6
// 478.162 us; speedup vs baseline: 2.9983x; 1.1312x over previous
//
#include <hip/hip_runtime.h>

#define N_NODES 100000
#define N_EDGES 640000
#define HID 128
#define N_CLASSES 40
#define N_GRAPHS 128
#define BN_EPS 1e-5f
#define POOL_SLICES 16

typedef __attribute__((ext_vector_type(8))) short bf16x8;
typedef __attribute__((ext_vector_type(4))) float f32x4;

// round-to-nearest-even f32 -> bf16 (as raw u16)
__device__ __forceinline__ unsigned short f2bf(float f) {
    unsigned u = __float_as_uint(f);
    u += 0x7FFFu + ((u >> 16) & 1u);
    return (unsigned short)(u >> 16);
}

// ---------------------------------------------------------------------------
// degree / CSR construction
// ---------------------------------------------------------------------------
__global__ void count_kernel(const int* __restrict__ row, const int* __restrict__ col,
                             int* degcnt, int* cnt, int E) {
    int e = blockIdx.x * 256 + threadIdx.x;
    if (e < E) {
        atomicAdd(&degcnt[row[e]], 1);
        atomicAdd(&cnt[col[e]], 1);
    }
}

__global__ void dinv_kernel(const int* __restrict__ degcnt, float* __restrict__ dinv, int n) {
    int i = blockIdx.x * 256 + threadIdx.x;
    if (i < n) dinv[i] = rsqrtf((float)degcnt[i] + 1.0f);
}

// block-level exclusive scan (1024 elements per block of 256 threads)
__global__ __launch_bounds__(256) void scanA(const int* __restrict__ cnt, int* __restrict__ rowptr,
                                             int* __restrict__ blockSums, int n) {
    __shared__ int sdata[256];
    int t = threadIdx.x;
    int base = blockIdx.x * 1024 + t * 4;
    int c[4];
#pragma unroll
    for (int j = 0; j < 4; ++j) c[j] = (base + j < n) ? cnt[base + j] : 0;
    int s = c[0] + c[1] + c[2] + c[3];
    sdata[t] = s;
    __syncthreads();
    for (int off = 1; off < 256; off <<= 1) {
        int v = (t >= off) ? sdata[t - off] : 0;
        __syncthreads();
        sdata[t] += v;
        __syncthreads();
    }
    int excl = sdata[t] - s;
    if (t == 255) blockSums[blockIdx.x] = sdata[255];
    int run = excl;
#pragma unroll
    for (int j = 0; j < 4; ++j) {
        if (base + j < n) rowptr[base + j] = run;
        run += c[j];
    }
}

__global__ void scanB(const int* __restrict__ blockSums, int* __restrict__ blockOffs, int nb) {
    __shared__ int sdata[128];
    int t = threadIdx.x;
    int v = (t < nb) ? blockSums[t] : 0;
    sdata[t] = v;
    __syncthreads();
    for (int off = 1; off < 128; off <<= 1) {
        int u = (t >= off) ? sdata[t - off] : 0;
        __syncthreads();
        sdata[t] += u;
        __syncthreads();
    }
    if (t < nb) blockOffs[t] = sdata[t] - v;
}

__global__ void scanC(int* __restrict__ rowptr, const int* __restrict__ blockOffs,
                      int* __restrict__ wptr, int n) {
    int i = blockIdx.x * 256 + threadIdx.x;
    if (i < n) {
        int v = rowptr[i] + blockOffs[i >> 10];
        rowptr[i] = v;
        wptr[i] = v;
    }
}

__global__ void fill_kernel(const int* __restrict__ row, const int* __restrict__ col,
                            int* wptr, int* __restrict__ srcIdx, int E) {
    int e = blockIdx.x * 256 + threadIdx.x;
    if (e < E) {
        int p = atomicAdd(&wptr[col[e]], 1);
        srcIdx[p] = row[e];
    }
}

// ---------------------------------------------------------------------------
// Pack W [128x128 f32, row-major k,n] -> bf16 fragment layout:
// Wb[(k>>3)*1024 + n*8 + (k&7)].
// ---------------------------------------------------------------------------
__global__ void packW(const float* __restrict__ W, unsigned short* __restrict__ Wb) {
    int idx = blockIdx.x * 256 + threadIdx.x;  // 0..16383
    int k = idx >> 7, n = idx & 127;
    Wb[(k >> 3) * 1024 + n * 8 + (k & 7)] = f2bf(W[k * 128 + n]);
}

// ---------------------------------------------------------------------------
// MFMA GEMM: out[N x 128] = f(in)[N x 128] @ W[128 x 128]
// f = identity or BN(scale,shift)+ReLU applied in f32 BEFORE bf16 rounding.
// ---------------------------------------------------------------------------
__global__ __launch_bounds__(256) void gemm_mfma(
    const float* __restrict__ in, const unsigned short* __restrict__ Wb,
    const float* __restrict__ bn_s, const float* __restrict__ bn_t,
    float* __restrict__ out, int nRows, int useBN) {
    const int wave = threadIdx.x >> 6;
    const int lane = threadIdx.x & 63;
    const int lrow = lane & 15;   // A row within tile / B,D col within tile
    const int lk = lane >> 4;     // k-group 0..3
    const long rowA = (long)blockIdx.x * 64 + wave * 16 + lrow;
    const bool okA = rowA < (long)nRows;
    const float* rp = in + (okA ? rowA : 0) * 128;

    bf16x8 afrag[4];
#pragma unroll
    for (int kk = 0; kk < 4; ++kk) {
        int k0 = kk * 32 + lk * 8;
        float4 v0, v1;
        if (okA) {
            v0 = *(const float4*)(rp + k0);
            v1 = *(const float4*)(rp + k0 + 4);
        } else {
            v0 = v1 = make_float4(0.f, 0.f, 0.f, 0.f);
        }
        if (useBN) {
            float4 s0 = *(const float4*)&bn_s[k0];
            float4 s1 = *(const float4*)&bn_s[k0 + 4];
            float4 t0 = *(const float4*)&bn_t[k0];
            float4 t1 = *(const float4*)&bn_t[k0 + 4];
            v0.x = fmaxf(fmaf(v0.x, s0.x, t0.x), 0.f);
            v0.y = fmaxf(fmaf(v0.y, s0.y, t0.y), 0.f);
            v0.z = fmaxf(fmaf(v0.z, s0.z, t0.z), 0.f);
            v0.w = fmaxf(fmaf(v0.w, s0.w, t0.w), 0.f);
            v1.x = fmaxf(fmaf(v1.x, s1.x, t1.x), 0.f);
            v1.y = fmaxf(fmaf(v1.y, s1.y, t1.y), 0.f);
            v1.z = fmaxf(fmaf(v1.z, s1.z, t1.z), 0.f);
            v1.w = fmaxf(fmaf(v1.w, s1.w, t1.w), 0.f);
        }
        bf16x8 a;
        a[0] = (short)f2bf(v0.x); a[1] = (short)f2bf(v0.y);
        a[2] = (short)f2bf(v0.z); a[3] = (short)f2bf(v0.w);
        a[4] = (short)f2bf(v1.x); a[5] = (short)f2bf(v1.y);
        a[6] = (short)f2bf(v1.z); a[7] = (short)f2bf(v1.w);
        afrag[kk] = a;
    }

    f32x4 acc[8];
#pragma unroll
    for (int nt = 0; nt < 8; ++nt) acc[nt] = (f32x4){0.f, 0.f, 0.f, 0.f};

#pragma unroll
    for (int nt = 0; nt < 8; ++nt) {
        const unsigned short* wp = Wb + lk * 1024 + (nt * 16 + lrow) * 8;
#pragma unroll
        for (int kk = 0; kk < 4; ++kk) {
            bf16x8 b = *(const bf16x8*)(wp + kk * 4096);
            acc[nt] = __builtin_amdgcn_mfma_f32_16x16x32_bf16(afrag[kk], b, acc[nt], 0, 0, 0);
        }
    }

    const long rowD0 = (long)blockIdx.x * 64 + wave * 16 + lk * 4;
#pragma unroll
    for (int r = 0; r < 4; ++r) {
        long rd = rowD0 + r;
        if (rd < nRows) {
            float* op = out + rd * 128 + lrow;
#pragma unroll
            for (int nt = 0; nt < 8; ++nt) op[nt * 16] = acc[nt][r];
        }
    }
}

// ---------------------------------------------------------------------------
// Aggregation: out[v] = dinv[v] * sum_{e in CSR(v)} dinv[src_e] * h[src_e]
// One wave per node. 4-way MLP: edges processed in predicated chunks of 4 so
// all srcIdx/dinv/h loads in a chunk are independent (latency-chain / 4).
// OOB slots re-load edge 0 with weight 0 (unconditional loads stay parallel).
// ---------------------------------------------------------------------------
__global__ __launch_bounds__(256) void agg_kernel(
    const float* __restrict__ h, const int* __restrict__ rowptr,
    const int* __restrict__ cnt, const int* __restrict__ srcIdx,
    const float* __restrict__ dinv, float* __restrict__ out, int nNodes) {
    int wave = threadIdx.x >> 6;
    int lane = threadIdx.x & 63;
    int v = blockIdx.x * 4 + wave;
    if (v >= nNodes) return;
    int start = rowptr[v];
    int n = cnt[v];
    float2 acc0 = make_float2(0.f, 0.f), acc1 = acc0, acc2 = acc0, acc3 = acc0;
    for (int e = 0; e < n; e += 4) {
        int i0 = start + e;
        int i1 = start + ((e + 1 < n) ? e + 1 : e);
        int i2 = start + ((e + 2 < n) ? e + 2 : e);
        int i3 = start + ((e + 3 < n) ? e + 3 : e);
        int s0 = srcIdx[i0], s1 = srcIdx[i1], s2 = srcIdx[i2], s3 = srcIdx[i3];
        float w0 = dinv[s0];
        float w1 = (e + 1 < n) ? dinv[s1] : 0.f;
        float w2 = (e + 2 < n) ? dinv[s2] : 0.f;
        float w3 = (e + 3 < n) ? dinv[s3] : 0.f;
        float2 h0 = *(const float2*)&h[(long)s0 * 128 + lane * 2];
        float2 h1 = *(const float2*)&h[(long)s1 * 128 + lane * 2];
        float2 h2 = *(const float2*)&h[(long)s2 * 128 + lane * 2];
        float2 h3 = *(const float2*)&h[(long)s3 * 128 + lane * 2];
        acc0.x = fmaf(w0, h0.x, acc0.x); acc0.y = fmaf(w0, h0.y, acc0.y);
        acc1.x = fmaf(w1, h1.x, acc1.x); acc1.y = fmaf(w1, h1.y, acc1.y);
        acc2.x = fmaf(w2, h2.x, acc2.x); acc2.y = fmaf(w2, h2.y, acc2.y);
        acc3.x = fmaf(w3, h3.x, acc3.x); acc3.y = fmaf(w3, h3.y, acc3.y);
    }
    float dv = dinv[v];
    float ox = ((acc0.x + acc1.x) + (acc2.x + acc3.x)) * dv;
    float oy = ((acc0.y + acc1.y) + (acc2.y + acc3.y)) * dv;
    *(float2*)&out[(long)v * 128 + lane * 2] = make_float2(ox, oy);
}

// ---------------------------------------------------------------------------
// BN statistics: per-column sum and sum-of-squares via block partials + atomics
// ---------------------------------------------------------------------------
__global__ __launch_bounds__(256) void bnstats(const float* __restrict__ h,
                                               float* __restrict__ sums, int nRows) {
    int col = threadIdx.x & 127;
    int half = threadIdx.x >> 7;
    int chunk = (nRows + gridDim.x - 1) / gridDim.x;
    int r0 = blockIdx.x * chunk;
    int r1 = min(r0 + chunk, nRows);
    float s = 0.f, s2 = 0.f;
    for (int r = r0 + half; r < r1; r += 2) {
        float v = h[(long)r * 128 + col];
        s += v;
        s2 = fmaf(v, v, s2);
    }
    __shared__ float l1[256], l2[256];
    l1[threadIdx.x] = s;
    l2[threadIdx.x] = s2;
    __syncthreads();
    if (half == 0) {
        s = l1[threadIdx.x] + l1[threadIdx.x + 128];
        s2 = l2[threadIdx.x] + l2[threadIdx.x + 128];
        atomicAdd(&sums[col], s);
        atomicAdd(&sums[128 + col], s2);
    }
}

__global__ void bnfin(const float* __restrict__ sums, const float* __restrict__ gamma,
                      const float* __restrict__ beta, float* __restrict__ bn_s,
                      float* __restrict__ bn_t, float invN) {
    int c = threadIdx.x;
    float mean = sums[c] * invN;
    float var = sums[128 + c] * invN - mean * mean;
    float rs = rsqrtf(var + BN_EPS);
    float s = gamma[c] * rs;
    bn_s[c] = s;
    bn_t[c] = beta[c] - mean * s;
}

// ---------------------------------------------------------------------------
// Global mean pool, stage 1: per-slice partial sums, atomicAdd into poolAcc.
// ---------------------------------------------------------------------------
__global__ __launch_bounds__(256) void pool_partial(
    const float* __restrict__ h, const int* __restrict__ batch,
    float* __restrict__ poolAcc, int nNodes) {
    int g = blockIdx.x / POOL_SLICES;
    int s = blockIdx.x % POOL_SLICES;
    int a = 0, b = nNodes;
    while (a < b) { int m = (a + b) >> 1; if (batch[m] < g) a = m + 1; else b = m; }
    int lo = a;
    b = nNodes;
    while (a < b) { int m = (a + b) >> 1; if (batch[m] < g + 1) a = m + 1; else b = m; }
    int hi = a;
    int len = hi - lo;
    int per = (len + POOL_SLICES - 1) / POOL_SLICES;
    int a0 = lo + s * per;
    int a1 = min(a0 + per, hi);
    if (a0 >= a1) return;
    int col = threadIdx.x & 127;
    int half = threadIdx.x >> 7;
    float acc = 0.f;
    for (int v = a0 + half; v < a1; v += 2) acc += h[(long)v * 128 + col];
    __shared__ float l[256];
    l[threadIdx.x] = acc;
    __syncthreads();
    if (half == 0) atomicAdd(&poolAcc[g * 128 + col], l[threadIdx.x] + l[threadIdx.x + 128]);
}

// ---------------------------------------------------------------------------
// MLP head: mean = poolAcc/cnt; relu(xg@Wg1+bg1) @ Wg2 + bg2 -> log_softmax
// ---------------------------------------------------------------------------
__global__ __launch_bounds__(128) void head_kernel(
    const float* __restrict__ poolAcc, const int* __restrict__ batch,
    const float* __restrict__ Wg1, const float* __restrict__ bg1,
    const float* __restrict__ Wg2, const float* __restrict__ bg2,
    float* __restrict__ out, int nNodes) {
    __shared__ float xr[128], tr[128], lg[N_CLASSES], red[2];
    int g = blockIdx.x, t = threadIdx.x;
    int a = 0, b = nNodes;
    while (a < b) { int m = (a + b) >> 1; if (batch[m] < g) a = m + 1; else b = m; }
    int lo = a;
    b = nNodes;
    while (a < b) { int m = (a + b) >> 1; if (batch[m] < g + 1) a = m + 1; else b = m; }
    float cntf = fmaxf((float)(a - lo), 1.0f);
    xr[t] = poolAcc[g * 128 + t] / cntf;
    __syncthreads();
    float s = bg1[t];
    for (int k = 0; k < 128; ++k) s = fmaf(xr[k], Wg1[k * 128 + t], s);
    tr[t] = fmaxf(s, 0.f);
    __syncthreads();
    if (t < N_CLASSES) {
        float s2 = bg2[t];
        for (int k = 0; k < 128; ++k) s2 = fmaf(tr[k], Wg2[k * N_CLASSES + t], s2);
        lg[t] = s2;
    }
    __syncthreads();
    if (t == 0) {
        float m = -1e30f;
        for (int j = 0; j < N_CLASSES; ++j) m = fmaxf(m, lg[j]);
        float se = 0.f;
        for (int j = 0; j < N_CLASSES; ++j) se += expf(lg[j] - m);
        red[0] = m;
        red[1] = logf(se);
    }
    __syncthreads();
    if (t < N_CLASSES) out[g * N_CLASSES + t] = lg[t] - red[0] - red[1];
}

// ---------------------------------------------------------------------------
extern "C" void kernel_launch(void* const* d_in, const int* in_sizes, int n_in,
                              void* d_out, int out_size, void* d_ws, size_t ws_size,
                              hipStream_t stream) {
    const float* x = (const float*)d_in[0];
    const int* edge = (const int*)d_in[1];
    const int* row = edge;
    const int* col = edge + N_EDGES;
    const int* batch = (const int*)d_in[2];
    const float* W0 = (const float*)d_in[3];
    const float* g0 = (const float*)d_in[4];
    const float* b0 = (const float*)d_in[5];
    const float* W1 = (const float*)d_in[6];
    const float* g1 = (const float*)d_in[7];
    const float* b1 = (const float*)d_in[8];
    const float* W2 = (const float*)d_in[9];
    const float* Wg1 = (const float*)d_in[10];
    const float* bg1 = (const float*)d_in[11];
    const float* Wg2 = (const float*)d_in[12];
    const float* bg2 = (const float*)d_in[13];
    float* out = (float*)d_out;

    char* p = (char*)d_ws;
    auto alloc = [&](size_t bytes) {
        void* r = (void*)p;
        p += (bytes + 255) & ~(size_t)255;
        return r;
    };
    float* bufA = (float*)alloc((size_t)N_NODES * 128 * 4);
    float* bufB = (float*)alloc((size_t)N_NODES * 128 * 4);
    float* dinv = (float*)alloc((size_t)N_NODES * 4);
    int* degcnt = (int*)alloc((size_t)N_NODES * 4);
    int* cnt = (int*)alloc((size_t)N_NODES * 4);
    int* rowptr = (int*)alloc((size_t)N_NODES * 4);
    int* wptr = (int*)alloc((size_t)N_NODES * 4);
    int* srcIdx = (int*)alloc((size_t)N_EDGES * 4);
    int* blockSums = (int*)alloc(1024 * 4);
    int* blockOffs = (int*)alloc(1024 * 4);
    float* bnacc = (float*)alloc(256 * 4);
    float* bn_s = (float*)alloc(128 * 4);
    float* bn_t = (float*)alloc(128 * 4);
    float* poolAcc = (float*)alloc(128 * 128 * 4);
    unsigned short* Wb0 = (unsigned short*)alloc(128 * 128 * 2);
    unsigned short* Wb1 = (unsigned short*)alloc(128 * 128 * 2);
    unsigned short* Wb2 = (unsigned short*)alloc(128 * 128 * 2);

    const int E = N_EDGES, N = N_NODES;
    const int scanBlocks = (N + 1023) / 1024;  // 98

    // --- degree + CSR (recomputed every call: deterministic work) ---
    hipMemsetAsync(degcnt, 0, (size_t)N * 4, stream);
    hipMemsetAsync(cnt, 0, (size_t)N * 4, stream);
    count_kernel<<<(E + 255) / 256, 256, 0, stream>>>(row, col, degcnt, cnt, E);
    dinv_kernel<<<(N + 255) / 256, 256, 0, stream>>>(degcnt, dinv, N);
    scanA<<<scanBlocks, 256, 0, stream>>>(cnt, rowptr, blockSums, N);
    scanB<<<1, 128, 0, stream>>>(blockSums, blockOffs, scanBlocks);
    scanC<<<(N + 255) / 256, 256, 0, stream>>>(rowptr, blockOffs, wptr, N);
    fill_kernel<<<(E + 255) / 256, 256, 0, stream>>>(row, col, wptr, srcIdx, E);

    // --- pack weights to bf16 fragment layout ---
    packW<<<64, 256, 0, stream>>>(W0, Wb0);
    packW<<<64, 256, 0, stream>>>(W1, Wb1);
    packW<<<64, 256, 0, stream>>>(W2, Wb2);

    const int gemmGrid = (N + 63) / 64;  // 1563
    const int aggGrid = (N + 3) / 4;     // 25000

    // --- layer 1 ---
    gemm_mfma<<<gemmGrid, 256, 0, stream>>>(x, Wb0, nullptr, nullptr, bufA, N, 0);
    agg_kernel<<<aggGrid, 256, 0, stream>>>(bufA, rowptr, cnt, srcIdx, dinv, bufB, N);
    hipMemsetAsync(bnacc, 0, 256 * 4, stream);
    bnstats<<<512, 256, 0, stream>>>(bufB, bnacc, N);
    bnfin<<<1, 128, 0, stream>>>(bnacc, g0, b0, bn_s, bn_t, 1.0f / N);

    // --- layer 2 ---
    gemm_mfma<<<gemmGrid, 256, 0, stream>>>(bufB, Wb1, bn_s, bn_t, bufA, N, 1);
    agg_kernel<<<aggGrid, 256, 0, stream>>>(bufA, rowptr, cnt, srcIdx, dinv, bufB, N);
    hipMemsetAsync(bnacc, 0, 256 * 4, stream);
    bnstats<<<512, 256, 0, stream>>>(bufB, bnacc, N);
    bnfin<<<1, 128, 0, stream>>>(bnacc, g1, b1, bn_s, bn_t, 1.0f / N);

    // --- layer 3 ---
    gemm_mfma<<<gemmGrid, 256, 0, stream>>>(bufB, Wb2, bn_s, bn_t, bufA, N, 1);
    agg_kernel<<<aggGrid, 256, 0, stream>>>(bufA, rowptr, cnt, srcIdx, dinv, bufB, N);

    // --- pool (parallel partials) + head ---
    hipMemsetAsync(poolAcc, 0, 128 * 128 * 4, stream);
    pool_partial<<<N_GRAPHS * POOL_SLICES, 256, 0, stream>>>(bufB, batch, poolAcc, N);
    head_kernel<<<N_GRAPHS, 128, 0, stream>>>(poolAcc, batch, Wg1, bg1, Wg2, bg2, out, N);
}

// Round 7
// 457.868 us; speedup vs baseline: 3.1312x; 1.0443x over previous
//
#include <hip/hip_runtime.h>

#define N_NODES 100000
#define N_EDGES 640000
#define HID 128
#define N_CLASSES 40
#define N_GRAPHS 128
#define BN_EPS 1e-5f
#define POOL_SLICES 16

typedef __attribute__((ext_vector_type(8))) short bf16x8;
typedef __attribute__((ext_vector_type(4))) float f32x4;

// round-to-nearest-even f32 -> bf16 (as raw u16)
__device__ __forceinline__ unsigned short f2bf(float f) {
    unsigned u = __float_as_uint(f);
    u += 0x7FFFu + ((u >> 16) & 1u);
    return (unsigned short)(u >> 16);
}

// ---------------------------------------------------------------------------
// degree / CSR construction
// ---------------------------------------------------------------------------
__global__ void count_kernel(const int* __restrict__ row, const int* __restrict__ col,
                             int* degcnt, int* cnt, int E) {
    int e = blockIdx.x * 256 + threadIdx.x;
    if (e < E) {
        atomicAdd(&degcnt[row[e]], 1);
        atomicAdd(&cnt[col[e]], 1);
    }
}

__global__ void dinv_kernel(const int* __restrict__ degcnt, float* __restrict__ dinv, int n) {
    int i = blockIdx.x * 256 + threadIdx.x;
    if (i < n) dinv[i] = rsqrtf((float)degcnt[i] + 1.0f);
}

// block-level exclusive scan (1024 elements per block of 256 threads)
__global__ __launch_bounds__(256) void scanA(const int* __restrict__ cnt, int* __restrict__ rowptr,
                                             int* __restrict__ blockSums, int n) {
    __shared__ int sdata[256];
    int t = threadIdx.x;
    int base = blockIdx.x * 1024 + t * 4;
    int c[4];
#pragma unroll
    for (int j = 0; j < 4; ++j) c[j] = (base + j < n) ? cnt[base + j] : 0;
    int s = c[0] + c[1] + c[2] + c[3];
    sdata[t] = s;
    __syncthreads();
    for (int off = 1; off < 256; off <<= 1) {
        int v = (t >= off) ? sdata[t - off] : 0;
        __syncthreads();
        sdata[t] += v;
        __syncthreads();
    }
    int excl = sdata[t] - s;
    if (t == 255) blockSums[blockIdx.x] = sdata[255];
    int run = excl;
#pragma unroll
    for (int j = 0; j < 4; ++j) {
        if (base + j < n) rowptr[base + j] = run;
        run += c[j];
    }
}

__global__ void scanB(const int* __restrict__ blockSums, int* __restrict__ blockOffs, int nb) {
    __shared__ int sdata[128];
    int t = threadIdx.x;
    int v = (t < nb) ? blockSums[t] : 0;
    sdata[t] = v;
    __syncthreads();
    for (int off = 1; off < 128; off <<= 1) {
        int u = (t >= off) ? sdata[t - off] : 0;
        __syncthreads();
        sdata[t] += u;
        __syncthreads();
    }
    if (t < nb) blockOffs[t] = sdata[t] - v;
}

__global__ void scanC(int* __restrict__ rowptr, const int* __restrict__ blockOffs,
                      int* __restrict__ wptr, int n) {
    int i = blockIdx.x * 256 + threadIdx.x;
    if (i < n) {
        int v = rowptr[i] + blockOffs[i >> 10];
        rowptr[i] = v;
        wptr[i] = v;
    }
}

__global__ void fill_kernel(const int* __restrict__ row, const int* __restrict__ col,
                            int* wptr, int* __restrict__ srcIdx, int E) {
    int e = blockIdx.x * 256 + threadIdx.x;
    if (e < E) {
        int p = atomicAdd(&wptr[col[e]], 1);
        srcIdx[p] = row[e];
    }
}

// ---------------------------------------------------------------------------
// Pack W [128x128 f32, row-major k,n] -> bf16 fragment layout:
// Wb[(k>>3)*1024 + n*8 + (k&7)].
// ---------------------------------------------------------------------------
__global__ void packW(const float* __restrict__ W, unsigned short* __restrict__ Wb) {
    int idx = blockIdx.x * 256 + threadIdx.x;  // 0..16383
    int k = idx >> 7, n = idx & 127;
    Wb[(k >> 3) * 1024 + n * 8 + (k & 7)] = f2bf(W[k * 128 + n]);
}

// ---------------------------------------------------------------------------
// MFMA GEMM: out_bf16[N x 128] = f(in)[N x 128] @ W[128 x 128]
// f = identity or BN(scale,shift)+ReLU applied in f32 BEFORE bf16 rounding.
// Output rounded to bf16 (halves agg gather + gemm write traffic).
// ---------------------------------------------------------------------------
__global__ __launch_bounds__(256) void gemm_mfma(
    const float* __restrict__ in, const unsigned short* __restrict__ Wb,
    const float* __restrict__ bn_s, const float* __restrict__ bn_t,
    unsigned short* __restrict__ out, int nRows, int useBN) {
    const int wave = threadIdx.x >> 6;
    const int lane = threadIdx.x & 63;
    const int lrow = lane & 15;   // A row within tile / B,D col within tile
    const int lk = lane >> 4;     // k-group 0..3
    const long rowA = (long)blockIdx.x * 64 + wave * 16 + lrow;
    const bool okA = rowA < (long)nRows;
    const float* rp = in + (okA ? rowA : 0) * 128;

    bf16x8 afrag[4];
#pragma unroll
    for (int kk = 0; kk < 4; ++kk) {
        int k0 = kk * 32 + lk * 8;
        float4 v0, v1;
        if (okA) {
            v0 = *(const float4*)(rp + k0);
            v1 = *(const float4*)(rp + k0 + 4);
        } else {
            v0 = v1 = make_float4(0.f, 0.f, 0.f, 0.f);
        }
        if (useBN) {
            float4 s0 = *(const float4*)&bn_s[k0];
            float4 s1 = *(const float4*)&bn_s[k0 + 4];
            float4 t0 = *(const float4*)&bn_t[k0];
            float4 t1 = *(const float4*)&bn_t[k0 + 4];
            v0.x = fmaxf(fmaf(v0.x, s0.x, t0.x), 0.f);
            v0.y = fmaxf(fmaf(v0.y, s0.y, t0.y), 0.f);
            v0.z = fmaxf(fmaf(v0.z, s0.z, t0.z), 0.f);
            v0.w = fmaxf(fmaf(v0.w, s0.w, t0.w), 0.f);
            v1.x = fmaxf(fmaf(v1.x, s1.x, t1.x), 0.f);
            v1.y = fmaxf(fmaf(v1.y, s1.y, t1.y), 0.f);
            v1.z = fmaxf(fmaf(v1.z, s1.z, t1.z), 0.f);
            v1.w = fmaxf(fmaf(v1.w, s1.w, t1.w), 0.f);
        }
        bf16x8 a;
        a[0] = (short)f2bf(v0.x); a[1] = (short)f2bf(v0.y);
        a[2] = (short)f2bf(v0.z); a[3] = (short)f2bf(v0.w);
        a[4] = (short)f2bf(v1.x); a[5] = (short)f2bf(v1.y);
        a[6] = (short)f2bf(v1.z); a[7] = (short)f2bf(v1.w);
        afrag[kk] = a;
    }

    f32x4 acc[8];
#pragma unroll
    for (int nt = 0; nt < 8; ++nt) acc[nt] = (f32x4){0.f, 0.f, 0.f, 0.f};

#pragma unroll
    for (int nt = 0; nt < 8; ++nt) {
        const unsigned short* wp = Wb + lk * 1024 + (nt * 16 + lrow) * 8;
#pragma unroll
        for (int kk = 0; kk < 4; ++kk) {
            bf16x8 b = *(const bf16x8*)(wp + kk * 4096);
            acc[nt] = __builtin_amdgcn_mfma_f32_16x16x32_bf16(afrag[kk], b, acc[nt], 0, 0, 0);
        }
    }

    const long rowD0 = (long)blockIdx.x * 64 + wave * 16 + lk * 4;
#pragma unroll
    for (int r = 0; r < 4; ++r) {
        long rd = rowD0 + r;
        if (rd < nRows) {
            unsigned short* op = out + rd * 128 + lrow;
#pragma unroll
            for (int nt = 0; nt < 8; ++nt) op[nt * 16] = f2bf(acc[nt][r]);
        }
    }
}

// ---------------------------------------------------------------------------
// Aggregation: out[v] = dinv[v] * sum_{e in CSR(v)} dinv[src_e] * h[src_e]
// h is bf16 (256 B/row gather, one uint = 2 cols per lane). 4-way MLP:
// chunks of 4 predicated edges, all loads independent. Accumulate f32.
// ---------------------------------------------------------------------------
__global__ __launch_bounds__(256) void agg_kernel(
    const unsigned short* __restrict__ h, const int* __restrict__ rowptr,
    const int* __restrict__ cnt, const int* __restrict__ srcIdx,
    const float* __restrict__ dinv, float* __restrict__ out, int nNodes) {
    int wave = threadIdx.x >> 6;
    int lane = threadIdx.x & 63;
    int v = blockIdx.x * 4 + wave;
    if (v >= nNodes) return;
    int start = rowptr[v];
    int n = cnt[v];
    float2 acc0 = make_float2(0.f, 0.f), acc1 = acc0, acc2 = acc0, acc3 = acc0;
    for (int e = 0; e < n; e += 4) {
        int i0 = start + e;
        int i1 = start + ((e + 1 < n) ? e + 1 : e);
        int i2 = start + ((e + 2 < n) ? e + 2 : e);
        int i3 = start + ((e + 3 < n) ? e + 3 : e);
        int s0 = srcIdx[i0], s1 = srcIdx[i1], s2 = srcIdx[i2], s3 = srcIdx[i3];
        float w0 = dinv[s0];
        float w1 = (e + 1 < n) ? dinv[s1] : 0.f;
        float w2 = (e + 2 < n) ? dinv[s2] : 0.f;
        float w3 = (e + 3 < n) ? dinv[s3] : 0.f;
        unsigned u0 = *(const unsigned*)&h[(long)s0 * 128 + lane * 2];
        unsigned u1 = *(const unsigned*)&h[(long)s1 * 128 + lane * 2];
        unsigned u2 = *(const unsigned*)&h[(long)s2 * 128 + lane * 2];
        unsigned u3 = *(const unsigned*)&h[(long)s3 * 128 + lane * 2];
        acc0.x = fmaf(w0, __uint_as_float(u0 << 16), acc0.x);
        acc0.y = fmaf(w0, __uint_as_float(u0 & 0xFFFF0000u), acc0.y);
        acc1.x = fmaf(w1, __uint_as_float(u1 << 16), acc1.x);
        acc1.y = fmaf(w1, __uint_as_float(u1 & 0xFFFF0000u), acc1.y);
        acc2.x = fmaf(w2, __uint_as_float(u2 << 16), acc2.x);
        acc2.y = fmaf(w2, __uint_as_float(u2 & 0xFFFF0000u), acc2.y);
        acc3.x = fmaf(w3, __uint_as_float(u3 << 16), acc3.x);
        acc3.y = fmaf(w3, __uint_as_float(u3 & 0xFFFF0000u), acc3.y);
    }
    float dv = dinv[v];
    float ox = ((acc0.x + acc1.x) + (acc2.x + acc3.x)) * dv;
    float oy = ((acc0.y + acc1.y) + (acc2.y + acc3.y)) * dv;
    *(float2*)&out[(long)v * 128 + lane * 2] = make_float2(ox, oy);
}

// ---------------------------------------------------------------------------
// BN statistics: per-column sum and sum-of-squares via block partials + atomics
// ---------------------------------------------------------------------------
__global__ __launch_bounds__(256) void bnstats(const float* __restrict__ h,
                                               float* __restrict__ sums, int nRows) {
    int col = threadIdx.x & 127;
    int half = threadIdx.x >> 7;
    int chunk = (nRows + gridDim.x - 1) / gridDim.x;
    int r0 = blockIdx.x * chunk;
    int r1 = min(r0 + chunk, nRows);
    float s = 0.f, s2 = 0.f;
    for (int r = r0 + half; r < r1; r += 2) {
        float v = h[(long)r * 128 + col];
        s += v;
        s2 = fmaf(v, v, s2);
    }
    __shared__ float l1[256], l2[256];
    l1[threadIdx.x] = s;
    l2[threadIdx.x] = s2;
    __syncthreads();
    if (half == 0) {
        s = l1[threadIdx.x] + l1[threadIdx.x + 128];
        s2 = l2[threadIdx.x] + l2[threadIdx.x + 128];
        atomicAdd(&sums[col], s);
        atomicAdd(&sums[128 + col], s2);
    }
}

__global__ void bnfin(const float* __restrict__ sums, const float* __restrict__ gamma,
                      const float* __restrict__ beta, float* __restrict__ bn_s,
                      float* __restrict__ bn_t, float invN) {
    int c = threadIdx.x;
    float mean = sums[c] * invN;
    float var = sums[128 + c] * invN - mean * mean;
    float rs = rsqrtf(var + BN_EPS);
    float s = gamma[c] * rs;
    bn_s[c] = s;
    bn_t[c] = beta[c] - mean * s;
}

// ---------------------------------------------------------------------------
// Global mean pool, stage 1: per-slice partial sums, atomicAdd into poolAcc.
// ---------------------------------------------------------------------------
__global__ __launch_bounds__(256) void pool_partial(
    const float* __restrict__ h, const int* __restrict__ batch,
    float* __restrict__ poolAcc, int nNodes) {
    int g = blockIdx.x / POOL_SLICES;
    int s = blockIdx.x % POOL_SLICES;
    int a = 0, b = nNodes;
    while (a < b) { int m = (a + b) >> 1; if (batch[m] < g) a = m + 1; else b = m; }
    int lo = a;
    b = nNodes;
    while (a < b) { int m = (a + b) >> 1; if (batch[m] < g + 1) a = m + 1; else b = m; }
    int hi = a;
    int len = hi - lo;
    int per = (len + POOL_SLICES - 1) / POOL_SLICES;
    int a0 = lo + s * per;
    int a1 = min(a0 + per, hi);
    if (a0 >= a1) return;
    int col = threadIdx.x & 127;
    int half = threadIdx.x >> 7;
    float acc = 0.f;
    for (int v = a0 + half; v < a1; v += 2) acc += h[(long)v * 128 + col];
    __shared__ float l[256];
    l[threadIdx.x] = acc;
    __syncthreads();
    if (half == 0) atomicAdd(&poolAcc[g * 128 + col], l[threadIdx.x] + l[threadIdx.x + 128]);
}

// ---------------------------------------------------------------------------
// MLP head: mean = poolAcc/cnt; relu(xg@Wg1+bg1) @ Wg2 + bg2 -> log_softmax
// ---------------------------------------------------------------------------
__global__ __launch_bounds__(128) void head_kernel(
    const float* __restrict__ poolAcc, const int* __restrict__ batch,
    const float* __restrict__ Wg1, const float* __restrict__ bg1,
    const float* __restrict__ Wg2, const float* __restrict__ bg2,
    float* __restrict__ out, int nNodes) {
    __shared__ float xr[128], tr[128], lg[N_CLASSES], red[2];
    int g = blockIdx.x, t = threadIdx.x;
    int a = 0, b = nNodes;
    while (a < b) { int m = (a + b) >> 1; if (batch[m] < g) a = m + 1; else b = m; }
    int lo = a;
    b = nNodes;
    while (a < b) { int m = (a + b) >> 1; if (batch[m] < g + 1) a = m + 1; else b = m; }
    float cntf = fmaxf((float)(a - lo), 1.0f);
    xr[t] = poolAcc[g * 128 + t] / cntf;
    __syncthreads();
    float s = bg1[t];
    for (int k = 0; k < 128; ++k) s = fmaf(xr[k], Wg1[k * 128 + t], s);
    tr[t] = fmaxf(s, 0.f);
    __syncthreads();
    if (t < N_CLASSES) {
        float s2 = bg2[t];
        for (int k = 0; k < 128; ++k) s2 = fmaf(tr[k], Wg2[k * N_CLASSES + t], s2);
        lg[t] = s2;
    }
    __syncthreads();
    if (t == 0) {
        float m = -1e30f;
        for (int j = 0; j < N_CLASSES; ++j) m = fmaxf(m, lg[j]);
        float se = 0.f;
        for (int j = 0; j < N_CLASSES; ++j) se += expf(lg[j] - m);
        red[0] = m;
        red[1] = logf(se);
    }
    __syncthreads();
    if (t < N_CLASSES) out[g * N_CLASSES + t] = lg[t] - red[0] - red[1];
}

// ---------------------------------------------------------------------------
extern "C" void kernel_launch(void* const* d_in, const int* in_sizes, int n_in,
                              void* d_out, int out_size, void* d_ws, size_t ws_size,
                              hipStream_t stream) {
    const float* x = (const float*)d_in[0];
    const int* edge = (const int*)d_in[1];
    const int* row = edge;
    const int* col = edge + N_EDGES;
    const int* batch = (const int*)d_in[2];
    const float* W0 = (const float*)d_in[3];
    const float* g0 = (const float*)d_in[4];
    const float* b0 = (const float*)d_in[5];
    const float* W1 = (const float*)d_in[6];
    const float* g1 = (const float*)d_in[7];
    const float* b1 = (const float*)d_in[8];
    const float* W2 = (const float*)d_in[9];
    const float* Wg1 = (const float*)d_in[10];
    const float* bg1 = (const float*)d_in[11];
    const float* Wg2 = (const float*)d_in[12];
    const float* bg2 = (const float*)d_in[13];
    float* out = (float*)d_out;

    char* p = (char*)d_ws;
    auto alloc = [&](size_t bytes) {
        void* r = (void*)p;
        p += (bytes + 255) & ~(size_t)255;
        return r;
    };
    unsigned short* bufA = (unsigned short*)alloc((size_t)N_NODES * 128 * 2);  // bf16 h
    float* bufB = (float*)alloc((size_t)N_NODES * 128 * 4);                    // f32 agg out
    float* dinv = (float*)alloc((size_t)N_NODES * 4);
    int* degcnt = (int*)alloc((size_t)N_NODES * 4);
    int* cnt = (int*)alloc((size_t)N_NODES * 4);
    int* rowptr = (int*)alloc((size_t)N_NODES * 4);
    int* wptr = (int*)alloc((size_t)N_NODES * 4);
    int* srcIdx = (int*)alloc((size_t)N_EDGES * 4);
    int* blockSums = (int*)alloc(1024 * 4);
    int* blockOffs = (int*)alloc(1024 * 4);
    float* bnacc = (float*)alloc(256 * 4);
    float* bn_s = (float*)alloc(128 * 4);
    float* bn_t = (float*)alloc(128 * 4);
    float* poolAcc = (float*)alloc(128 * 128 * 4);
    unsigned short* Wb0 = (unsigned short*)alloc(128 * 128 * 2);
    unsigned short* Wb1 = (unsigned short*)alloc(128 * 128 * 2);
    unsigned short* Wb2 = (unsigned short*)alloc(128 * 128 * 2);

    const int E = N_EDGES, N = N_NODES;
    const int scanBlocks = (N + 1023) / 1024;  // 98

    // --- degree + CSR (recomputed every call: deterministic work) ---
    hipMemsetAsync(degcnt, 0, (size_t)N * 4, stream);
    hipMemsetAsync(cnt, 0, (size_t)N * 4, stream);
    count_kernel<<<(E + 255) / 256, 256, 0, stream>>>(row, col, degcnt, cnt, E);
    dinv_kernel<<<(N + 255) / 256, 256, 0, stream>>>(degcnt, dinv, N);
    scanA<<<scanBlocks, 256, 0, stream>>>(cnt, rowptr, blockSums, N);
    scanB<<<1, 128, 0, stream>>>(blockSums, blockOffs, scanBlocks);
    scanC<<<(N + 255) / 256, 256, 0, stream>>>(rowptr, blockOffs, wptr, N);
    fill_kernel<<<(E + 255) / 256, 256, 0, stream>>>(row, col, wptr, srcIdx, E);

    // --- pack weights to bf16 fragment layout ---
    packW<<<64, 256, 0, stream>>>(W0, Wb0);
    packW<<<64, 256, 0, stream>>>(W1, Wb1);
    packW<<<64, 256, 0, stream>>>(W2, Wb2);

    const int gemmGrid = (N + 63) / 64;  // 1563
    const int aggGrid = (N + 3) / 4;     // 25000

    // --- layer 1 ---
    gemm_mfma<<<gemmGrid, 256, 0, stream>>>(x, Wb0, nullptr, nullptr, bufA, N, 0);
    agg_kernel<<<aggGrid, 256, 0, stream>>>(bufA, rowptr, cnt, srcIdx, dinv, bufB, N);
    hipMemsetAsync(bnacc, 0, 256 * 4, stream);
    bnstats<<<512, 256, 0, stream>>>(bufB, bnacc, N);
    bnfin<<<1, 128, 0, stream>>>(bnacc, g0, b0, bn_s, bn_t, 1.0f / N);

    // --- layer 2 ---
    gemm_mfma<<<gemmGrid, 256, 0, stream>>>(bufB, Wb1, bn_s, bn_t, bufA, N, 1);
    agg_kernel<<<aggGrid, 256, 0, stream>>>(bufA, rowptr, cnt, srcIdx, dinv, bufB, N);
    hipMemsetAsync(bnacc, 0, 256 * 4, stream);
    bnstats<<<512, 256, 0, stream>>>(bufB, bnacc, N);
    bnfin<<<1, 128, 0, stream>>>(bnacc, g1, b1, bn_s, bn_t, 1.0f / N);

    // --- layer 3 ---
    gemm_mfma<<<gemmGrid, 256, 0, stream>>>(bufB, Wb2, bn_s, bn_t, bufA, N, 1);
    agg_kernel<<<aggGrid, 256, 0, stream>>>(bufA, rowptr, cnt, srcIdx, dinv, bufB, N);

    // --- pool (parallel partials) + head ---
    hipMemsetAsync(poolAcc, 0, 128 * 128 * 4, stream);
    pool_partial<<<N_GRAPHS * POOL_SLICES, 256, 0, stream>>>(bufB, batch, poolAcc, N);
    head_kernel<<<N_GRAPHS, 128, 0, stream>>>(poolAcc, batch, Wg1, bg1, Wg2, bg2, out, N);
}

// Round 8
// 432.096 us; speedup vs baseline: 3.3179x; 1.0596x over previous
//
#include <hip/hip_runtime.h>

#define N_NODES 100000
#define N_EDGES 640000
#define HID 128
#define N_CLASSES 40
#define N_GRAPHS 128
#define BN_EPS 1e-5f
#define POOL_SLICES 16

typedef __attribute__((ext_vector_type(8))) short bf16x8;
typedef __attribute__((ext_vector_type(4))) float f32x4;

// round-to-nearest-even f32 -> bf16 (as raw u16)
__device__ __forceinline__ unsigned short f2bf(float f) {
    unsigned u = __float_as_uint(f);
    u += 0x7FFFu + ((u >> 16) & 1u);
    return (unsigned short)(u >> 16);
}

__device__ __forceinline__ float bflo(unsigned u) { return __uint_as_float(u << 16); }
__device__ __forceinline__ float bfhi(unsigned u) { return __uint_as_float(u & 0xFFFF0000u); }

// ---------------------------------------------------------------------------
// degree / CSR construction
// ---------------------------------------------------------------------------
__global__ void count_kernel(const int* __restrict__ row, const int* __restrict__ col,
                             int* degcnt, int* cnt, int E) {
    int e = blockIdx.x * 256 + threadIdx.x;
    if (e < E) {
        atomicAdd(&degcnt[row[e]], 1);
        atomicAdd(&cnt[col[e]], 1);
    }
}

__global__ void dinv_kernel(const int* __restrict__ degcnt, float* __restrict__ dinv, int n) {
    int i = blockIdx.x * 256 + threadIdx.x;
    if (i < n) dinv[i] = rsqrtf((float)degcnt[i] + 1.0f);
}

// block-level exclusive scan (1024 elements per block of 256 threads)
__global__ __launch_bounds__(256) void scanA(const int* __restrict__ cnt, int* __restrict__ rowptr,
                                             int* __restrict__ blockSums, int n) {
    __shared__ int sdata[256];
    int t = threadIdx.x;
    int base = blockIdx.x * 1024 + t * 4;
    int c[4];
#pragma unroll
    for (int j = 0; j < 4; ++j) c[j] = (base + j < n) ? cnt[base + j] : 0;
    int s = c[0] + c[1] + c[2] + c[3];
    sdata[t] = s;
    __syncthreads();
    for (int off = 1; off < 256; off <<= 1) {
        int v = (t >= off) ? sdata[t - off] : 0;
        __syncthreads();
        sdata[t] += v;
        __syncthreads();
    }
    int excl = sdata[t] - s;
    if (t == 255) blockSums[blockIdx.x] = sdata[255];
    int run = excl;
#pragma unroll
    for (int j = 0; j < 4; ++j) {
        if (base + j < n) rowptr[base + j] = run;
        run += c[j];
    }
}

__global__ void scanB(const int* __restrict__ blockSums, int* __restrict__ blockOffs, int nb) {
    __shared__ int sdata[128];
    int t = threadIdx.x;
    int v = (t < nb) ? blockSums[t] : 0;
    sdata[t] = v;
    __syncthreads();
    for (int off = 1; off < 128; off <<= 1) {
        int u = (t >= off) ? sdata[t - off] : 0;
        __syncthreads();
        sdata[t] += u;
        __syncthreads();
    }
    if (t < nb) blockOffs[t] = sdata[t] - v;
}

__global__ void scanC(int* __restrict__ rowptr, const int* __restrict__ blockOffs,
                      int* __restrict__ wptr, int n) {
    int i = blockIdx.x * 256 + threadIdx.x;
    if (i < n) {
        int v = rowptr[i] + blockOffs[i >> 10];
        rowptr[i] = v;
        wptr[i] = v;
    }
}

__global__ void fill_kernel(const int* __restrict__ row, const int* __restrict__ col,
                            int* wptr, int* __restrict__ srcIdx, int E) {
    int e = blockIdx.x * 256 + threadIdx.x;
    if (e < E) {
        int p = atomicAdd(&wptr[col[e]], 1);
        srcIdx[p] = row[e];
    }
}

// ---------------------------------------------------------------------------
// Pack W [128x128 f32, row-major k,n] -> bf16 fragment layout:
// Wb[(k>>3)*1024 + n*8 + (k&7)].
// ---------------------------------------------------------------------------
__global__ void packW(const float* __restrict__ W, unsigned short* __restrict__ Wb) {
    int idx = blockIdx.x * 256 + threadIdx.x;  // 0..16383
    int k = idx >> 7, n = idx & 127;
    Wb[(k >> 3) * 1024 + n * 8 + (k & 7)] = f2bf(W[k * 128 + n]);
}

// ---------------------------------------------------------------------------
// MFMA GEMM: out_bf16[N x 128] = f(in)[N x 128] @ W[128 x 128]
// f = identity or BN(scale,shift)+ReLU applied in f32 BEFORE bf16 rounding.
// ---------------------------------------------------------------------------
__global__ __launch_bounds__(256) void gemm_mfma(
    const float* __restrict__ in, const unsigned short* __restrict__ Wb,
    const float* __restrict__ bn_s, const float* __restrict__ bn_t,
    unsigned short* __restrict__ out, int nRows, int useBN) {
    const int wave = threadIdx.x >> 6;
    const int lane = threadIdx.x & 63;
    const int lrow = lane & 15;   // A row within tile / B,D col within tile
    const int lk = lane >> 4;     // k-group 0..3
    const long rowA = (long)blockIdx.x * 64 + wave * 16 + lrow;
    const bool okA = rowA < (long)nRows;
    const float* rp = in + (okA ? rowA : 0) * 128;

    bf16x8 afrag[4];
#pragma unroll
    for (int kk = 0; kk < 4; ++kk) {
        int k0 = kk * 32 + lk * 8;
        float4 v0, v1;
        if (okA) {
            v0 = *(const float4*)(rp + k0);
            v1 = *(const float4*)(rp + k0 + 4);
        } else {
            v0 = v1 = make_float4(0.f, 0.f, 0.f, 0.f);
        }
        if (useBN) {
            float4 s0 = *(const float4*)&bn_s[k0];
            float4 s1 = *(const float4*)&bn_s[k0 + 4];
            float4 t0 = *(const float4*)&bn_t[k0];
            float4 t1 = *(const float4*)&bn_t[k0 + 4];
            v0.x = fmaxf(fmaf(v0.x, s0.x, t0.x), 0.f);
            v0.y = fmaxf(fmaf(v0.y, s0.y, t0.y), 0.f);
            v0.z = fmaxf(fmaf(v0.z, s0.z, t0.z), 0.f);
            v0.w = fmaxf(fmaf(v0.w, s0.w, t0.w), 0.f);
            v1.x = fmaxf(fmaf(v1.x, s1.x, t1.x), 0.f);
            v1.y = fmaxf(fmaf(v1.y, s1.y, t1.y), 0.f);
            v1.z = fmaxf(fmaf(v1.z, s1.z, t1.z), 0.f);
            v1.w = fmaxf(fmaf(v1.w, s1.w, t1.w), 0.f);
        }
        bf16x8 a;
        a[0] = (short)f2bf(v0.x); a[1] = (short)f2bf(v0.y);
        a[2] = (short)f2bf(v0.z); a[3] = (short)f2bf(v0.w);
        a[4] = (short)f2bf(v1.x); a[5] = (short)f2bf(v1.y);
        a[6] = (short)f2bf(v1.z); a[7] = (short)f2bf(v1.w);
        afrag[kk] = a;
    }

    f32x4 acc[8];
#pragma unroll
    for (int nt = 0; nt < 8; ++nt) acc[nt] = (f32x4){0.f, 0.f, 0.f, 0.f};

#pragma unroll
    for (int nt = 0; nt < 8; ++nt) {
        const unsigned short* wp = Wb + lk * 1024 + (nt * 16 + lrow) * 8;
#pragma unroll
        for (int kk = 0; kk < 4; ++kk) {
            bf16x8 b = *(const bf16x8*)(wp + kk * 4096);
            acc[nt] = __builtin_amdgcn_mfma_f32_16x16x32_bf16(afrag[kk], b, acc[nt], 0, 0, 0);
        }
    }

    const long rowD0 = (long)blockIdx.x * 64 + wave * 16 + lk * 4;
#pragma unroll
    for (int r = 0; r < 4; ++r) {
        long rd = rowD0 + r;
        if (rd < nRows) {
            unsigned short* op = out + rd * 128 + lrow;
#pragma unroll
            for (int nt = 0; nt < 8; ++nt) op[nt * 16] = f2bf(acc[nt][r]);
        }
    }
}

// ---------------------------------------------------------------------------
// Aggregation: out[v] = dinv[v] * sum_{e in CSR(v)} dinv[src_e] * h[src_e]
// h is bf16. Wave per node; lane loads uint2 (4 cols, 8B) so 32 lanes cover a
// row and each wave-load fetches TWO edges (lanes 0-31 even slot, 32-63 odd).
// 4 loads in flight -> 8 edges per chunk. OOB slots: weight 0, load edge 0.
// Epilogue: slot-reduce in regs + one shfl_xor(32) cross-half add.
// ---------------------------------------------------------------------------
__global__ __launch_bounds__(256) void agg_kernel(
    const unsigned short* __restrict__ h, const int* __restrict__ rowptr,
    const int* __restrict__ cnt, const int* __restrict__ srcIdx,
    const float* __restrict__ dinv, float* __restrict__ out, int nNodes) {
    int wave = threadIdx.x >> 6;
    int lane = threadIdx.x & 63;
    int half = lane >> 5;   // which edge parity this lane serves
    int l5 = lane & 31;     // column group: cols 4*l5 .. 4*l5+3
    int v = blockIdx.x * 4 + wave;
    if (v >= nNodes) return;
    int start = rowptr[v];
    int n = cnt[v];
    float4 a0 = make_float4(0.f, 0.f, 0.f, 0.f), a1 = a0, a2 = a0, a3 = a0;
    for (int e = 0; e < n; e += 8) {
        int e0 = e + half, e1 = e + 2 + half, e2 = e + 4 + half, e3 = e + 6 + half;
        int i0 = start + ((e0 < n) ? e0 : 0);
        int i1 = start + ((e1 < n) ? e1 : 0);
        int i2 = start + ((e2 < n) ? e2 : 0);
        int i3 = start + ((e3 < n) ? e3 : 0);
        int s0 = srcIdx[i0], s1 = srcIdx[i1], s2 = srcIdx[i2], s3 = srcIdx[i3];
        float w0 = (e0 < n) ? dinv[s0] : 0.f;
        float w1 = (e1 < n) ? dinv[s1] : 0.f;
        float w2 = (e2 < n) ? dinv[s2] : 0.f;
        float w3 = (e3 < n) ? dinv[s3] : 0.f;
        uint2 u0 = *(const uint2*)&h[(long)s0 * 128 + l5 * 4];
        uint2 u1 = *(const uint2*)&h[(long)s1 * 128 + l5 * 4];
        uint2 u2 = *(const uint2*)&h[(long)s2 * 128 + l5 * 4];
        uint2 u3 = *(const uint2*)&h[(long)s3 * 128 + l5 * 4];
        a0.x = fmaf(w0, bflo(u0.x), a0.x); a0.y = fmaf(w0, bfhi(u0.x), a0.y);
        a0.z = fmaf(w0, bflo(u0.y), a0.z); a0.w = fmaf(w0, bfhi(u0.y), a0.w);
        a1.x = fmaf(w1, bflo(u1.x), a1.x); a1.y = fmaf(w1, bfhi(u1.x), a1.y);
        a1.z = fmaf(w1, bflo(u1.y), a1.z); a1.w = fmaf(w1, bfhi(u1.y), a1.w);
        a2.x = fmaf(w2, bflo(u2.x), a2.x); a2.y = fmaf(w2, bfhi(u2.x), a2.y);
        a2.z = fmaf(w2, bflo(u2.y), a2.z); a2.w = fmaf(w2, bfhi(u2.y), a2.w);
        a3.x = fmaf(w3, bflo(u3.x), a3.x); a3.y = fmaf(w3, bfhi(u3.x), a3.y);
        a3.z = fmaf(w3, bflo(u3.y), a3.z); a3.w = fmaf(w3, bfhi(u3.y), a3.w);
    }
    float tx = (a0.x + a1.x) + (a2.x + a3.x);
    float ty = (a0.y + a1.y) + (a2.y + a3.y);
    float tz = (a0.z + a1.z) + (a2.z + a3.z);
    float tw = (a0.w + a1.w) + (a2.w + a3.w);
    tx += __shfl_xor(tx, 32);
    ty += __shfl_xor(ty, 32);
    tz += __shfl_xor(tz, 32);
    tw += __shfl_xor(tw, 32);
    if (half == 0) {
        float dv = dinv[v];
        *(float4*)&out[(long)v * 128 + l5 * 4] =
            make_float4(tx * dv, ty * dv, tz * dv, tw * dv);
    }
}

// ---------------------------------------------------------------------------
// BN statistics: per-column sum and sum-of-squares via block partials + atomics
// ---------------------------------------------------------------------------
__global__ __launch_bounds__(256) void bnstats(const float* __restrict__ h,
                                               float* __restrict__ sums, int nRows) {
    int col = threadIdx.x & 127;
    int half = threadIdx.x >> 7;
    int chunk = (nRows + gridDim.x - 1) / gridDim.x;
    int r0 = blockIdx.x * chunk;
    int r1 = min(r0 + chunk, nRows);
    float s = 0.f, s2 = 0.f;
    for (int r = r0 + half; r < r1; r += 2) {
        float v = h[(long)r * 128 + col];
        s += v;
        s2 = fmaf(v, v, s2);
    }
    __shared__ float l1[256], l2[256];
    l1[threadIdx.x] = s;
    l2[threadIdx.x] = s2;
    __syncthreads();
    if (half == 0) {
        s = l1[threadIdx.x] + l1[threadIdx.x + 128];
        s2 = l2[threadIdx.x] + l2[threadIdx.x + 128];
        atomicAdd(&sums[col], s);
        atomicAdd(&sums[128 + col], s2);
    }
}

__global__ void bnfin(const float* __restrict__ sums, const float* __restrict__ gamma,
                      const float* __restrict__ beta, float* __restrict__ bn_s,
                      float* __restrict__ bn_t, float invN) {
    int c = threadIdx.x;
    float mean = sums[c] * invN;
    float var = sums[128 + c] * invN - mean * mean;
    float rs = rsqrtf(var + BN_EPS);
    float s = gamma[c] * rs;
    bn_s[c] = s;
    bn_t[c] = beta[c] - mean * s;
}

// ---------------------------------------------------------------------------
// Global mean pool, stage 1: per-slice partial sums, atomicAdd into poolAcc.
// ---------------------------------------------------------------------------
__global__ __launch_bounds__(256) void pool_partial(
    const float* __restrict__ h, const int* __restrict__ batch,
    float* __restrict__ poolAcc, int nNodes) {
    int g = blockIdx.x / POOL_SLICES;
    int s = blockIdx.x % POOL_SLICES;
    int a = 0, b = nNodes;
    while (a < b) { int m = (a + b) >> 1; if (batch[m] < g) a = m + 1; else b = m; }
    int lo = a;
    b = nNodes;
    while (a < b) { int m = (a + b) >> 1; if (batch[m] < g + 1) a = m + 1; else b = m; }
    int hi = a;
    int len = hi - lo;
    int per = (len + POOL_SLICES - 1) / POOL_SLICES;
    int a0 = lo + s * per;
    int a1 = min(a0 + per, hi);
    if (a0 >= a1) return;
    int col = threadIdx.x & 127;
    int half = threadIdx.x >> 7;
    float acc = 0.f;
    for (int v = a0 + half; v < a1; v += 2) acc += h[(long)v * 128 + col];
    __shared__ float l[256];
    l[threadIdx.x] = acc;
    __syncthreads();
    if (half == 0) atomicAdd(&poolAcc[g * 128 + col], l[threadIdx.x] + l[threadIdx.x + 128]);
}

// ---------------------------------------------------------------------------
// MLP head: mean = poolAcc/cnt; relu(xg@Wg1+bg1) @ Wg2 + bg2 -> log_softmax
// ---------------------------------------------------------------------------
__global__ __launch_bounds__(128) void head_kernel(
    const float* __restrict__ poolAcc, const int* __restrict__ batch,
    const float* __restrict__ Wg1, const float* __restrict__ bg1,
    const float* __restrict__ Wg2, const float* __restrict__ bg2,
    float* __restrict__ out, int nNodes) {
    __shared__ float xr[128], tr[128], lg[N_CLASSES], red[2];
    int g = blockIdx.x, t = threadIdx.x;
    int a = 0, b = nNodes;
    while (a < b) { int m = (a + b) >> 1; if (batch[m] < g) a = m + 1; else b = m; }
    int lo = a;
    b = nNodes;
    while (a < b) { int m = (a + b) >> 1; if (batch[m] < g + 1) a = m + 1; else b = m; }
    float cntf = fmaxf((float)(a - lo), 1.0f);
    xr[t] = poolAcc[g * 128 + t] / cntf;
    __syncthreads();
    float s = bg1[t];
    for (int k = 0; k < 128; ++k) s = fmaf(xr[k], Wg1[k * 128 + t], s);
    tr[t] = fmaxf(s, 0.f);
    __syncthreads();
    if (t < N_CLASSES) {
        float s2 = bg2[t];
        for (int k = 0; k < 128; ++k) s2 = fmaf(tr[k], Wg2[k * N_CLASSES + t], s2);
        lg[t] = s2;
    }
    __syncthreads();
    if (t == 0) {
        float m = -1e30f;
        for (int j = 0; j < N_CLASSES; ++j) m = fmaxf(m, lg[j]);
        float se = 0.f;
        for (int j = 0; j < N_CLASSES; ++j) se += expf(lg[j] - m);
        red[0] = m;
        red[1] = logf(se);
    }
    __syncthreads();
    if (t < N_CLASSES) out[g * N_CLASSES + t] = lg[t] - red[0] - red[1];
}

// ---------------------------------------------------------------------------
extern "C" void kernel_launch(void* const* d_in, const int* in_sizes, int n_in,
                              void* d_out, int out_size, void* d_ws, size_t ws_size,
                              hipStream_t stream) {
    const float* x = (const float*)d_in[0];
    const int* edge = (const int*)d_in[1];
    const int* row = edge;
    const int* col = edge + N_EDGES;
    const int* batch = (const int*)d_in[2];
    const float* W0 = (const float*)d_in[3];
    const float* g0 = (const float*)d_in[4];
    const float* b0 = (const float*)d_in[5];
    const float* W1 = (const float*)d_in[6];
    const float* g1 = (const float*)d_in[7];
    const float* b1 = (const float*)d_in[8];
    const float* W2 = (const float*)d_in[9];
    const float* Wg1 = (const float*)d_in[10];
    const float* bg1 = (const float*)d_in[11];
    const float* Wg2 = (const float*)d_in[12];
    const float* bg2 = (const float*)d_in[13];
    float* out = (float*)d_out;

    char* p = (char*)d_ws;
    auto alloc = [&](size_t bytes) {
        void* r = (void*)p;
        p += (bytes + 255) & ~(size_t)255;
        return r;
    };
    unsigned short* bufA = (unsigned short*)alloc((size_t)N_NODES * 128 * 2);  // bf16 h
    float* bufB = (float*)alloc((size_t)N_NODES * 128 * 4);                    // f32 agg out
    float* dinv = (float*)alloc((size_t)N_NODES * 4);
    int* degcnt = (int*)alloc((size_t)N_NODES * 4);
    int* cnt = (int*)alloc((size_t)N_NODES * 4);
    int* rowptr = (int*)alloc((size_t)N_NODES * 4);
    int* wptr = (int*)alloc((size_t)N_NODES * 4);
    int* srcIdx = (int*)alloc((size_t)N_EDGES * 4);
    int* blockSums = (int*)alloc(1024 * 4);
    int* blockOffs = (int*)alloc(1024 * 4);
    float* bnacc = (float*)alloc(256 * 4);
    float* bn_s = (float*)alloc(128 * 4);
    float* bn_t = (float*)alloc(128 * 4);
    float* poolAcc = (float*)alloc(128 * 128 * 4);
    unsigned short* Wb0 = (unsigned short*)alloc(128 * 128 * 2);
    unsigned short* Wb1 = (unsigned short*)alloc(128 * 128 * 2);
    unsigned short* Wb2 = (unsigned short*)alloc(128 * 128 * 2);

    const int E = N_EDGES, N = N_NODES;
    const int scanBlocks = (N + 1023) / 1024;  // 98

    // --- degree + CSR (recomputed every call: deterministic work) ---
    hipMemsetAsync(degcnt, 0, (size_t)N * 4, stream);
    hipMemsetAsync(cnt, 0, (size_t)N * 4, stream);
    count_kernel<<<(E + 255) / 256, 256, 0, stream>>>(row, col, degcnt, cnt, E);
    dinv_kernel<<<(N + 255) / 256, 256, 0, stream>>>(degcnt, dinv, N);
    scanA<<<scanBlocks, 256, 0, stream>>>(cnt, rowptr, blockSums, N);
    scanB<<<1, 128, 0, stream>>>(blockSums, blockOffs, scanBlocks);
    scanC<<<(N + 255) / 256, 256, 0, stream>>>(rowptr, blockOffs, wptr, N);
    fill_kernel<<<(E + 255) / 256, 256, 0, stream>>>(row, col, wptr, srcIdx, E);

    // --- pack weights to bf16 fragment layout ---
    packW<<<64, 256, 0, stream>>>(W0, Wb0);
    packW<<<64, 256, 0, stream>>>(W1, Wb1);
    packW<<<64, 256, 0, stream>>>(W2, Wb2);

    const int gemmGrid = (N + 63) / 64;  // 1563
    const int aggGrid = (N + 3) / 4;     // 25000

    // --- layer 1 ---
    gemm_mfma<<<gemmGrid, 256, 0, stream>>>(x, Wb0, nullptr, nullptr, bufA, N, 0);
    agg_kernel<<<aggGrid, 256, 0, stream>>>(bufA, rowptr, cnt, srcIdx, dinv, bufB, N);
    hipMemsetAsync(bnacc, 0, 256 * 4, stream);
    bnstats<<<512, 256, 0, stream>>>(bufB, bnacc, N);
    bnfin<<<1, 128, 0, stream>>>(bnacc, g0, b0, bn_s, bn_t, 1.0f / N);

    // --- layer 2 ---
    gemm_mfma<<<gemmGrid, 256, 0, stream>>>(bufB, Wb1, bn_s, bn_t, bufA, N, 1);
    agg_kernel<<<aggGrid, 256, 0, stream>>>(bufA, rowptr, cnt, srcIdx, dinv, bufB, N);
    hipMemsetAsync(bnacc, 0, 256 * 4, stream);
    bnstats<<<512, 256, 0, stream>>>(bufB, bnacc, N);
    bnfin<<<1, 128, 0, stream>>>(bnacc, g1, b1, bn_s, bn_t, 1.0f / N);

    // --- layer 3 ---
    gemm_mfma<<<gemmGrid, 256, 0, stream>>>(bufB, Wb2, bn_s, bn_t, bufA, N, 1);
    agg_kernel<<<aggGrid, 256, 0, stream>>>(bufA, rowptr, cnt, srcIdx, dinv, bufB, N);

    // --- pool (parallel partials) + head ---
    hipMemsetAsync(poolAcc, 0, 128 * 128 * 4, stream);
    pool_partial<<<N_GRAPHS * POOL_SLICES, 256, 0, stream>>>(bufB, batch, poolAcc, N);
    head_kernel<<<N_GRAPHS, 128, 0, stream>>>(poolAcc, batch, Wg1, bg1, Wg2, bg2, out, N);
}

// Round 9
// 417.324 us; speedup vs baseline: 3.4354x; 1.0354x over previous
//
#include <hip/hip_runtime.h>

#define N_NODES 100000
#define N_EDGES 640000
#define HID 128
#define N_CLASSES 40
#define N_GRAPHS 128
#define BN_EPS 1e-5f
#define POOL_SLICES 16

#define GEMM_GRID 1563   // (N_NODES + 63) / 64
#define COUNT_GRID 2500  // (N_EDGES + 255) / 256
#define PACK_BLOCKS 64   // 16384 elems / 256 per weight matrix

typedef __attribute__((ext_vector_type(8))) short bf16x8;
typedef __attribute__((ext_vector_type(4))) float f32x4;

// round-to-nearest-even f32 -> bf16 (as raw u16)
__device__ __forceinline__ unsigned short f2bf(float f) {
    unsigned u = __float_as_uint(f);
    u += 0x7FFFu + ((u >> 16) & 1u);
    return (unsigned short)(u >> 16);
}

__device__ __forceinline__ float bflo(unsigned u) { return __uint_as_float(u << 16); }
__device__ __forceinline__ float bfhi(unsigned u) { return __uint_as_float(u & 0xFFFF0000u); }

// ---------------------------------------------------------------------------
// Phase A mega-kernel: [gemm layer-1] || [edge counting] || [pack Wb1/Wb2].
// All three are mutually independent; count's atomic latency hides under
// gemm's MFMA/VALU work (single-stream graph capture forbids multi-stream).
// ---------------------------------------------------------------------------
__global__ __launch_bounds__(256) void phaseA(
    const float* __restrict__ x, const float* __restrict__ W0,
    const int* __restrict__ row, const int* __restrict__ col,
    int* degcnt, int* cnt,
    const float* __restrict__ W1, const float* __restrict__ W2,
    unsigned short* __restrict__ Wb1, unsigned short* __restrict__ Wb2,
    unsigned short* __restrict__ outA, int nRows, int E) {
    __shared__ unsigned short Wl[128 * 128];  // 32 KB (gemm branch only)
    const int b = blockIdx.x;

    if (b < GEMM_GRID) {
        // ---- gemm layer 1: outA = bf16( x @ W0 ) ----
        // pack W0 -> LDS fragment layout Wl[(k>>3)*1024 + n*8 + (k&7)]
        for (int i = threadIdx.x; i < 128 * 128; i += 256) {
            int k = i >> 7, n = i & 127;
            Wl[(k >> 3) * 1024 + n * 8 + (k & 7)] = f2bf(W0[i]);
        }
        __syncthreads();

        const int wave = threadIdx.x >> 6;
        const int lane = threadIdx.x & 63;
        const int lrow = lane & 15;
        const int lk = lane >> 4;
        const long rowA = (long)b * 64 + wave * 16 + lrow;
        const bool okA = rowA < (long)nRows;
        const float* rp = x + (okA ? rowA : 0) * 128;

        bf16x8 afrag[4];
#pragma unroll
        for (int kk = 0; kk < 4; ++kk) {
            int k0 = kk * 32 + lk * 8;
            float4 v0, v1;
            if (okA) {
                v0 = *(const float4*)(rp + k0);
                v1 = *(const float4*)(rp + k0 + 4);
            } else {
                v0 = v1 = make_float4(0.f, 0.f, 0.f, 0.f);
            }
            bf16x8 a;
            a[0] = (short)f2bf(v0.x); a[1] = (short)f2bf(v0.y);
            a[2] = (short)f2bf(v0.z); a[3] = (short)f2bf(v0.w);
            a[4] = (short)f2bf(v1.x); a[5] = (short)f2bf(v1.y);
            a[6] = (short)f2bf(v1.z); a[7] = (short)f2bf(v1.w);
            afrag[kk] = a;
        }

        f32x4 acc[8];
#pragma unroll
        for (int nt = 0; nt < 8; ++nt) acc[nt] = (f32x4){0.f, 0.f, 0.f, 0.f};

#pragma unroll
        for (int nt = 0; nt < 8; ++nt) {
            const unsigned short* wp = Wl + lk * 1024 + (nt * 16 + lrow) * 8;
#pragma unroll
            for (int kk = 0; kk < 4; ++kk) {
                bf16x8 bb = *(const bf16x8*)(wp + kk * 4096);
                acc[nt] = __builtin_amdgcn_mfma_f32_16x16x32_bf16(afrag[kk], bb, acc[nt], 0, 0, 0);
            }
        }

        const long rowD0 = (long)b * 64 + wave * 16 + lk * 4;
#pragma unroll
        for (int r = 0; r < 4; ++r) {
            long rd = rowD0 + r;
            if (rd < nRows) {
                unsigned short* op = outA + rd * 128 + lrow;
#pragma unroll
                for (int nt = 0; nt < 8; ++nt) op[nt * 16] = f2bf(acc[nt][r]);
            }
        }
    } else if (b < GEMM_GRID + COUNT_GRID) {
        // ---- edge degree counting ----
        int e = (b - GEMM_GRID) * 256 + threadIdx.x;
        if (e < E) {
            atomicAdd(&degcnt[row[e]], 1);
            atomicAdd(&cnt[col[e]], 1);
        }
    } else {
        // ---- pack W1 / W2 to bf16 fragment layout ----
        int pb = b - GEMM_GRID - COUNT_GRID;  // 0..127
        const float* Wsrc = (pb < PACK_BLOCKS) ? W1 : W2;
        unsigned short* Wdst = (pb < PACK_BLOCKS) ? Wb1 : Wb2;
        int idx = (pb & (PACK_BLOCKS - 1)) * 256 + threadIdx.x;
        int k = idx >> 7, n = idx & 127;
        Wdst[(k >> 3) * 1024 + n * 8 + (k & 7)] = f2bf(Wsrc[k * 128 + n]);
    }
}

__global__ void dinv_kernel(const int* __restrict__ degcnt, float* __restrict__ dinv, int n) {
    int i = blockIdx.x * 256 + threadIdx.x;
    if (i < n) dinv[i] = rsqrtf((float)degcnt[i] + 1.0f);
}

// block-level exclusive scan (1024 elements per block of 256 threads)
__global__ __launch_bounds__(256) void scanA(const int* __restrict__ cnt, int* __restrict__ rowptr,
                                             int* __restrict__ blockSums, int n) {
    __shared__ int sdata[256];
    int t = threadIdx.x;
    int base = blockIdx.x * 1024 + t * 4;
    int c[4];
#pragma unroll
    for (int j = 0; j < 4; ++j) c[j] = (base + j < n) ? cnt[base + j] : 0;
    int s = c[0] + c[1] + c[2] + c[3];
    sdata[t] = s;
    __syncthreads();
    for (int off = 1; off < 256; off <<= 1) {
        int v = (t >= off) ? sdata[t - off] : 0;
        __syncthreads();
        sdata[t] += v;
        __syncthreads();
    }
    int excl = sdata[t] - s;
    if (t == 255) blockSums[blockIdx.x] = sdata[255];
    int run = excl;
#pragma unroll
    for (int j = 0; j < 4; ++j) {
        if (base + j < n) rowptr[base + j] = run;
        run += c[j];
    }
}

__global__ void scanB(const int* __restrict__ blockSums, int* __restrict__ blockOffs, int nb) {
    __shared__ int sdata[128];
    int t = threadIdx.x;
    int v = (t < nb) ? blockSums[t] : 0;
    sdata[t] = v;
    __syncthreads();
    for (int off = 1; off < 128; off <<= 1) {
        int u = (t >= off) ? sdata[t - off] : 0;
        __syncthreads();
        sdata[t] += u;
        __syncthreads();
    }
    if (t < nb) blockOffs[t] = sdata[t] - v;
}

__global__ void scanC(int* __restrict__ rowptr, const int* __restrict__ blockOffs,
                      int* __restrict__ wptr, int n) {
    int i = blockIdx.x * 256 + threadIdx.x;
    if (i < n) {
        int v = rowptr[i] + blockOffs[i >> 10];
        rowptr[i] = v;
        wptr[i] = v;
    }
}

__global__ void fill_kernel(const int* __restrict__ row, const int* __restrict__ col,
                            int* wptr, int* __restrict__ srcIdx, int E) {
    int e = blockIdx.x * 256 + threadIdx.x;
    if (e < E) {
        int p = atomicAdd(&wptr[col[e]], 1);
        srcIdx[p] = row[e];
    }
}

// ---------------------------------------------------------------------------
// MFMA GEMM (layers 2,3): out_bf16 = bf16( relu(BN(in)) @ W ), Wb pre-packed.
// ---------------------------------------------------------------------------
__global__ __launch_bounds__(256) void gemm_mfma(
    const float* __restrict__ in, const unsigned short* __restrict__ Wb,
    const float* __restrict__ bn_s, const float* __restrict__ bn_t,
    unsigned short* __restrict__ out, int nRows) {
    const int wave = threadIdx.x >> 6;
    const int lane = threadIdx.x & 63;
    const int lrow = lane & 15;
    const int lk = lane >> 4;
    const long rowA = (long)blockIdx.x * 64 + wave * 16 + lrow;
    const bool okA = rowA < (long)nRows;
    const float* rp = in + (okA ? rowA : 0) * 128;

    bf16x8 afrag[4];
#pragma unroll
    for (int kk = 0; kk < 4; ++kk) {
        int k0 = kk * 32 + lk * 8;
        float4 v0, v1;
        if (okA) {
            v0 = *(const float4*)(rp + k0);
            v1 = *(const float4*)(rp + k0 + 4);
        } else {
            v0 = v1 = make_float4(0.f, 0.f, 0.f, 0.f);
        }
        float4 s0 = *(const float4*)&bn_s[k0];
        float4 s1 = *(const float4*)&bn_s[k0 + 4];
        float4 t0 = *(const float4*)&bn_t[k0];
        float4 t1 = *(const float4*)&bn_t[k0 + 4];
        v0.x = fmaxf(fmaf(v0.x, s0.x, t0.x), 0.f);
        v0.y = fmaxf(fmaf(v0.y, s0.y, t0.y), 0.f);
        v0.z = fmaxf(fmaf(v0.z, s0.z, t0.z), 0.f);
        v0.w = fmaxf(fmaf(v0.w, s0.w, t0.w), 0.f);
        v1.x = fmaxf(fmaf(v1.x, s1.x, t1.x), 0.f);
        v1.y = fmaxf(fmaf(v1.y, s1.y, t1.y), 0.f);
        v1.z = fmaxf(fmaf(v1.z, s1.z, t1.z), 0.f);
        v1.w = fmaxf(fmaf(v1.w, s1.w, t1.w), 0.f);
        bf16x8 a;
        a[0] = (short)f2bf(v0.x); a[1] = (short)f2bf(v0.y);
        a[2] = (short)f2bf(v0.z); a[3] = (short)f2bf(v0.w);
        a[4] = (short)f2bf(v1.x); a[5] = (short)f2bf(v1.y);
        a[6] = (short)f2bf(v1.z); a[7] = (short)f2bf(v1.w);
        afrag[kk] = a;
    }

    f32x4 acc[8];
#pragma unroll
    for (int nt = 0; nt < 8; ++nt) acc[nt] = (f32x4){0.f, 0.f, 0.f, 0.f};

#pragma unroll
    for (int nt = 0; nt < 8; ++nt) {
        const unsigned short* wp = Wb + lk * 1024 + (nt * 16 + lrow) * 8;
#pragma unroll
        for (int kk = 0; kk < 4; ++kk) {
            bf16x8 b = *(const bf16x8*)(wp + kk * 4096);
            acc[nt] = __builtin_amdgcn_mfma_f32_16x16x32_bf16(afrag[kk], b, acc[nt], 0, 0, 0);
        }
    }

    const long rowD0 = (long)blockIdx.x * 64 + wave * 16 + lk * 4;
#pragma unroll
    for (int r = 0; r < 4; ++r) {
        long rd = rowD0 + r;
        if (rd < nRows) {
            unsigned short* op = out + rd * 128 + lrow;
#pragma unroll
            for (int nt = 0; nt < 8; ++nt) op[nt * 16] = f2bf(acc[nt][r]);
        }
    }
}

// ---------------------------------------------------------------------------
// Aggregation: out[v] = dinv[v] * sum_{e in CSR(v)} dinv[src_e] * h[src_e]
// h bf16; lane loads uint2 (4 cols); 32 lanes/row -> 2 edges per wave-load;
// 4 loads in flight -> 8 edges/chunk. shfl_xor(32) cross-half reduce.
// ---------------------------------------------------------------------------
__global__ __launch_bounds__(256) void agg_kernel(
    const unsigned short* __restrict__ h, const int* __restrict__ rowptr,
    const int* __restrict__ cnt, const int* __restrict__ srcIdx,
    const float* __restrict__ dinv, float* __restrict__ out, int nNodes) {
    int wave = threadIdx.x >> 6;
    int lane = threadIdx.x & 63;
    int half = lane >> 5;
    int l5 = lane & 31;
    int v = blockIdx.x * 4 + wave;
    if (v >= nNodes) return;
    int start = rowptr[v];
    int n = cnt[v];
    float4 a0 = make_float4(0.f, 0.f, 0.f, 0.f), a1 = a0, a2 = a0, a3 = a0;
    for (int e = 0; e < n; e += 8) {
        int e0 = e + half, e1 = e + 2 + half, e2 = e + 4 + half, e3 = e + 6 + half;
        int i0 = start + ((e0 < n) ? e0 : 0);
        int i1 = start + ((e1 < n) ? e1 : 0);
        int i2 = start + ((e2 < n) ? e2 : 0);
        int i3 = start + ((e3 < n) ? e3 : 0);
        int s0 = srcIdx[i0], s1 = srcIdx[i1], s2 = srcIdx[i2], s3 = srcIdx[i3];
        float w0 = (e0 < n) ? dinv[s0] : 0.f;
        float w1 = (e1 < n) ? dinv[s1] : 0.f;
        float w2 = (e2 < n) ? dinv[s2] : 0.f;
        float w3 = (e3 < n) ? dinv[s3] : 0.f;
        uint2 u0 = *(const uint2*)&h[(long)s0 * 128 + l5 * 4];
        uint2 u1 = *(const uint2*)&h[(long)s1 * 128 + l5 * 4];
        uint2 u2 = *(const uint2*)&h[(long)s2 * 128 + l5 * 4];
        uint2 u3 = *(const uint2*)&h[(long)s3 * 128 + l5 * 4];
        a0.x = fmaf(w0, bflo(u0.x), a0.x); a0.y = fmaf(w0, bfhi(u0.x), a0.y);
        a0.z = fmaf(w0, bflo(u0.y), a0.z); a0.w = fmaf(w0, bfhi(u0.y), a0.w);
        a1.x = fmaf(w1, bflo(u1.x), a1.x); a1.y = fmaf(w1, bfhi(u1.x), a1.y);
        a1.z = fmaf(w1, bflo(u1.y), a1.z); a1.w = fmaf(w1, bfhi(u1.y), a1.w);
        a2.x = fmaf(w2, bflo(u2.x), a2.x); a2.y = fmaf(w2, bfhi(u2.x), a2.y);
        a2.z = fmaf(w2, bflo(u2.y), a2.z); a2.w = fmaf(w2, bfhi(u2.y), a2.w);
        a3.x = fmaf(w3, bflo(u3.x), a3.x); a3.y = fmaf(w3, bfhi(u3.x), a3.y);
        a3.z = fmaf(w3, bflo(u3.y), a3.z); a3.w = fmaf(w3, bfhi(u3.y), a3.w);
    }
    float tx = (a0.x + a1.x) + (a2.x + a3.x);
    float ty = (a0.y + a1.y) + (a2.y + a3.y);
    float tz = (a0.z + a1.z) + (a2.z + a3.z);
    float tw = (a0.w + a1.w) + (a2.w + a3.w);
    tx += __shfl_xor(tx, 32);
    ty += __shfl_xor(ty, 32);
    tz += __shfl_xor(tz, 32);
    tw += __shfl_xor(tw, 32);
    if (half == 0) {
        float dv = dinv[v];
        *(float4*)&out[(long)v * 128 + l5 * 4] =
            make_float4(tx * dv, ty * dv, tz * dv, tw * dv);
    }
}

// ---------------------------------------------------------------------------
// BN statistics: per-column sum and sum-of-squares via block partials + atomics
// ---------------------------------------------------------------------------
__global__ __launch_bounds__(256) void bnstats(const float* __restrict__ h,
                                               float* __restrict__ sums, int nRows) {
    int col = threadIdx.x & 127;
    int half = threadIdx.x >> 7;
    int chunk = (nRows + gridDim.x - 1) / gridDim.x;
    int r0 = blockIdx.x * chunk;
    int r1 = min(r0 + chunk, nRows);
    float s = 0.f, s2 = 0.f;
    for (int r = r0 + half; r < r1; r += 2) {
        float v = h[(long)r * 128 + col];
        s += v;
        s2 = fmaf(v, v, s2);
    }
    __shared__ float l1[256], l2[256];
    l1[threadIdx.x] = s;
    l2[threadIdx.x] = s2;
    __syncthreads();
    if (half == 0) {
        s = l1[threadIdx.x] + l1[threadIdx.x + 128];
        s2 = l2[threadIdx.x] + l2[threadIdx.x + 128];
        atomicAdd(&sums[col], s);
        atomicAdd(&sums[128 + col], s2);
    }
}

__global__ void bnfin(const float* __restrict__ sums, const float* __restrict__ gamma,
                      const float* __restrict__ beta, float* __restrict__ bn_s,
                      float* __restrict__ bn_t, float invN) {
    int c = threadIdx.x;
    float mean = sums[c] * invN;
    float var = sums[128 + c] * invN - mean * mean;
    float rs = rsqrtf(var + BN_EPS);
    float s = gamma[c] * rs;
    bn_s[c] = s;
    bn_t[c] = beta[c] - mean * s;
}

// ---------------------------------------------------------------------------
// Global mean pool, stage 1: per-slice partial sums, atomicAdd into poolAcc.
// ---------------------------------------------------------------------------
__global__ __launch_bounds__(256) void pool_partial(
    const float* __restrict__ h, const int* __restrict__ batch,
    float* __restrict__ poolAcc, int nNodes) {
    int g = blockIdx.x / POOL_SLICES;
    int s = blockIdx.x % POOL_SLICES;
    int a = 0, b = nNodes;
    while (a < b) { int m = (a + b) >> 1; if (batch[m] < g) a = m + 1; else b = m; }
    int lo = a;
    b = nNodes;
    while (a < b) { int m = (a + b) >> 1; if (batch[m] < g + 1) a = m + 1; else b = m; }
    int hi = a;
    int len = hi - lo;
    int per = (len + POOL_SLICES - 1) / POOL_SLICES;
    int a0 = lo + s * per;
    int a1 = min(a0 + per, hi);
    if (a0 >= a1) return;
    int col = threadIdx.x & 127;
    int half = threadIdx.x >> 7;
    float acc = 0.f;
    for (int v = a0 + half; v < a1; v += 2) acc += h[(long)v * 128 + col];
    __shared__ float l[256];
    l[threadIdx.x] = acc;
    __syncthreads();
    if (half == 0) atomicAdd(&poolAcc[g * 128 + col], l[threadIdx.x] + l[threadIdx.x + 128]);
}

// ---------------------------------------------------------------------------
// MLP head: mean = poolAcc/cnt; relu(xg@Wg1+bg1) @ Wg2 + bg2 -> log_softmax
// ---------------------------------------------------------------------------
__global__ __launch_bounds__(128) void head_kernel(
    const float* __restrict__ poolAcc, const int* __restrict__ batch,
    const float* __restrict__ Wg1, const float* __restrict__ bg1,
    const float* __restrict__ Wg2, const float* __restrict__ bg2,
    float* __restrict__ out, int nNodes) {
    __shared__ float xr[128], tr[128], lg[N_CLASSES], red[2];
    int g = blockIdx.x, t = threadIdx.x;
    int a = 0, b = nNodes;
    while (a < b) { int m = (a + b) >> 1; if (batch[m] < g) a = m + 1; else b = m; }
    int lo = a;
    b = nNodes;
    while (a < b) { int m = (a + b) >> 1; if (batch[m] < g + 1) a = m + 1; else b = m; }
    float cntf = fmaxf((float)(a - lo), 1.0f);
    xr[t] = poolAcc[g * 128 + t] / cntf;
    __syncthreads();
    float s = bg1[t];
    for (int k = 0; k < 128; ++k) s = fmaf(xr[k], Wg1[k * 128 + t], s);
    tr[t] = fmaxf(s, 0.f);
    __syncthreads();
    if (t < N_CLASSES) {
        float s2 = bg2[t];
        for (int k = 0; k < 128; ++k) s2 = fmaf(tr[k], Wg2[k * N_CLASSES + t], s2);
        lg[t] = s2;
    }
    __syncthreads();
    if (t == 0) {
        float m = -1e30f;
        for (int j = 0; j < N_CLASSES; ++j) m = fmaxf(m, lg[j]);
        float se = 0.f;
        for (int j = 0; j < N_CLASSES; ++j) se += expf(lg[j] - m);
        red[0] = m;
        red[1] = logf(se);
    }
    __syncthreads();
    if (t < N_CLASSES) out[g * N_CLASSES + t] = lg[t] - red[0] - red[1];
}

// ---------------------------------------------------------------------------
extern "C" void kernel_launch(void* const* d_in, const int* in_sizes, int n_in,
                              void* d_out, int out_size, void* d_ws, size_t ws_size,
                              hipStream_t stream) {
    const float* x = (const float*)d_in[0];
    const int* edge = (const int*)d_in[1];
    const int* row = edge;
    const int* col = edge + N_EDGES;
    const int* batch = (const int*)d_in[2];
    const float* W0 = (const float*)d_in[3];
    const float* g0 = (const float*)d_in[4];
    const float* b0 = (const float*)d_in[5];
    const float* W1 = (const float*)d_in[6];
    const float* g1 = (const float*)d_in[7];
    const float* b1 = (const float*)d_in[8];
    const float* W2 = (const float*)d_in[9];
    const float* Wg1 = (const float*)d_in[10];
    const float* bg1 = (const float*)d_in[11];
    const float* Wg2 = (const float*)d_in[12];
    const float* bg2 = (const float*)d_in[13];
    float* out = (float*)d_out;

    char* p = (char*)d_ws;
    auto alloc = [&](size_t bytes) {
        void* r = (void*)p;
        p += (bytes + 255) & ~(size_t)255;
        return r;
    };
    unsigned short* bufA = (unsigned short*)alloc((size_t)N_NODES * 128 * 2);  // bf16 h
    float* bufB = (float*)alloc((size_t)N_NODES * 128 * 4);                    // f32 agg out
    float* dinv = (float*)alloc((size_t)N_NODES * 4);
    int* degcnt = (int*)alloc((size_t)N_NODES * 4);
    int* cnt = (int*)alloc((size_t)N_NODES * 4);
    int* rowptr = (int*)alloc((size_t)N_NODES * 4);
    int* wptr = (int*)alloc((size_t)N_NODES * 4);
    int* srcIdx = (int*)alloc((size_t)N_EDGES * 4);
    int* blockSums = (int*)alloc(1024 * 4);
    int* blockOffs = (int*)alloc(1024 * 4);
    float* bnacc = (float*)alloc(256 * 4);
    float* bn_s = (float*)alloc(128 * 4);
    float* bn_t = (float*)alloc(128 * 4);
    float* poolAcc = (float*)alloc(128 * 128 * 4);
    unsigned short* Wb1 = (unsigned short*)alloc(128 * 128 * 2);
    unsigned short* Wb2 = (unsigned short*)alloc(128 * 128 * 2);

    const int E = N_EDGES, N = N_NODES;
    const int scanBlocks = (N + 1023) / 1024;  // 98

    // --- zero counters, then phase A: gemm1 || count || packW1/2 ---
    hipMemsetAsync(degcnt, 0, (size_t)N * 4, stream);
    hipMemsetAsync(cnt, 0, (size_t)N * 4, stream);
    phaseA<<<GEMM_GRID + COUNT_GRID + 2 * PACK_BLOCKS, 256, 0, stream>>>(
        x, W0, row, col, degcnt, cnt, W1, W2, Wb1, Wb2, bufA, N, E);

    // --- CSR finish ---
    dinv_kernel<<<(N + 255) / 256, 256, 0, stream>>>(degcnt, dinv, N);
    scanA<<<scanBlocks, 256, 0, stream>>>(cnt, rowptr, blockSums, N);
    scanB<<<1, 128, 0, stream>>>(blockSums, blockOffs, scanBlocks);
    scanC<<<(N + 255) / 256, 256, 0, stream>>>(rowptr, blockOffs, wptr, N);
    fill_kernel<<<(E + 255) / 256, 256, 0, stream>>>(row, col, wptr, srcIdx, E);

    const int gemmGrid = (N + 63) / 64;  // 1563
    const int aggGrid = (N + 3) / 4;     // 25000

    // --- layer 1 aggregation (gemm1 already done in phase A) ---
    agg_kernel<<<aggGrid, 256, 0, stream>>>(bufA, rowptr, cnt, srcIdx, dinv, bufB, N);
    hipMemsetAsync(bnacc, 0, 256 * 4, stream);
    bnstats<<<512, 256, 0, stream>>>(bufB, bnacc, N);
    bnfin<<<1, 128, 0, stream>>>(bnacc, g0, b0, bn_s, bn_t, 1.0f / N);

    // --- layer 2 ---
    gemm_mfma<<<gemmGrid, 256, 0, stream>>>(bufB, Wb1, bn_s, bn_t, bufA, N);
    agg_kernel<<<aggGrid, 256, 0, stream>>>(bufA, rowptr, cnt, srcIdx, dinv, bufB, N);
    hipMemsetAsync(bnacc, 0, 256 * 4, stream);
    bnstats<<<512, 256, 0, stream>>>(bufB, bnacc, N);
    bnfin<<<1, 128, 0, stream>>>(bnacc, g1, b1, bn_s, bn_t, 1.0f / N);

    // --- layer 3 ---
    gemm_mfma<<<gemmGrid, 256, 0, stream>>>(bufB, Wb2, bn_s, bn_t, bufA, N);
    agg_kernel<<<aggGrid, 256, 0, stream>>>(bufA, rowptr, cnt, srcIdx, dinv, bufB, N);

    // --- pool (parallel partials) + head ---
    hipMemsetAsync(poolAcc, 0, 128 * 128 * 4, stream);
    pool_partial<<<N_GRAPHS * POOL_SLICES, 256, 0, stream>>>(bufB, batch, poolAcc, N);
    head_kernel<<<N_GRAPHS, 128, 0, stream>>>(poolAcc, batch, Wg1, bg1, Wg2, bg2, out, N);
}

// Round 10
// 408.281 us; speedup vs baseline: 3.5115x; 1.0221x over previous
//
#include <hip/hip_runtime.h>

#define N_NODES 100000
#define N_EDGES 640000
#define HID 128
#define N_CLASSES 40
#define N_GRAPHS 128
#define BN_EPS 1e-5f
#define POOL_SLICES 16

#define GEMM_GRID 1563   // (N_NODES + 63) / 64
#define COUNT_GRID 2500  // (N_EDGES + 255) / 256
#define PACK_BLOCKS 64   // 16384 elems / 256 per weight matrix

typedef __attribute__((ext_vector_type(8))) short bf16x8;
typedef __attribute__((ext_vector_type(4))) float f32x4;

// round-to-nearest-even f32 -> bf16 (as raw u16)
__device__ __forceinline__ unsigned short f2bf(float f) {
    unsigned u = __float_as_uint(f);
    u += 0x7FFFu + ((u >> 16) & 1u);
    return (unsigned short)(u >> 16);
}

__device__ __forceinline__ float bflo(unsigned u) { return __uint_as_float(u << 16); }
__device__ __forceinline__ float bfhi(unsigned u) { return __uint_as_float(u & 0xFFFF0000u); }

// ---------------------------------------------------------------------------
// Pack W [128x128 f32, row-major k,n] -> bf16 fragment layout:
// Wb[(k>>3)*1024 + n*8 + (k&7)].
// ---------------------------------------------------------------------------
__global__ void packW(const float* __restrict__ W, unsigned short* __restrict__ Wb) {
    int idx = blockIdx.x * 256 + threadIdx.x;  // 0..16383
    int k = idx >> 7, n = idx & 127;
    Wb[(k >> 3) * 1024 + n * 8 + (k & 7)] = f2bf(W[k * 128 + n]);
}

// ---------------------------------------------------------------------------
// Phase A mega-kernel: [gemm layer-1 (Wb0 pre-packed, global/L1 reads, no
// LDS)] || [edge counting] || [pack Wb1/Wb2]. Independent block ranges;
// count's atomic latency hides under gemm's MFMA/VALU work.
// ---------------------------------------------------------------------------
__global__ __launch_bounds__(256) void phaseA(
    const float* __restrict__ x, const unsigned short* __restrict__ Wb0,
    const int* __restrict__ row, const int* __restrict__ col,
    int* degcnt, int* cnt,
    const float* __restrict__ W1, const float* __restrict__ W2,
    unsigned short* __restrict__ Wb1, unsigned short* __restrict__ Wb2,
    unsigned short* __restrict__ outA, int nRows, int E) {
    const int b = blockIdx.x;

    if (b < GEMM_GRID) {
        // ---- gemm layer 1: outA = bf16( x @ W0 ) ----
        const int wave = threadIdx.x >> 6;
        const int lane = threadIdx.x & 63;
        const int lrow = lane & 15;
        const int lk = lane >> 4;
        const long rowA = (long)b * 64 + wave * 16 + lrow;
        const bool okA = rowA < (long)nRows;
        const float* rp = x + (okA ? rowA : 0) * 128;

        bf16x8 afrag[4];
#pragma unroll
        for (int kk = 0; kk < 4; ++kk) {
            int k0 = kk * 32 + lk * 8;
            float4 v0, v1;
            if (okA) {
                v0 = *(const float4*)(rp + k0);
                v1 = *(const float4*)(rp + k0 + 4);
            } else {
                v0 = v1 = make_float4(0.f, 0.f, 0.f, 0.f);
            }
            bf16x8 a;
            a[0] = (short)f2bf(v0.x); a[1] = (short)f2bf(v0.y);
            a[2] = (short)f2bf(v0.z); a[3] = (short)f2bf(v0.w);
            a[4] = (short)f2bf(v1.x); a[5] = (short)f2bf(v1.y);
            a[6] = (short)f2bf(v1.z); a[7] = (short)f2bf(v1.w);
            afrag[kk] = a;
        }

        f32x4 acc[8];
#pragma unroll
        for (int nt = 0; nt < 8; ++nt) acc[nt] = (f32x4){0.f, 0.f, 0.f, 0.f};

#pragma unroll
        for (int nt = 0; nt < 8; ++nt) {
            const unsigned short* wp = Wb0 + lk * 1024 + (nt * 16 + lrow) * 8;
#pragma unroll
            for (int kk = 0; kk < 4; ++kk) {
                bf16x8 bb = *(const bf16x8*)(wp + kk * 4096);
                acc[nt] = __builtin_amdgcn_mfma_f32_16x16x32_bf16(afrag[kk], bb, acc[nt], 0, 0, 0);
            }
        }

        const long rowD0 = (long)b * 64 + wave * 16 + lk * 4;
#pragma unroll
        for (int r = 0; r < 4; ++r) {
            long rd = rowD0 + r;
            if (rd < nRows) {
                unsigned short* op = outA + rd * 128 + lrow;
#pragma unroll
                for (int nt = 0; nt < 8; ++nt) op[nt * 16] = f2bf(acc[nt][r]);
            }
        }
    } else if (b < GEMM_GRID + COUNT_GRID) {
        // ---- edge degree counting ----
        int e = (b - GEMM_GRID) * 256 + threadIdx.x;
        if (e < E) {
            atomicAdd(&degcnt[row[e]], 1);
            atomicAdd(&cnt[col[e]], 1);
        }
    } else {
        // ---- pack W1 / W2 to bf16 fragment layout ----
        int pb = b - GEMM_GRID - COUNT_GRID;  // 0..127
        const float* Wsrc = (pb < PACK_BLOCKS) ? W1 : W2;
        unsigned short* Wdst = (pb < PACK_BLOCKS) ? Wb1 : Wb2;
        int idx = (pb & (PACK_BLOCKS - 1)) * 256 + threadIdx.x;
        int k = idx >> 7, n = idx & 127;
        Wdst[(k >> 3) * 1024 + n * 8 + (k & 7)] = f2bf(Wsrc[k * 128 + n]);
    }
}

__global__ void dinv_kernel(const int* __restrict__ degcnt, float* __restrict__ dinv, int n) {
    int i = blockIdx.x * 256 + threadIdx.x;
    if (i < n) dinv[i] = rsqrtf((float)degcnt[i] + 1.0f);
}

// block-level exclusive scan (1024 elements per block of 256 threads)
__global__ __launch_bounds__(256) void scanA(const int* __restrict__ cnt, int* __restrict__ rowptr,
                                             int* __restrict__ blockSums, int n) {
    __shared__ int sdata[256];
    int t = threadIdx.x;
    int base = blockIdx.x * 1024 + t * 4;
    int c[4];
#pragma unroll
    for (int j = 0; j < 4; ++j) c[j] = (base + j < n) ? cnt[base + j] : 0;
    int s = c[0] + c[1] + c[2] + c[3];
    sdata[t] = s;
    __syncthreads();
    for (int off = 1; off < 256; off <<= 1) {
        int v = (t >= off) ? sdata[t - off] : 0;
        __syncthreads();
        sdata[t] += v;
        __syncthreads();
    }
    int excl = sdata[t] - s;
    if (t == 255) blockSums[blockIdx.x] = sdata[255];
    int run = excl;
#pragma unroll
    for (int j = 0; j < 4; ++j) {
        if (base + j < n) rowptr[base + j] = run;
        run += c[j];
    }
}

__global__ void scanB(const int* __restrict__ blockSums, int* __restrict__ blockOffs, int nb) {
    __shared__ int sdata[128];
    int t = threadIdx.x;
    int v = (t < nb) ? blockSums[t] : 0;
    sdata[t] = v;
    __syncthreads();
    for (int off = 1; off < 128; off <<= 1) {
        int u = (t >= off) ? sdata[t - off] : 0;
        __syncthreads();
        sdata[t] += u;
        __syncthreads();
    }
    if (t < nb) blockOffs[t] = sdata[t] - v;
}

__global__ void scanC(int* __restrict__ rowptr, const int* __restrict__ blockOffs,
                      int* __restrict__ wptr, int n) {
    int i = blockIdx.x * 256 + threadIdx.x;
    if (i < n) {
        int v = rowptr[i] + blockOffs[i >> 10];
        rowptr[i] = v;
        wptr[i] = v;
    }
}

__global__ void fill_kernel(const int* __restrict__ row, const int* __restrict__ col,
                            int* wptr, int* __restrict__ srcIdx, int E) {
    int e = blockIdx.x * 256 + threadIdx.x;
    if (e < E) {
        int p = atomicAdd(&wptr[col[e]], 1);
        srcIdx[p] = row[e];
    }
}

// ---------------------------------------------------------------------------
// MFMA GEMM (layers 2,3): out_bf16 = bf16( relu(BN(in_bf16)) @ W ).
// Input h is bf16; BN+ReLU applied in f32 between load and re-rounding.
// ---------------------------------------------------------------------------
__global__ __launch_bounds__(256) void gemm_mfma(
    const unsigned short* __restrict__ in, const unsigned short* __restrict__ Wb,
    const float* __restrict__ bn_s, const float* __restrict__ bn_t,
    unsigned short* __restrict__ out, int nRows) {
    const int wave = threadIdx.x >> 6;
    const int lane = threadIdx.x & 63;
    const int lrow = lane & 15;
    const int lk = lane >> 4;
    const long rowA = (long)blockIdx.x * 64 + wave * 16 + lrow;
    const bool okA = rowA < (long)nRows;
    const unsigned short* rp = in + (okA ? rowA : 0) * 128;

    bf16x8 afrag[4];
#pragma unroll
    for (int kk = 0; kk < 4; ++kk) {
        int k0 = kk * 32 + lk * 8;
        unsigned ru[4] = {0u, 0u, 0u, 0u};
        if (okA) {
            uint4 u = *(const uint4*)(rp + k0);
            ru[0] = u.x; ru[1] = u.y; ru[2] = u.z; ru[3] = u.w;
        }
        float f[8];
        f[0] = bflo(ru[0]); f[1] = bfhi(ru[0]);
        f[2] = bflo(ru[1]); f[3] = bfhi(ru[1]);
        f[4] = bflo(ru[2]); f[5] = bfhi(ru[2]);
        f[6] = bflo(ru[3]); f[7] = bfhi(ru[3]);
        float4 s0 = *(const float4*)&bn_s[k0];
        float4 s1 = *(const float4*)&bn_s[k0 + 4];
        float4 t0 = *(const float4*)&bn_t[k0];
        float4 t1 = *(const float4*)&bn_t[k0 + 4];
        f[0] = fmaxf(fmaf(f[0], s0.x, t0.x), 0.f);
        f[1] = fmaxf(fmaf(f[1], s0.y, t0.y), 0.f);
        f[2] = fmaxf(fmaf(f[2], s0.z, t0.z), 0.f);
        f[3] = fmaxf(fmaf(f[3], s0.w, t0.w), 0.f);
        f[4] = fmaxf(fmaf(f[4], s1.x, t1.x), 0.f);
        f[5] = fmaxf(fmaf(f[5], s1.y, t1.y), 0.f);
        f[6] = fmaxf(fmaf(f[6], s1.z, t1.z), 0.f);
        f[7] = fmaxf(fmaf(f[7], s1.w, t1.w), 0.f);
        bf16x8 a;
#pragma unroll
        for (int j = 0; j < 8; ++j) a[j] = (short)f2bf(f[j]);
        afrag[kk] = a;
    }

    f32x4 acc[8];
#pragma unroll
    for (int nt = 0; nt < 8; ++nt) acc[nt] = (f32x4){0.f, 0.f, 0.f, 0.f};

#pragma unroll
    for (int nt = 0; nt < 8; ++nt) {
        const unsigned short* wp = Wb + lk * 1024 + (nt * 16 + lrow) * 8;
#pragma unroll
        for (int kk = 0; kk < 4; ++kk) {
            bf16x8 b = *(const bf16x8*)(wp + kk * 4096);
            acc[nt] = __builtin_amdgcn_mfma_f32_16x16x32_bf16(afrag[kk], b, acc[nt], 0, 0, 0);
        }
    }

    const long rowD0 = (long)blockIdx.x * 64 + wave * 16 + lk * 4;
#pragma unroll
    for (int r = 0; r < 4; ++r) {
        long rd = rowD0 + r;
        if (rd < nRows) {
            unsigned short* op = out + rd * 128 + lrow;
#pragma unroll
            for (int nt = 0; nt < 8; ++nt) op[nt * 16] = f2bf(acc[nt][r]);
        }
    }
}

// ---------------------------------------------------------------------------
// Aggregation: out_bf16[v] = bf16( dinv[v] * sum dinv[src] * h_bf16[src] ).
// Wave per node; lane loads uint2 (4 cols); 32 lanes/row -> 2 edges per
// wave-load; 4 loads in flight -> 8 edges/chunk. f32 accumulate.
// ---------------------------------------------------------------------------
__global__ __launch_bounds__(256) void agg_kernel(
    const unsigned short* __restrict__ h, const int* __restrict__ rowptr,
    const int* __restrict__ cnt, const int* __restrict__ srcIdx,
    const float* __restrict__ dinv, unsigned short* __restrict__ out, int nNodes) {
    int wave = threadIdx.x >> 6;
    int lane = threadIdx.x & 63;
    int half = lane >> 5;
    int l5 = lane & 31;
    int v = blockIdx.x * 4 + wave;
    if (v >= nNodes) return;
    int start = rowptr[v];
    int n = cnt[v];
    float4 a0 = make_float4(0.f, 0.f, 0.f, 0.f), a1 = a0, a2 = a0, a3 = a0;
    for (int e = 0; e < n; e += 8) {
        int e0 = e + half, e1 = e + 2 + half, e2 = e + 4 + half, e3 = e + 6 + half;
        int i0 = start + ((e0 < n) ? e0 : 0);
        int i1 = start + ((e1 < n) ? e1 : 0);
        int i2 = start + ((e2 < n) ? e2 : 0);
        int i3 = start + ((e3 < n) ? e3 : 0);
        int s0 = srcIdx[i0], s1 = srcIdx[i1], s2 = srcIdx[i2], s3 = srcIdx[i3];
        float w0 = (e0 < n) ? dinv[s0] : 0.f;
        float w1 = (e1 < n) ? dinv[s1] : 0.f;
        float w2 = (e2 < n) ? dinv[s2] : 0.f;
        float w3 = (e3 < n) ? dinv[s3] : 0.f;
        uint2 u0 = *(const uint2*)&h[(long)s0 * 128 + l5 * 4];
        uint2 u1 = *(const uint2*)&h[(long)s1 * 128 + l5 * 4];
        uint2 u2 = *(const uint2*)&h[(long)s2 * 128 + l5 * 4];
        uint2 u3 = *(const uint2*)&h[(long)s3 * 128 + l5 * 4];
        a0.x = fmaf(w0, bflo(u0.x), a0.x); a0.y = fmaf(w0, bfhi(u0.x), a0.y);
        a0.z = fmaf(w0, bflo(u0.y), a0.z); a0.w = fmaf(w0, bfhi(u0.y), a0.w);
        a1.x = fmaf(w1, bflo(u1.x), a1.x); a1.y = fmaf(w1, bfhi(u1.x), a1.y);
        a1.z = fmaf(w1, bflo(u1.y), a1.z); a1.w = fmaf(w1, bfhi(u1.y), a1.w);
        a2.x = fmaf(w2, bflo(u2.x), a2.x); a2.y = fmaf(w2, bfhi(u2.x), a2.y);
        a2.z = fmaf(w2, bflo(u2.y), a2.z); a2.w = fmaf(w2, bfhi(u2.y), a2.w);
        a3.x = fmaf(w3, bflo(u3.x), a3.x); a3.y = fmaf(w3, bfhi(u3.x), a3.y);
        a3.z = fmaf(w3, bflo(u3.y), a3.z); a3.w = fmaf(w3, bfhi(u3.y), a3.w);
    }
    float tx = (a0.x + a1.x) + (a2.x + a3.x);
    float ty = (a0.y + a1.y) + (a2.y + a3.y);
    float tz = (a0.z + a1.z) + (a2.z + a3.z);
    float tw = (a0.w + a1.w) + (a2.w + a3.w);
    tx += __shfl_xor(tx, 32);
    ty += __shfl_xor(ty, 32);
    tz += __shfl_xor(tz, 32);
    tw += __shfl_xor(tw, 32);
    if (half == 0) {
        float dv = dinv[v];
        unsigned lo = ((unsigned)f2bf(ty * dv) << 16) | (unsigned)f2bf(tx * dv);
        unsigned hi = ((unsigned)f2bf(tw * dv) << 16) | (unsigned)f2bf(tz * dv);
        *(uint2*)&out[(long)v * 128 + l5 * 4] = make_uint2(lo, hi);
    }
}

// ---------------------------------------------------------------------------
// BN statistics over bf16 h: per-column sum and sum-of-squares.
// Thread (c2 = t&63 handles cols 2c2,2c2+1; rg = t>>6 row group of 4).
// ---------------------------------------------------------------------------
__global__ __launch_bounds__(256) void bnstats(const unsigned short* __restrict__ h,
                                               float* __restrict__ sums, int nRows) {
    int c2 = threadIdx.x & 63;
    int rg = threadIdx.x >> 6;
    int chunk = (nRows + gridDim.x - 1) / gridDim.x;
    int r0 = blockIdx.x * chunk;
    int r1 = min(r0 + chunk, nRows);
    float slo = 0.f, s2lo = 0.f, shi = 0.f, s2hi = 0.f;
    for (int r = r0 + rg; r < r1; r += 4) {
        unsigned u = *(const unsigned*)&h[(long)r * 128 + c2 * 2];
        float lo = bflo(u), hi = bfhi(u);
        slo += lo; s2lo = fmaf(lo, lo, s2lo);
        shi += hi; s2hi = fmaf(hi, hi, s2hi);
    }
    __shared__ float l[4][256];
    l[0][threadIdx.x] = slo; l[1][threadIdx.x] = s2lo;
    l[2][threadIdx.x] = shi; l[3][threadIdx.x] = s2hi;
    __syncthreads();
    if (rg == 0) {
        float a = 0.f, b = 0.f, c = 0.f, d = 0.f;
#pragma unroll
        for (int g = 0; g < 4; ++g) {
            a += l[0][g * 64 + c2]; b += l[1][g * 64 + c2];
            c += l[2][g * 64 + c2]; d += l[3][g * 64 + c2];
        }
        atomicAdd(&sums[c2 * 2], a);
        atomicAdd(&sums[128 + c2 * 2], b);
        atomicAdd(&sums[c2 * 2 + 1], c);
        atomicAdd(&sums[129 + c2 * 2], d);
    }
}

__global__ void bnfin(const float* __restrict__ sums, const float* __restrict__ gamma,
                      const float* __restrict__ beta, float* __restrict__ bn_s,
                      float* __restrict__ bn_t, float invN) {
    int c = threadIdx.x;
    float mean = sums[c] * invN;
    float var = sums[128 + c] * invN - mean * mean;
    float rs = rsqrtf(var + BN_EPS);
    float s = gamma[c] * rs;
    bn_s[c] = s;
    bn_t[c] = beta[c] - mean * s;
}

// ---------------------------------------------------------------------------
// Global mean pool over bf16 h: per-slice partial sums -> poolAcc (f32).
// ---------------------------------------------------------------------------
__global__ __launch_bounds__(256) void pool_partial(
    const unsigned short* __restrict__ h, const int* __restrict__ batch,
    float* __restrict__ poolAcc, int nNodes) {
    int g = blockIdx.x / POOL_SLICES;
    int s = blockIdx.x % POOL_SLICES;
    int a = 0, b = nNodes;
    while (a < b) { int m = (a + b) >> 1; if (batch[m] < g) a = m + 1; else b = m; }
    int lo = a;
    b = nNodes;
    while (a < b) { int m = (a + b) >> 1; if (batch[m] < g + 1) a = m + 1; else b = m; }
    int hi = a;
    int len = hi - lo;
    int per = (len + POOL_SLICES - 1) / POOL_SLICES;
    int a0 = lo + s * per;
    int a1 = min(a0 + per, hi);
    if (a0 >= a1) return;
    int c2 = threadIdx.x & 63;
    int rg = threadIdx.x >> 6;
    float alo = 0.f, ahi = 0.f;
    for (int v = a0 + rg; v < a1; v += 4) {
        unsigned u = *(const unsigned*)&h[(long)v * 128 + c2 * 2];
        alo += bflo(u);
        ahi += bfhi(u);
    }
    __shared__ float l[2][256];
    l[0][threadIdx.x] = alo;
    l[1][threadIdx.x] = ahi;
    __syncthreads();
    if (rg == 0) {
        float aa = 0.f, bb = 0.f;
#pragma unroll
        for (int gg = 0; gg < 4; ++gg) {
            aa += l[0][gg * 64 + c2];
            bb += l[1][gg * 64 + c2];
        }
        atomicAdd(&poolAcc[g * 128 + c2 * 2], aa);
        atomicAdd(&poolAcc[g * 128 + c2 * 2 + 1], bb);
    }
}

// ---------------------------------------------------------------------------
// MLP head: mean = poolAcc/cnt; relu(xg@Wg1+bg1) @ Wg2 + bg2 -> log_softmax
// ---------------------------------------------------------------------------
__global__ __launch_bounds__(128) void head_kernel(
    const float* __restrict__ poolAcc, const int* __restrict__ batch,
    const float* __restrict__ Wg1, const float* __restrict__ bg1,
    const float* __restrict__ Wg2, const float* __restrict__ bg2,
    float* __restrict__ out, int nNodes) {
    __shared__ float xr[128], tr[128], lg[N_CLASSES], red[2];
    int g = blockIdx.x, t = threadIdx.x;
    int a = 0, b = nNodes;
    while (a < b) { int m = (a + b) >> 1; if (batch[m] < g) a = m + 1; else b = m; }
    int lo = a;
    b = nNodes;
    while (a < b) { int m = (a + b) >> 1; if (batch[m] < g + 1) a = m + 1; else b = m; }
    float cntf = fmaxf((float)(a - lo), 1.0f);
    xr[t] = poolAcc[g * 128 + t] / cntf;
    __syncthreads();
    float s = bg1[t];
    for (int k = 0; k < 128; ++k) s = fmaf(xr[k], Wg1[k * 128 + t], s);
    tr[t] = fmaxf(s, 0.f);
    __syncthreads();
    if (t < N_CLASSES) {
        float s2 = bg2[t];
        for (int k = 0; k < 128; ++k) s2 = fmaf(tr[k], Wg2[k * N_CLASSES + t], s2);
        lg[t] = s2;
    }
    __syncthreads();
    if (t == 0) {
        float m = -1e30f;
        for (int j = 0; j < N_CLASSES; ++j) m = fmaxf(m, lg[j]);
        float se = 0.f;
        for (int j = 0; j < N_CLASSES; ++j) se += expf(lg[j] - m);
        red[0] = m;
        red[1] = logf(se);
    }
    __syncthreads();
    if (t < N_CLASSES) out[g * N_CLASSES + t] = lg[t] - red[0] - red[1];
}

// ---------------------------------------------------------------------------
extern "C" void kernel_launch(void* const* d_in, const int* in_sizes, int n_in,
                              void* d_out, int out_size, void* d_ws, size_t ws_size,
                              hipStream_t stream) {
    const float* x = (const float*)d_in[0];
    const int* edge = (const int*)d_in[1];
    const int* row = edge;
    const int* col = edge + N_EDGES;
    const int* batch = (const int*)d_in[2];
    const float* W0 = (const float*)d_in[3];
    const float* g0 = (const float*)d_in[4];
    const float* b0 = (const float*)d_in[5];
    const float* W1 = (const float*)d_in[6];
    const float* g1 = (const float*)d_in[7];
    const float* b1 = (const float*)d_in[8];
    const float* W2 = (const float*)d_in[9];
    const float* Wg1 = (const float*)d_in[10];
    const float* bg1 = (const float*)d_in[11];
    const float* Wg2 = (const float*)d_in[12];
    const float* bg2 = (const float*)d_in[13];
    float* out = (float*)d_out;

    char* p = (char*)d_ws;
    auto alloc = [&](size_t bytes) {
        void* r = (void*)p;
        p += (bytes + 255) & ~(size_t)255;
        return r;
    };
    unsigned short* bufA = (unsigned short*)alloc((size_t)N_NODES * 128 * 2);  // bf16 gemm out
    unsigned short* bufB = (unsigned short*)alloc((size_t)N_NODES * 128 * 2);  // bf16 agg out
    float* dinv = (float*)alloc((size_t)N_NODES * 4);
    int* degcnt = (int*)alloc((size_t)N_NODES * 4);
    int* cnt = (int*)alloc((size_t)N_NODES * 4);
    int* rowptr = (int*)alloc((size_t)N_NODES * 4);
    int* wptr = (int*)alloc((size_t)N_NODES * 4);
    int* srcIdx = (int*)alloc((size_t)N_EDGES * 4);
    int* blockSums = (int*)alloc(1024 * 4);
    int* blockOffs = (int*)alloc(1024 * 4);
    float* bnacc = (float*)alloc(256 * 4);
    float* bn_s = (float*)alloc(128 * 4);
    float* bn_t = (float*)alloc(128 * 4);
    float* poolAcc = (float*)alloc(128 * 128 * 4);
    unsigned short* Wb0 = (unsigned short*)alloc(128 * 128 * 2);
    unsigned short* Wb1 = (unsigned short*)alloc(128 * 128 * 2);
    unsigned short* Wb2 = (unsigned short*)alloc(128 * 128 * 2);

    const int E = N_EDGES, N = N_NODES;
    const int scanBlocks = (N + 1023) / 1024;  // 98

    // --- zero counters + pack Wb0, then phase A: gemm1 || count || packW1/2 ---
    hipMemsetAsync(degcnt, 0, (size_t)N * 4, stream);
    hipMemsetAsync(cnt, 0, (size_t)N * 4, stream);
    packW<<<PACK_BLOCKS, 256, 0, stream>>>(W0, Wb0);
    phaseA<<<GEMM_GRID + COUNT_GRID + 2 * PACK_BLOCKS, 256, 0, stream>>>(
        x, Wb0, row, col, degcnt, cnt, W1, W2, Wb1, Wb2, bufA, N, E);

    // --- CSR finish ---
    dinv_kernel<<<(N + 255) / 256, 256, 0, stream>>>(degcnt, dinv, N);
    scanA<<<scanBlocks, 256, 0, stream>>>(cnt, rowptr, blockSums, N);
    scanB<<<1, 128, 0, stream>>>(blockSums, blockOffs, scanBlocks);
    scanC<<<(N + 255) / 256, 256, 0, stream>>>(rowptr, blockOffs, wptr, N);
    fill_kernel<<<(E + 255) / 256, 256, 0, stream>>>(row, col, wptr, srcIdx, E);

    const int gemmGrid = (N + 63) / 64;  // 1563
    const int aggGrid = (N + 3) / 4;     // 25000

    // --- layer 1 aggregation (gemm1 already done in phase A) ---
    agg_kernel<<<aggGrid, 256, 0, stream>>>(bufA, rowptr, cnt, srcIdx, dinv, bufB, N);
    hipMemsetAsync(bnacc, 0, 256 * 4, stream);
    bnstats<<<512, 256, 0, stream>>>(bufB, bnacc, N);
    bnfin<<<1, 128, 0, stream>>>(bnacc, g0, b0, bn_s, bn_t, 1.0f / N);

    // --- layer 2 ---
    gemm_mfma<<<gemmGrid, 256, 0, stream>>>(bufB, Wb1, bn_s, bn_t, bufA, N);
    agg_kernel<<<aggGrid, 256, 0, stream>>>(bufA, rowptr, cnt, srcIdx, dinv, bufB, N);
    hipMemsetAsync(bnacc, 0, 256 * 4, stream);
    bnstats<<<512, 256, 0, stream>>>(bufB, bnacc, N);
    bnfin<<<1, 128, 0, stream>>>(bnacc, g1, b1, bn_s, bn_t, 1.0f / N);

    // --- layer 3 ---
    gemm_mfma<<<gemmGrid, 256, 0, stream>>>(bufB, Wb2, bn_s, bn_t, bufA, N);
    agg_kernel<<<aggGrid, 256, 0, stream>>>(bufA, rowptr, cnt, srcIdx, dinv, bufB, N);

    // --- pool (parallel partials) + head ---
    hipMemsetAsync(poolAcc, 0, 128 * 128 * 4, stream);
    pool_partial<<<N_GRAPHS * POOL_SLICES, 256, 0, stream>>>(bufB, batch, poolAcc, N);
    head_kernel<<<N_GRAPHS, 128, 0, stream>>>(poolAcc, batch, Wg1, bg1, Wg2, bg2, out, N);
}

// Round 11
// 405.012 us; speedup vs baseline: 3.5398x; 1.0081x over previous
//
#include <hip/hip_runtime.h>

#define N_NODES 100000
#define N_EDGES 640000
#define HID 128
#define N_CLASSES 40
#define N_GRAPHS 128
#define BN_EPS 1e-5f
#define POOL_SLICES 16

#define GEMM_GRID 1563   // (N_NODES + 63) / 64
#define COUNT_GRID 2500  // (N_EDGES + 255) / 256
#define PACK_BLOCKS 64   // 16384 elems / 256 per weight matrix

typedef __attribute__((ext_vector_type(8))) short bf16x8;
typedef __attribute__((ext_vector_type(4))) float f32x4;

// round-to-nearest-even f32 -> bf16 (as raw u16)
__device__ __forceinline__ unsigned short f2bf(float f) {
    unsigned u = __float_as_uint(f);
    u += 0x7FFFu + ((u >> 16) & 1u);
    return (unsigned short)(u >> 16);
}

__device__ __forceinline__ float bflo(unsigned u) { return __uint_as_float(u << 16); }
__device__ __forceinline__ float bfhi(unsigned u) { return __uint_as_float(u & 0xFFFF0000u); }

// ---------------------------------------------------------------------------
// Pack W [128x128 f32, row-major k,n] -> bf16 fragment layout:
// Wb[(k>>3)*1024 + n*8 + (k&7)].
// ---------------------------------------------------------------------------
__global__ void packW(const float* __restrict__ W, unsigned short* __restrict__ Wb) {
    int idx = blockIdx.x * 256 + threadIdx.x;  // 0..16383
    int k = idx >> 7, n = idx & 127;
    Wb[(k >> 3) * 1024 + n * 8 + (k & 7)] = f2bf(W[k * 128 + n]);
}

// ---------------------------------------------------------------------------
// Phase A mega-kernel: [gemm layer-1] || [edge counting + slot capture] ||
// [pack Wb1/Wb2]. count branch records each edge's arrival order (slot) so
// the later fill pass needs NO atomics.
// ---------------------------------------------------------------------------
__global__ __launch_bounds__(256) void phaseA(
    const float* __restrict__ x, const unsigned short* __restrict__ Wb0,
    const int* __restrict__ row, const int* __restrict__ col,
    int* degcnt, int* cnt, int* __restrict__ slot,
    const float* __restrict__ W1, const float* __restrict__ W2,
    unsigned short* __restrict__ Wb1, unsigned short* __restrict__ Wb2,
    unsigned short* __restrict__ outA, int nRows, int E) {
    const int b = blockIdx.x;

    if (b < GEMM_GRID) {
        // ---- gemm layer 1: outA = bf16( x @ W0 ) ----
        const int wave = threadIdx.x >> 6;
        const int lane = threadIdx.x & 63;
        const int lrow = lane & 15;
        const int lk = lane >> 4;
        const long rowA = (long)b * 64 + wave * 16 + lrow;
        const bool okA = rowA < (long)nRows;
        const float* rp = x + (okA ? rowA : 0) * 128;

        bf16x8 afrag[4];
#pragma unroll
        for (int kk = 0; kk < 4; ++kk) {
            int k0 = kk * 32 + lk * 8;
            float4 v0, v1;
            if (okA) {
                v0 = *(const float4*)(rp + k0);
                v1 = *(const float4*)(rp + k0 + 4);
            } else {
                v0 = v1 = make_float4(0.f, 0.f, 0.f, 0.f);
            }
            bf16x8 a;
            a[0] = (short)f2bf(v0.x); a[1] = (short)f2bf(v0.y);
            a[2] = (short)f2bf(v0.z); a[3] = (short)f2bf(v0.w);
            a[4] = (short)f2bf(v1.x); a[5] = (short)f2bf(v1.y);
            a[6] = (short)f2bf(v1.z); a[7] = (short)f2bf(v1.w);
            afrag[kk] = a;
        }

        f32x4 acc[8];
#pragma unroll
        for (int nt = 0; nt < 8; ++nt) acc[nt] = (f32x4){0.f, 0.f, 0.f, 0.f};

#pragma unroll
        for (int nt = 0; nt < 8; ++nt) {
            const unsigned short* wp = Wb0 + lk * 1024 + (nt * 16 + lrow) * 8;
#pragma unroll
            for (int kk = 0; kk < 4; ++kk) {
                bf16x8 bb = *(const bf16x8*)(wp + kk * 4096);
                acc[nt] = __builtin_amdgcn_mfma_f32_16x16x32_bf16(afrag[kk], bb, acc[nt], 0, 0, 0);
            }
        }

        const long rowD0 = (long)b * 64 + wave * 16 + lk * 4;
#pragma unroll
        for (int r = 0; r < 4; ++r) {
            long rd = rowD0 + r;
            if (rd < nRows) {
                unsigned short* op = outA + rd * 128 + lrow;
#pragma unroll
                for (int nt = 0; nt < 8; ++nt) op[nt * 16] = f2bf(acc[nt][r]);
            }
        }
    } else if (b < GEMM_GRID + COUNT_GRID) {
        // ---- edge degree counting + slot capture ----
        int e = (b - GEMM_GRID) * 256 + threadIdx.x;
        if (e < E) {
            atomicAdd(&degcnt[row[e]], 1);
            slot[e] = atomicAdd(&cnt[col[e]], 1);
        }
    } else {
        // ---- pack W1 / W2 to bf16 fragment layout ----
        int pb = b - GEMM_GRID - COUNT_GRID;  // 0..127
        const float* Wsrc = (pb < PACK_BLOCKS) ? W1 : W2;
        unsigned short* Wdst = (pb < PACK_BLOCKS) ? Wb1 : Wb2;
        int idx = (pb & (PACK_BLOCKS - 1)) * 256 + threadIdx.x;
        int k = idx >> 7, n = idx & 127;
        Wdst[(k >> 3) * 1024 + n * 8 + (k & 7)] = f2bf(Wsrc[k * 128 + n]);
    }
}

__global__ void dinv_kernel(const int* __restrict__ degcnt, float* __restrict__ dinv, int n) {
    int i = blockIdx.x * 256 + threadIdx.x;
    if (i < n) dinv[i] = rsqrtf((float)degcnt[i] + 1.0f);
}

// block-level exclusive scan (1024 elements per block of 256 threads)
__global__ __launch_bounds__(256) void scanA(const int* __restrict__ cnt, int* __restrict__ rowptr,
                                             int* __restrict__ blockSums, int n) {
    __shared__ int sdata[256];
    int t = threadIdx.x;
    int base = blockIdx.x * 1024 + t * 4;
    int c[4];
#pragma unroll
    for (int j = 0; j < 4; ++j) c[j] = (base + j < n) ? cnt[base + j] : 0;
    int s = c[0] + c[1] + c[2] + c[3];
    sdata[t] = s;
    __syncthreads();
    for (int off = 1; off < 256; off <<= 1) {
        int v = (t >= off) ? sdata[t - off] : 0;
        __syncthreads();
        sdata[t] += v;
        __syncthreads();
    }
    int excl = sdata[t] - s;
    if (t == 255) blockSums[blockIdx.x] = sdata[255];
    int run = excl;
#pragma unroll
    for (int j = 0; j < 4; ++j) {
        if (base + j < n) rowptr[base + j] = run;
        run += c[j];
    }
}

__global__ void scanB(const int* __restrict__ blockSums, int* __restrict__ blockOffs, int nb) {
    __shared__ int sdata[128];
    int t = threadIdx.x;
    int v = (t < nb) ? blockSums[t] : 0;
    sdata[t] = v;
    __syncthreads();
    for (int off = 1; off < 128; off <<= 1) {
        int u = (t >= off) ? sdata[t - off] : 0;
        __syncthreads();
        sdata[t] += u;
        __syncthreads();
    }
    if (t < nb) blockOffs[t] = sdata[t] - v;
}

__global__ void scanC(int* __restrict__ rowptr, const int* __restrict__ blockOffs, int n) {
    int i = blockIdx.x * 256 + threadIdx.x;
    if (i < n) rowptr[i] += blockOffs[i >> 10];
}

// fill without atomics: position = rowptr[col] + slot captured at count time
__global__ void fill_kernel(const int* __restrict__ row, const int* __restrict__ col,
                            const int* __restrict__ rowptr, const int* __restrict__ slot,
                            int* __restrict__ srcIdx, int E) {
    int e = blockIdx.x * 256 + threadIdx.x;
    if (e < E) srcIdx[rowptr[col[e]] + slot[e]] = row[e];
}

// ---------------------------------------------------------------------------
// MFMA GEMM (layers 2,3): out_bf16 = bf16( relu(BN(in_bf16)) @ W ).
// ---------------------------------------------------------------------------
__global__ __launch_bounds__(256) void gemm_mfma(
    const unsigned short* __restrict__ in, const unsigned short* __restrict__ Wb,
    const float* __restrict__ bn_s, const float* __restrict__ bn_t,
    unsigned short* __restrict__ out, int nRows) {
    const int wave = threadIdx.x >> 6;
    const int lane = threadIdx.x & 63;
    const int lrow = lane & 15;
    const int lk = lane >> 4;
    const long rowA = (long)blockIdx.x * 64 + wave * 16 + lrow;
    const bool okA = rowA < (long)nRows;
    const unsigned short* rp = in + (okA ? rowA : 0) * 128;

    bf16x8 afrag[4];
#pragma unroll
    for (int kk = 0; kk < 4; ++kk) {
        int k0 = kk * 32 + lk * 8;
        unsigned ru[4] = {0u, 0u, 0u, 0u};
        if (okA) {
            uint4 u = *(const uint4*)(rp + k0);
            ru[0] = u.x; ru[1] = u.y; ru[2] = u.z; ru[3] = u.w;
        }
        float f[8];
        f[0] = bflo(ru[0]); f[1] = bfhi(ru[0]);
        f[2] = bflo(ru[1]); f[3] = bfhi(ru[1]);
        f[4] = bflo(ru[2]); f[5] = bfhi(ru[2]);
        f[6] = bflo(ru[3]); f[7] = bfhi(ru[3]);
        float4 s0 = *(const float4*)&bn_s[k0];
        float4 s1 = *(const float4*)&bn_s[k0 + 4];
        float4 t0 = *(const float4*)&bn_t[k0];
        float4 t1 = *(const float4*)&bn_t[k0 + 4];
        f[0] = fmaxf(fmaf(f[0], s0.x, t0.x), 0.f);
        f[1] = fmaxf(fmaf(f[1], s0.y, t0.y), 0.f);
        f[2] = fmaxf(fmaf(f[2], s0.z, t0.z), 0.f);
        f[3] = fmaxf(fmaf(f[3], s0.w, t0.w), 0.f);
        f[4] = fmaxf(fmaf(f[4], s1.x, t1.x), 0.f);
        f[5] = fmaxf(fmaf(f[5], s1.y, t1.y), 0.f);
        f[6] = fmaxf(fmaf(f[6], s1.z, t1.z), 0.f);
        f[7] = fmaxf(fmaf(f[7], s1.w, t1.w), 0.f);
        bf16x8 a;
#pragma unroll
        for (int j = 0; j < 8; ++j) a[j] = (short)f2bf(f[j]);
        afrag[kk] = a;
    }

    f32x4 acc[8];
#pragma unroll
    for (int nt = 0; nt < 8; ++nt) acc[nt] = (f32x4){0.f, 0.f, 0.f, 0.f};

#pragma unroll
    for (int nt = 0; nt < 8; ++nt) {
        const unsigned short* wp = Wb + lk * 1024 + (nt * 16 + lrow) * 8;
#pragma unroll
        for (int kk = 0; kk < 4; ++kk) {
            bf16x8 b = *(const bf16x8*)(wp + kk * 4096);
            acc[nt] = __builtin_amdgcn_mfma_f32_16x16x32_bf16(afrag[kk], b, acc[nt], 0, 0, 0);
        }
    }

    const long rowD0 = (long)blockIdx.x * 64 + wave * 16 + lk * 4;
#pragma unroll
    for (int r = 0; r < 4; ++r) {
        long rd = rowD0 + r;
        if (rd < nRows) {
            unsigned short* op = out + rd * 128 + lrow;
#pragma unroll
            for (int nt = 0; nt < 8; ++nt) op[nt * 16] = f2bf(acc[nt][r]);
        }
    }
}

// ---------------------------------------------------------------------------
// Aggregation: out_bf16[v] = bf16( dinv[v] * sum dinv[src] * h_bf16[src] ).
// Wave per node; lane loads uint4 (8 cols, 16B): 16 lanes cover a row, so one
// wave-load fetches FOUR edge rows (quarter q serves edge e+q). 4 loads in
// flight -> 16 edges per chunk; deg<=16 nodes finish in ONE latency chain.
// Reduce: slot-sum in regs, shfl_xor(16), shfl_xor(32); q==0 writes uint4.
// ---------------------------------------------------------------------------
__global__ __launch_bounds__(256) void agg_kernel(
    const unsigned short* __restrict__ h, const int* __restrict__ rowptr,
    const int* __restrict__ cnt, const int* __restrict__ srcIdx,
    const float* __restrict__ dinv, unsigned short* __restrict__ out, int nNodes) {
    int wave = threadIdx.x >> 6;
    int lane = threadIdx.x & 63;
    int q = lane >> 4;    // edge sub-slot 0..3
    int c4 = lane & 15;   // cols 8*c4 .. 8*c4+7
    int v = blockIdx.x * 4 + wave;
    if (v >= nNodes) return;
    int start = rowptr[v];
    int n = cnt[v];
    float a0[8], a1[8], a2[8], a3[8];
#pragma unroll
    for (int j = 0; j < 8; ++j) { a0[j] = 0.f; a1[j] = 0.f; a2[j] = 0.f; a3[j] = 0.f; }
    for (int e = 0; e < n; e += 16) {
        int e0 = e + q, e1 = e + 4 + q, e2 = e + 8 + q, e3 = e + 12 + q;
        int i0 = start + ((e0 < n) ? e0 : 0);
        int i1 = start + ((e1 < n) ? e1 : 0);
        int i2 = start + ((e2 < n) ? e2 : 0);
        int i3 = start + ((e3 < n) ? e3 : 0);
        int s0 = srcIdx[i0], s1 = srcIdx[i1], s2 = srcIdx[i2], s3 = srcIdx[i3];
        float w0 = (e0 < n) ? dinv[s0] : 0.f;
        float w1 = (e1 < n) ? dinv[s1] : 0.f;
        float w2 = (e2 < n) ? dinv[s2] : 0.f;
        float w3 = (e3 < n) ? dinv[s3] : 0.f;
        uint4 u0 = *(const uint4*)&h[(long)s0 * 128 + c4 * 8];
        uint4 u1 = *(const uint4*)&h[(long)s1 * 128 + c4 * 8];
        uint4 u2 = *(const uint4*)&h[(long)s2 * 128 + c4 * 8];
        uint4 u3 = *(const uint4*)&h[(long)s3 * 128 + c4 * 8];
        a0[0] = fmaf(w0, bflo(u0.x), a0[0]); a0[1] = fmaf(w0, bfhi(u0.x), a0[1]);
        a0[2] = fmaf(w0, bflo(u0.y), a0[2]); a0[3] = fmaf(w0, bfhi(u0.y), a0[3]);
        a0[4] = fmaf(w0, bflo(u0.z), a0[4]); a0[5] = fmaf(w0, bfhi(u0.z), a0[5]);
        a0[6] = fmaf(w0, bflo(u0.w), a0[6]); a0[7] = fmaf(w0, bfhi(u0.w), a0[7]);
        a1[0] = fmaf(w1, bflo(u1.x), a1[0]); a1[1] = fmaf(w1, bfhi(u1.x), a1[1]);
        a1[2] = fmaf(w1, bflo(u1.y), a1[2]); a1[3] = fmaf(w1, bfhi(u1.y), a1[3]);
        a1[4] = fmaf(w1, bflo(u1.z), a1[4]); a1[5] = fmaf(w1, bfhi(u1.z), a1[5]);
        a1[6] = fmaf(w1, bflo(u1.w), a1[6]); a1[7] = fmaf(w1, bfhi(u1.w), a1[7]);
        a2[0] = fmaf(w2, bflo(u2.x), a2[0]); a2[1] = fmaf(w2, bfhi(u2.x), a2[1]);
        a2[2] = fmaf(w2, bflo(u2.y), a2[2]); a2[3] = fmaf(w2, bfhi(u2.y), a2[3]);
        a2[4] = fmaf(w2, bflo(u2.z), a2[4]); a2[5] = fmaf(w2, bfhi(u2.z), a2[5]);
        a2[6] = fmaf(w2, bflo(u2.w), a2[6]); a2[7] = fmaf(w2, bfhi(u2.w), a2[7]);
        a3[0] = fmaf(w3, bflo(u3.x), a3[0]); a3[1] = fmaf(w3, bfhi(u3.x), a3[1]);
        a3[2] = fmaf(w3, bflo(u3.y), a3[2]); a3[3] = fmaf(w3, bfhi(u3.y), a3[3]);
        a3[4] = fmaf(w3, bflo(u3.z), a3[4]); a3[5] = fmaf(w3, bfhi(u3.z), a3[5]);
        a3[6] = fmaf(w3, bflo(u3.w), a3[6]); a3[7] = fmaf(w3, bfhi(u3.w), a3[7]);
    }
    float r[8];
#pragma unroll
    for (int j = 0; j < 8; ++j) {
        r[j] = (a0[j] + a1[j]) + (a2[j] + a3[j]);
        r[j] += __shfl_xor(r[j], 16);
        r[j] += __shfl_xor(r[j], 32);
    }
    if (q == 0) {
        float dv = dinv[v];
        uint4 o;
        o.x = ((unsigned)f2bf(r[1] * dv) << 16) | (unsigned)f2bf(r[0] * dv);
        o.y = ((unsigned)f2bf(r[3] * dv) << 16) | (unsigned)f2bf(r[2] * dv);
        o.z = ((unsigned)f2bf(r[5] * dv) << 16) | (unsigned)f2bf(r[4] * dv);
        o.w = ((unsigned)f2bf(r[7] * dv) << 16) | (unsigned)f2bf(r[6] * dv);
        *(uint4*)&out[(long)v * 128 + c4 * 8] = o;
    }
}

// ---------------------------------------------------------------------------
// BN statistics over bf16 h: per-column sum and sum-of-squares.
// ---------------------------------------------------------------------------
__global__ __launch_bounds__(256) void bnstats(const unsigned short* __restrict__ h,
                                               float* __restrict__ sums, int nRows) {
    int c2 = threadIdx.x & 63;
    int rg = threadIdx.x >> 6;
    int chunk = (nRows + gridDim.x - 1) / gridDim.x;
    int r0 = blockIdx.x * chunk;
    int r1 = min(r0 + chunk, nRows);
    float slo = 0.f, s2lo = 0.f, shi = 0.f, s2hi = 0.f;
    for (int r = r0 + rg; r < r1; r += 4) {
        unsigned u = *(const unsigned*)&h[(long)r * 128 + c2 * 2];
        float lo = bflo(u), hi = bfhi(u);
        slo += lo; s2lo = fmaf(lo, lo, s2lo);
        shi += hi; s2hi = fmaf(hi, hi, s2hi);
    }
    __shared__ float l[4][256];
    l[0][threadIdx.x] = slo; l[1][threadIdx.x] = s2lo;
    l[2][threadIdx.x] = shi; l[3][threadIdx.x] = s2hi;
    __syncthreads();
    if (rg == 0) {
        float a = 0.f, b = 0.f, c = 0.f, d = 0.f;
#pragma unroll
        for (int g = 0; g < 4; ++g) {
            a += l[0][g * 64 + c2]; b += l[1][g * 64 + c2];
            c += l[2][g * 64 + c2]; d += l[3][g * 64 + c2];
        }
        atomicAdd(&sums[c2 * 2], a);
        atomicAdd(&sums[128 + c2 * 2], b);
        atomicAdd(&sums[c2 * 2 + 1], c);
        atomicAdd(&sums[129 + c2 * 2], d);
    }
}

__global__ void bnfin(const float* __restrict__ sums, const float* __restrict__ gamma,
                      const float* __restrict__ beta, float* __restrict__ bn_s,
                      float* __restrict__ bn_t, float invN) {
    int c = threadIdx.x;
    float mean = sums[c] * invN;
    float var = sums[128 + c] * invN - mean * mean;
    float rs = rsqrtf(var + BN_EPS);
    float s = gamma[c] * rs;
    bn_s[c] = s;
    bn_t[c] = beta[c] - mean * s;
}

// ---------------------------------------------------------------------------
// Global mean pool over bf16 h: per-slice partial sums -> poolAcc (f32).
// ---------------------------------------------------------------------------
__global__ __launch_bounds__(256) void pool_partial(
    const unsigned short* __restrict__ h, const int* __restrict__ batch,
    float* __restrict__ poolAcc, int nNodes) {
    int g = blockIdx.x / POOL_SLICES;
    int s = blockIdx.x % POOL_SLICES;
    int a = 0, b = nNodes;
    while (a < b) { int m = (a + b) >> 1; if (batch[m] < g) a = m + 1; else b = m; }
    int lo = a;
    b = nNodes;
    while (a < b) { int m = (a + b) >> 1; if (batch[m] < g + 1) a = m + 1; else b = m; }
    int hi = a;
    int len = hi - lo;
    int per = (len + POOL_SLICES - 1) / POOL_SLICES;
    int a0 = lo + s * per;
    int a1 = min(a0 + per, hi);
    if (a0 >= a1) return;
    int c2 = threadIdx.x & 63;
    int rg = threadIdx.x >> 6;
    float alo = 0.f, ahi = 0.f;
    for (int v = a0 + rg; v < a1; v += 4) {
        unsigned u = *(const unsigned*)&h[(long)v * 128 + c2 * 2];
        alo += bflo(u);
        ahi += bfhi(u);
    }
    __shared__ float l[2][256];
    l[0][threadIdx.x] = alo;
    l[1][threadIdx.x] = ahi;
    __syncthreads();
    if (rg == 0) {
        float aa = 0.f, bb = 0.f;
#pragma unroll
        for (int gg = 0; gg < 4; ++gg) {
            aa += l[0][gg * 64 + c2];
            bb += l[1][gg * 64 + c2];
        }
        atomicAdd(&poolAcc[g * 128 + c2 * 2], aa);
        atomicAdd(&poolAcc[g * 128 + c2 * 2 + 1], bb);
    }
}

// ---------------------------------------------------------------------------
// MLP head: mean = poolAcc/cnt; relu(xg@Wg1+bg1) @ Wg2 + bg2 -> log_softmax
// ---------------------------------------------------------------------------
__global__ __launch_bounds__(128) void head_kernel(
    const float* __restrict__ poolAcc, const int* __restrict__ batch,
    const float* __restrict__ Wg1, const float* __restrict__ bg1,
    const float* __restrict__ Wg2, const float* __restrict__ bg2,
    float* __restrict__ out, int nNodes) {
    __shared__ float xr[128], tr[128], lg[N_CLASSES], red[2];
    int g = blockIdx.x, t = threadIdx.x;
    int a = 0, b = nNodes;
    while (a < b) { int m = (a + b) >> 1; if (batch[m] < g) a = m + 1; else b = m; }
    int lo = a;
    b = nNodes;
    while (a < b) { int m = (a + b) >> 1; if (batch[m] < g + 1) a = m + 1; else b = m; }
    float cntf = fmaxf((float)(a - lo), 1.0f);
    xr[t] = poolAcc[g * 128 + t] / cntf;
    __syncthreads();
    float s = bg1[t];
    for (int k = 0; k < 128; ++k) s = fmaf(xr[k], Wg1[k * 128 + t], s);
    tr[t] = fmaxf(s, 0.f);
    __syncthreads();
    if (t < N_CLASSES) {
        float s2 = bg2[t];
        for (int k = 0; k < 128; ++k) s2 = fmaf(tr[k], Wg2[k * N_CLASSES + t], s2);
        lg[t] = s2;
    }
    __syncthreads();
    if (t == 0) {
        float m = -1e30f;
        for (int j = 0; j < N_CLASSES; ++j) m = fmaxf(m, lg[j]);
        float se = 0.f;
        for (int j = 0; j < N_CLASSES; ++j) se += expf(lg[j] - m);
        red[0] = m;
        red[1] = logf(se);
    }
    __syncthreads();
    if (t < N_CLASSES) out[g * N_CLASSES + t] = lg[t] - red[0] - red[1];
}

// ---------------------------------------------------------------------------
extern "C" void kernel_launch(void* const* d_in, const int* in_sizes, int n_in,
                              void* d_out, int out_size, void* d_ws, size_t ws_size,
                              hipStream_t stream) {
    const float* x = (const float*)d_in[0];
    const int* edge = (const int*)d_in[1];
    const int* row = edge;
    const int* col = edge + N_EDGES;
    const int* batch = (const int*)d_in[2];
    const float* W0 = (const float*)d_in[3];
    const float* g0 = (const float*)d_in[4];
    const float* b0 = (const float*)d_in[5];
    const float* W1 = (const float*)d_in[6];
    const float* g1 = (const float*)d_in[7];
    const float* b1 = (const float*)d_in[8];
    const float* W2 = (const float*)d_in[9];
    const float* Wg1 = (const float*)d_in[10];
    const float* bg1 = (const float*)d_in[11];
    const float* Wg2 = (const float*)d_in[12];
    const float* bg2 = (const float*)d_in[13];
    float* out = (float*)d_out;

    char* p = (char*)d_ws;
    auto alloc = [&](size_t bytes) {
        void* r = (void*)p;
        p += (bytes + 255) & ~(size_t)255;
        return r;
    };
    unsigned short* bufA = (unsigned short*)alloc((size_t)N_NODES * 128 * 2);  // bf16 gemm out
    unsigned short* bufB = (unsigned short*)alloc((size_t)N_NODES * 128 * 2);  // bf16 agg out
    float* dinv = (float*)alloc((size_t)N_NODES * 4);
    int* degcnt = (int*)alloc((size_t)N_NODES * 4);
    int* cnt = (int*)alloc((size_t)N_NODES * 4);
    int* rowptr = (int*)alloc((size_t)N_NODES * 4);
    int* slot = (int*)alloc((size_t)N_EDGES * 4);
    int* srcIdx = (int*)alloc((size_t)N_EDGES * 4);
    int* blockSums = (int*)alloc(1024 * 4);
    int* blockOffs = (int*)alloc(1024 * 4);
    float* bnacc = (float*)alloc(256 * 4);
    float* bn_s = (float*)alloc(128 * 4);
    float* bn_t = (float*)alloc(128 * 4);
    float* poolAcc = (float*)alloc(128 * 128 * 4);
    unsigned short* Wb0 = (unsigned short*)alloc(128 * 128 * 2);
    unsigned short* Wb1 = (unsigned short*)alloc(128 * 128 * 2);
    unsigned short* Wb2 = (unsigned short*)alloc(128 * 128 * 2);

    const int E = N_EDGES, N = N_NODES;
    const int scanBlocks = (N + 1023) / 1024;  // 98

    // --- zero counters + pack Wb0, then phase A: gemm1 || count+slot || packW1/2
    hipMemsetAsync(degcnt, 0, (size_t)N * 4, stream);
    hipMemsetAsync(cnt, 0, (size_t)N * 4, stream);
    packW<<<PACK_BLOCKS, 256, 0, stream>>>(W0, Wb0);
    phaseA<<<GEMM_GRID + COUNT_GRID + 2 * PACK_BLOCKS, 256, 0, stream>>>(
        x, Wb0, row, col, degcnt, cnt, slot, W1, W2, Wb1, Wb2, bufA, N, E);

    // --- CSR finish (fill has no atomics now) ---
    dinv_kernel<<<(N + 255) / 256, 256, 0, stream>>>(degcnt, dinv, N);
    scanA<<<scanBlocks, 256, 0, stream>>>(cnt, rowptr, blockSums, N);
    scanB<<<1, 128, 0, stream>>>(blockSums, blockOffs, scanBlocks);
    scanC<<<(N + 255) / 256, 256, 0, stream>>>(rowptr, blockOffs, N);
    fill_kernel<<<(E + 255) / 256, 256, 0, stream>>>(row, col, rowptr, slot, srcIdx, E);

    const int gemmGrid = (N + 63) / 64;  // 1563
    const int aggGrid = (N + 3) / 4;     // 25000

    // --- layer 1 aggregation (gemm1 already done in phase A) ---
    agg_kernel<<<aggGrid, 256, 0, stream>>>(bufA, rowptr, cnt, srcIdx, dinv, bufB, N);
    hipMemsetAsync(bnacc, 0, 256 * 4, stream);
    bnstats<<<512, 256, 0, stream>>>(bufB, bnacc, N);
    bnfin<<<1, 128, 0, stream>>>(bnacc, g0, b0, bn_s, bn_t, 1.0f / N);

    // --- layer 2 ---
    gemm_mfma<<<gemmGrid, 256, 0, stream>>>(bufB, Wb1, bn_s, bn_t, bufA, N);
    agg_kernel<<<aggGrid, 256, 0, stream>>>(bufA, rowptr, cnt, srcIdx, dinv, bufB, N);
    hipMemsetAsync(bnacc, 0, 256 * 4, stream);
    bnstats<<<512, 256, 0, stream>>>(bufB, bnacc, N);
    bnfin<<<1, 128, 0, stream>>>(bnacc, g1, b1, bn_s, bn_t, 1.0f / N);

    // --- layer 3 ---
    gemm_mfma<<<gemmGrid, 256, 0, stream>>>(bufB, Wb2, bn_s, bn_t, bufA, N);
    agg_kernel<<<aggGrid, 256, 0, stream>>>(bufA, rowptr, cnt, srcIdx, dinv, bufB, N);

    // --- pool (parallel partials) + head ---
    hipMemsetAsync(poolAcc, 0, 128 * 128 * 4, stream);
    pool_partial<<<N_GRAPHS * POOL_SLICES, 256, 0, stream>>>(bufB, batch, poolAcc, N);
    head_kernel<<<N_GRAPHS, 128, 0, stream>>>(poolAcc, batch, Wg1, bg1, Wg2, bg2, out, N);
}